// Round 8
// baseline (287.203 us; speedup 1.0000x reference)
//
#include <hip/hip_runtime.h>
#include <math.h>

#define HW_ 9216
#define IH 96
#define IW 96
#define NB 2
#define ST (NB*HW_)   // 18432 pixels total

typedef __attribute__((ext_vector_type(8))) short bf16x8;
typedef __attribute__((ext_vector_type(4))) float f32x4;
typedef unsigned short u16;

__device__ __forceinline__ float gelu_f(float v){
  return 0.5f*v*(1.0f+erff(v*0.70710678118654752440f));
}
__device__ __forceinline__ unsigned f2bf(float f){
  unsigned u = __float_as_uint(f);
  return (u + 0x7FFF + ((u>>16)&1)) >> 16;
}
__device__ __forceinline__ float bfl(unsigned u){ return __uint_as_float(u<<16); }
__device__ __forceinline__ float bfh(unsigned u){ return __uint_as_float(u & 0xffff0000u); }

// ---------------------------------------------------------------------------
// K2: fused dual LayerNorm from NCHW input. Block: 32 px x 192 ch via LDS.
// ---------------------------------------------------------------------------
__global__ __launch_bounds__(256) void ln12_k(const float* __restrict__ x,
    const float* __restrict__ g1, const float* __restrict__ b1,
    const float* __restrict__ g2, const float* __restrict__ b2,
    u16* __restrict__ lnc, u16* __restrict__ ln1o,
    float* __restrict__ xc, float* __restrict__ xt)
{
  __shared__ float t[192][33];
  const int p0 = blockIdx.x<<5;
  const int bb = p0/HW_, hw0 = p0 - bb*HW_;
  const int tid = threadIdx.x;
  const int px = tid & 31, cr = tid >> 5;
  const float* xb = x + (size_t)bb*192*HW_ + hw0;
  #pragma unroll
  for (int k=0;k<24;k++){
    int c = cr + k*8;
    t[c][px] = xb[(size_t)c*HW_ + px];
  }
  __syncthreads();
  const int lane = tid&63, wv = tid>>6;
  #pragma unroll 1
  for (int i=0;i<8;i++){
    const int lp = wv*8+i;
    const size_t p = p0 + lp;
    float a0 = t[lane][lp];
    float a1 = (lane<32)? t[64+lane][lp] : 0.f;
    float c0 = t[96+lane][lp];
    float c1 = (lane<32)? t[160+lane][lp] : 0.f;
    float s1=a0+a1, s2=c0+c1;
    #pragma unroll
    for (int o=32;o;o>>=1){ s1+=__shfl_xor(s1,o); s2+=__shfl_xor(s2,o); }
    const float mu1=s1*(1.f/96.f), mu2=s2*(1.f/96.f);
    const float d0=a0-mu1, d1=a1-mu1, e0=c0-mu2, e1=c1-mu2;
    float q1=d0*d0+((lane<32)?d1*d1:0.f), q2=e0*e0+((lane<32)?e1*e1:0.f);
    #pragma unroll
    for (int o=32;o;o>>=1){ q1+=__shfl_xor(q1,o); q2+=__shfl_xor(q2,o); }
    const float r1=rsqrtf(q1*(1.f/96.f)+1e-5f), r2=rsqrtf(q2*(1.f/96.f)+1e-5f);
    lnc [p*96+lane] = (u16)f2bf(d0*r1*g1[lane]+b1[lane]);
    ln1o[p*96+lane] = (u16)f2bf(e0*r2*g2[lane]+b2[lane]);
    xc  [p*96+lane] = a0;
    xt  [p*96+lane] = c0;
    if (lane<32){
      lnc [p*96+64+lane] = (u16)f2bf(d1*r1*g1[64+lane]+b1[64+lane]);
      ln1o[p*96+64+lane] = (u16)f2bf(e1*r2*g2[64+lane]+b2[64+lane]);
      xc  [p*96+64+lane] = a1;
      xt  [p*96+64+lane] = c1;
    }
  }
}

// ---------------------------------------------------------------------------
// K2b: single LayerNorm (fp32 in, bf16 out) — ln2.
// ---------------------------------------------------------------------------
__global__ __launch_bounds__(256) void ln_k(const float* __restrict__ in, int istride,
                                            const float* __restrict__ gam, const float* __restrict__ bet,
                                            u16* __restrict__ out){
  int lane = threadIdx.x & 63;
  int wv   = threadIdx.x >> 6;
  int p    = (blockIdx.x << 2) + wv;
  const float* row = in + (size_t)p*istride;
  float v0 = row[lane];
  float v1 = (lane < 32) ? row[64+lane] : 0.0f;
  float s = v0 + v1;
  #pragma unroll
  for (int o=32;o;o>>=1) s += __shfl_xor(s,o);
  float mu = s * (1.0f/96.0f);
  float d0 = v0 - mu;
  float d1 = v1 - mu;
  float qv = d0*d0 + ((lane<32)? d1*d1 : 0.0f);
  #pragma unroll
  for (int o=32;o;o>>=1) qv += __shfl_xor(qv,o);
  float rstd = rsqrtf(qv*(1.0f/96.0f) + 1e-5f);
  u16* orow = out + (size_t)p*96;
  orow[lane] = (u16)f2bf(d0*rstd*gam[lane] + bet[lane]);
  if (lane < 32) orow[64+lane] = (u16)f2bf(d1*rstd*gam[64+lane] + bet[64+lane]);
}

// ---------------------------------------------------------------------------
// K3b: bf16-MFMA conv1x1.  Block: 128 px x 64 couts, 4 waves (2M x 2N).
// SPLIT: couts >=384 get bias(=p1 bias)+relu and go to out2 (stride 16, bf16).
// ---------------------------------------------------------------------------
template<int ACT, bool CONCAT, bool FINAL, bool HASB, bool HASR, bool OUTBF, bool SPLIT>
__global__ __launch_bounds__(256) void conv_mfma_k(
    const u16* __restrict__ in1, const float* __restrict__ in2f, int istride,
    const u16* __restrict__ wbf, const float* __restrict__ bias,
    const float* __restrict__ res, int rstride,
    void* __restrict__ out, int ostride, int Cin, int Cout,
    u16* __restrict__ out2)
{
  __shared__ __align__(16) unsigned char smem[39936];
  unsigned char* actl = smem;          // [128][208B]
  unsigned char* wl   = smem + 26624;  // [64][208B]
  const int tid=threadIdx.x, lane=tid&63, wv=tid>>6;
  const int lr=lane&15, g4=lane>>4, wm=wv>>1, wn=wv&1;
  const int p0=blockIdx.x<<7, co0=blockIdx.y<<6;

  f32x4 acc[2][4];
  #pragma unroll
  for (int m=0;m<2;m++)
    #pragma unroll
    for (int n=0;n<4;n++) acc[m][n]=(f32x4){0.f,0.f,0.f,0.f};

  for (int kc=0; kc<Cin; kc+=96){
    {
      const int row=tid>>1, half=tid&1;
      if (!CONCAT || kc==0){
        const u16* rp = in1 + (size_t)(p0+row)*istride + (CONCAT?0:kc) + half*48;
        #pragma unroll
        for (int s=0;s<6;s++)
          *(uint4*)(actl + row*208 + (half*6+s)*16) = *(const uint4*)(rp + s*8);
      } else {
        const float* rp = in2f + (size_t)(p0+row)*96 + half*48;
        #pragma unroll
        for (int s=0;s<6;s++){
          float4 a=*(const float4*)(rp+s*8), b=*(const float4*)(rp+s*8+4);
          uint4 pk;
          pk.x=f2bf(a.x)|(f2bf(a.y)<<16);
          pk.y=f2bf(a.z)|(f2bf(a.w)<<16);
          pk.z=f2bf(b.x)|(f2bf(b.y)<<16);
          pk.w=f2bf(b.z)|(f2bf(b.w)<<16);
          *(uint4*)(actl + row*208 + (half*6+s)*16) = pk;
        }
      }
    }
    {
      const int row=tid&63, grp=tid>>6;
      const int co=co0+row;
      const u16* wr = wbf + (size_t)co*Cin + kc;
      #pragma unroll
      for (int s=0;s<3;s++){
        int sl=grp*3+s;
        uint4 v={0,0,0,0};
        if (co<Cout) v=*(const uint4*)(wr + sl*8);
        *(uint4*)(wl + row*208 + sl*16)=v;
      }
    }
    __syncthreads();
    #pragma unroll
    for (int ks=0;ks<3;ks++){
      const int sl=ks*4+g4;
      bf16x8 afr[2], bfr[4];
      #pragma unroll
      for (int m=0;m<2;m++) afr[m]=*(const bf16x8*)(wl + ((wm*2+m)*16+lr)*208 + sl*16);
      #pragma unroll
      for (int n=0;n<4;n++) bfr[n]=*(const bf16x8*)(actl + (wn*64+n*16+lr)*208 + sl*16);
      #pragma unroll
      for (int m=0;m<2;m++)
        #pragma unroll
        for (int n=0;n<4;n++)
          acc[m][n]=__builtin_amdgcn_mfma_f32_16x16x32_bf16(afr[m], bfr[n], acc[m][n],0,0,0);
    }
    __syncthreads();
  }

  if (FINAL){
    float* outf = (float*)out;
    #pragma unroll
    for (int m=0;m<2;m++){
      const int cb=co0+(wm*2+m)*16+(g4<<2);
      float4 bv = make_float4(0.f,0.f,0.f,0.f);
      if (HASB) bv = *(const float4*)(bias+cb);
      #pragma unroll
      for (int n=0;n<4;n++){
        const int p=p0+wn*64+n*16+lr;
        const int bb=p/HW_, hw=p-bb*HW_;
        const float av[4]={acc[m][n].x,acc[m][n].y,acc[m][n].z,acc[m][n].w};
        const float bvv[4]={bv.x,bv.y,bv.z,bv.w};
        #pragma unroll
        for (int j=0;j<4;j++){
          size_t oi=((size_t)bb*192+cb+j)*HW_+hw;
          outf[oi]=av[j]+bvv[j]+res[oi];
        }
      }
    }
    return;
  }
  float* lt=(float*)smem;
  #pragma unroll
  for (int m=0;m<2;m++)
    #pragma unroll
    for (int n=0;n<4;n++){
      int px=wn*64+n*16+lr;
      int c=(wm*2+m)*16+(g4<<2);
      *(f32x4*)&lt[px*68+c]=acc[m][n];
    }
  __syncthreads();
  {
    const int pr=tid>>1, half=tid&1;
    const int p=p0+pr;
    #pragma unroll
    for (int s=0;s<8;s++){
      int cl=half*32+s*4;
      int co=co0+cl;
      if (co<Cout){
        float4 v=*(float4*)&lt[pr*68+cl];
        if (SPLIT && co>=384){
          const int c2 = co-384;
          const float4 bv=*(const float4*)(bias+c2);
          v.x=fmaxf(v.x+bv.x,0.f); v.y=fmaxf(v.y+bv.y,0.f);
          v.z=fmaxf(v.z+bv.z,0.f); v.w=fmaxf(v.w+bv.w,0.f);
          uint2 pk;
          pk.x = f2bf(v.x)|(f2bf(v.y)<<16);
          pk.y = f2bf(v.z)|(f2bf(v.w)<<16);
          *(uint2*)(out2 + (size_t)p*16 + c2) = pk;
          continue;
        }
        if (HASB){ const float4 bv=*(const float4*)(bias+co); v.x+=bv.x;v.y+=bv.y;v.z+=bv.z;v.w+=bv.w; }
        if (ACT==1){
          v.x=fmaxf(v.x,0.f); v.y=fmaxf(v.y,0.f); v.z=fmaxf(v.z,0.f); v.w=fmaxf(v.w,0.f);
        }
        if (HASR){ const float4 rv=*(const float4*)(res+(size_t)p*rstride+co); v.x+=rv.x;v.y+=rv.y;v.z+=rv.z;v.w+=rv.w; }
        if (OUTBF){
          uint2 pk;
          pk.x = f2bf(v.x)|(f2bf(v.y)<<16);
          pk.y = f2bf(v.z)|(f2bf(v.w)<<16);
          *(uint2*)((u16*)out + (size_t)p*ostride + co) = pk;
        } else {
          *(float4*)((float*)out + (size_t)p*ostride + co) = v;
        }
      }
    }
  }
}

// ---------------------------------------------------------------------------
// K4: depthwise 3x3, bf16 in/out, 8 ch/thread (uint4 I/O).
// ---------------------------------------------------------------------------
template<bool HASB, bool DOGELU>
__global__ __launch_bounds__(256) void dw3x3_k(const u16* __restrict__ in, int istride,
                                               const float* __restrict__ w,
                                               const float* __restrict__ bias,
                                               u16* __restrict__ out, int C){
  int t = blockIdx.x*256 + threadIdx.x;
  int cg = C >> 3;
  int p = t / cg;
  if (p >= ST) return;
  int c8 = (t - p*cg) << 3;
  int bb = p / HW_, hw = p - bb*HW_;
  int hy = hw / IW, wx = hw - hy*IW;
  float wr[8][9];
  #pragma unroll
  for (int k=0;k<8;k++)
    #pragma unroll
    for (int tp=0;tp<9;tp++) wr[k][tp]=w[(c8+k)*9+tp];
  float a[8];
  #pragma unroll
  for (int k=0;k<8;k++) a[k]=0.f;
  #pragma unroll
  for (int i=0;i<3;i++){
    int y = hy+i-1;
    if ((unsigned)y >= IH) continue;
    #pragma unroll
    for (int j=0;j<3;j++){
      int x2 = wx+j-1;
      if ((unsigned)x2 >= IW) continue;
      const uint4 r = *(const uint4*)(in + ((size_t)bb*HW_ + y*IW + x2)*istride + c8);
      int tp=i*3+j;
      a[0]+=bfl(r.x)*wr[0][tp]; a[1]+=bfh(r.x)*wr[1][tp];
      a[2]+=bfl(r.y)*wr[2][tp]; a[3]+=bfh(r.y)*wr[3][tp];
      a[4]+=bfl(r.z)*wr[4][tp]; a[5]+=bfh(r.z)*wr[5][tp];
      a[6]+=bfl(r.w)*wr[6][tp]; a[7]+=bfh(r.w)*wr[7][tp];
    }
  }
  if (HASB){
    #pragma unroll
    for (int k=0;k<8;k++) a[k]+=bias[c8+k];
  }
  if (DOGELU){
    #pragma unroll
    for (int k=0;k<8;k++) a[k]=gelu_f(a[k]);
  }
  uint4 pk;
  pk.x = f2bf(a[0])|(f2bf(a[1])<<16);
  pk.y = f2bf(a[2])|(f2bf(a[3])<<16);
  pk.z = f2bf(a[4])|(f2bf(a[5])<<16);
  pk.w = f2bf(a[6])|(f2bf(a[7])<<16);
  *(uint4*)(out + (size_t)p*C + c8) = pk;
}

// ---------------------------------------------------------------------------
// K5: full 3x3 conv 16->16 (para branch), bf16 in / fp32 out. 4 thr/px.
// ---------------------------------------------------------------------------
__global__ __launch_bounds__(256) void p2conv_k(const u16* __restrict__ in, const float* __restrict__ w,
                                                const float* __restrict__ bias, float* __restrict__ out){
  __shared__ float ws[2304];
  int tid = threadIdx.x;
  for (int i=tid;i<2304;i+=256) ws[i]=w[i];
  __syncthreads();
  int gidx = blockIdx.x*256 + tid;
  int p = gidx >> 2, qq = gidx & 3;
  int bb = p / HW_, hw = p - bb*HW_;
  int hy = hw / IW, wx = hw - hy*IW;
  const int cb = qq<<2;
  float a0=bias[cb], a1=bias[cb+1], a2=bias[cb+2], a3=bias[cb+3];
  #pragma unroll
  for (int i=0;i<3;i++){
    int y=hy+i-1; if ((unsigned)y>=IH) continue;
    #pragma unroll
    for (int j=0;j<3;j++){
      int x2=wx+j-1; if ((unsigned)x2>=IW) continue;
      int tap=i*3+j;
      const uint4 r = *(const uint4*)(in + ((size_t)bb*HW_ + y*IW + x2)*16);
      const uint4 r2 = *(const uint4*)(in + ((size_t)bb*HW_ + y*IW + x2)*16 + 8);
      float vv[16]={bfl(r.x),bfh(r.x),bfl(r.y),bfh(r.y),bfl(r.z),bfh(r.z),bfl(r.w),bfh(r.w),
                    bfl(r2.x),bfh(r2.x),bfl(r2.y),bfh(r2.y),bfl(r2.z),bfh(r2.z),bfl(r2.w),bfh(r2.w)};
      #pragma unroll
      for (int ci=0;ci<16;ci++){
        float v = vv[ci];
        a0 += ws[(cb+0)*144 + ci*9 + tap]*v;
        a1 += ws[(cb+1)*144 + ci*9 + tap]*v;
        a2 += ws[(cb+2)*144 + ci*9 + tap]*v;
        a3 += ws[(cb+3)*144 + ci*9 + tap]*v;
      }
    }
  }
  *(float4*)(out + (size_t)p*16 + cb) = make_float4(a0,a1,a2,a3);
}

// ---------------------------------------------------------------------------
// K6a: prep ada_w -> bf16 Amat[g][row=o*16+r][k'=tap*16+cl], K'=160.
// ---------------------------------------------------------------------------
__global__ __launch_bounds__(256) void ada_prep_k(const float* __restrict__ aw,
                                                  u16* __restrict__ apre){
  int g = blockIdx.y;
  int e = blockIdx.x*256 + threadIdx.x;
  int row = e / 160, kp = e - row*160;
  int tap = kp >> 4, cl = kp & 15;
  int o = row >> 4, r = row & 15;
  float v = 0.f;
  if (tap < 9 && cl < 12)
    v = aw[(((size_t)(g*12+o)*108) + cl*9 + tap)*16 + r];
  apre[(size_t)g*30720 + e] = (u16)f2bf(v);
}

// ---------------------------------------------------------------------------
// K6c: fp32 -> bf16 weight prep (8 matrices)
// ---------------------------------------------------------------------------
__global__ __launch_bounds__(256) void wprep_k(
    const float* __restrict__ s0, const float* __restrict__ s1,
    const float* __restrict__ s2, const float* __restrict__ s3,
    const float* __restrict__ s4, const float* __restrict__ s5,
    const float* __restrict__ s6, const float* __restrict__ s7,
    u16* __restrict__ dst)
{
  const int sz[8]  = {27648,18432,18432,18432,9216,18432,18432,36864};
  const int off[8] = {0,27648,46080,66048,84480,93696,112128,130560};
  int m = blockIdx.y;
  int i = blockIdx.x*256 + threadIdx.x;
  const float* s = (m==0)?s0:(m==1)?s1:(m==2)?s2:(m==3)?s3:(m==4)?s4:(m==5)?s5:(m==6)?s6:s7;
  if (i < sz[m]) dst[off[m]+i] = (u16)f2bf(s[i]);
}

// ---------------------------------------------------------------------------
// K6d: P1eff[o][ci] = sum_k p1w[o][k] * c2w[k][ci]  (16x96, K=192) -> bf16
// ---------------------------------------------------------------------------
__global__ __launch_bounds__(256) void p1eff_k(const float* __restrict__ p1w,
                                               const float* __restrict__ c2w,
                                               u16* __restrict__ dst){
  int i = blockIdx.x*256 + threadIdx.x;
  if (i >= 1536) return;
  int o = i/96, ci = i - o*96;
  float s = 0.f;
  for (int k=0;k<192;k++) s += p1w[o*192+k]*c2w[k*96+ci];
  dst[o*96+ci] = (u16)f2bf(s);
}

// ---------------------------------------------------------------------------
// K6b v7: adaconv MFMA, region-loop (4 regions/block), async-stage pipeline.
// Block: (b, g, 4-region group) = (18,16,2) grid. A-frags in regs (loaded 1x).
// Per region: issue next stage loads -> MFMA current -> write stage -> barrier.
// ---------------------------------------------------------------------------
__global__ __launch_bounds__(256) void adaconv_mfma_k(
    const u16* __restrict__ x2, const float* __restrict__ para,
    const u16* __restrict__ apre, const u16* __restrict__ dw1,
    u16* __restrict__ outb2)
{
  __shared__ __align__(16) unsigned char smem[44032];
  // HB[2]: @0, @8640 (18x10 px x 48B)
  // PS[2]: @17280, @27520 ([2 sub][64][20] f32)
  // OS:    @37760 ([2 sub][64][12] f32)
  float* OS = (float*)(smem + 37760);

  const int tid=threadIdx.x, lane=tid&63, wv=tid>>6;
  const int lr=lane&15, g4=lane>>4;
  const int hi=(lane>>5)&1, lo16=(lane>>4)&1;
  const int b=blockIdx.z, g=blockIdx.y, grp=blockIdx.x;
  const int band=grp/3, cg=grp-band*3;
  const int rh = band<<4;

  // --- A fragments (tap-major K'=160), 15 x 16B per lane from L2 ---
  bf16x8 af[3][5];
  {
    const u16* ag = apre + (size_t)g*30720;
    #pragma unroll
    for (int oo=0;oo<3;oo++){
      const int row=(wv*3+oo)*16+lr;
      #pragma unroll
      for (int ks=0;ks<5;ks++)
        af[oo][ks] = *(const bf16x8*)(ag + row*160 + ks*32 + g4*8);
    }
  }

  const int hy = tid/10, hx = tid - hy*10;       // halo coords (tid<180)
  const int pp = (tid>>2)&63, pq = tid&3;        // para coords

  // prologue: stage region 0 into buf 0
  {
    const int rw0 = (cg<<5);
    if (tid < 180){
      int gy = rh+hy-1, gx = rw0+hx-1;
      uint2 a={0,0}, c={0,0}, d={0,0};
      if ((unsigned)gy<IH && (unsigned)gx<IW){
        const uint2* s2 = (const uint2*)(x2 + ((size_t)b*HW_ + gy*IW + gx)*384 + g*12);
        a=s2[0]; c=s2[1]; d=s2[2];
      }
      *(uint4*)(smem + tid*48)      = make_uint4(a.x,a.y,c.x,c.y);
      *(uint4*)(smem + tid*48 + 16) = make_uint4(d.x,d.y,0,0);
    }
    float* PSb = (float*)(smem + 17280);
    #pragma unroll
    for (int it=0; it<2; ++it){
      int sub = it;
      int gy = rh + (sub<<3) + (pp>>3), gx = rw0 + (pp&7);
      float4 v = *(const float4*)(para + ((size_t)b*HW_+gy*IW+gx)*16 + pq*4);
      *(float4*)&PSb[sub*1280 + pp*20 + pq*4] = v;
    }
  }
  __syncthreads();

  int tapoff[5];
  tapoff[0] = hi ? 48   : 0;
  tapoff[1] = hi ? 480  : 96;
  tapoff[2] = hi ? 576  : 528;
  tapoff[3] = hi ? 1008 : 960;
  tapoff[4] = 1056;

  #pragma unroll 1
  for (int r=0; r<4; ++r){
    const int rw = (cg<<5) + (r<<3);
    const int bi = r&1;
    unsigned char* HBb = smem + bi*8640;
    float* PSb = (float*)(smem + 17280 + bi*10240);

    // --- issue next region's staging loads (to regs) ---
    uint2 hA={0,0}, hC={0,0}, hD={0,0};
    float4 pL[2];
    const bool pre = (r<3);
    if (pre){
      const int rwn = rw + 8;
      if (tid<180){
        int gy = rh+hy-1, gx = rwn+hx-1;
        if ((unsigned)gy<IH && (unsigned)gx<IW){
          const uint2* s2 = (const uint2*)(x2 + ((size_t)b*HW_ + gy*IW + gx)*384 + g*12);
          hA=s2[0]; hC=s2[1]; hD=s2[2];
        }
      }
      #pragma unroll
      for (int it=0; it<2; ++it){
        int gy = rh + (it<<3) + (pp>>3), gx = rwn + (pp&7);
        pL[it] = *(const float4*)(para + ((size_t)b*HW_+gy*IW+gx)*16 + pq*4);
      }
    }

    // --- compute both subtiles from buf bi ---
    #pragma unroll
    for (int sub=0; sub<2; ++sub){
      const int sy = sub<<3;
      const int base0 = ((sy + (lr>>3))*10 + (lr&7))*48 + lo16*16;

      f32x4 acc[3][4];
      #pragma unroll
      for (int oo=0;oo<3;oo++)
        #pragma unroll
        for (int n=0;n<4;n++) acc[oo][n]=(f32x4){0.f,0.f,0.f,0.f};

      #pragma unroll
      for (int ks=0;ks<5;ks++){
        bf16x8 bfr[4];
        #pragma unroll
        for (int n=0;n<4;n++)
          bfr[n] = *(const bf16x8*)(HBb + base0 + n*960 + tapoff[ks]);
        #pragma unroll
        for (int oo=0;oo<3;oo++)
          #pragma unroll
          for (int n=0;n<4;n++)
            acc[oo][n]=__builtin_amdgcn_mfma_f32_16x16x32_bf16(af[oo][ks], bfr[n], acc[oo][n],0,0,0);
      }

      const float* ps = &PSb[sub*1280];
      #pragma unroll
      for (int oo=0;oo<3;oo++){
        const int o=wv*3+oo;
        #pragma unroll
        for (int n=0;n<4;n++){
          const int p=(n<<4)+lr;
          const f32x4 prv = *(const f32x4*)&ps[p*20+(g4<<2)];
          float s=acc[oo][n].x*prv.x+acc[oo][n].y*prv.y+acc[oo][n].z*prv.z+acc[oo][n].w*prv.w;
          s += __shfl_xor(s,16); s += __shfl_xor(s,32);
          if (g4==n) OS[((sub<<6)+p)*12+o] = gelu_f(s);
        }
      }
    }

    // --- write the staged regs into the other buffer ---
    if (pre){
      unsigned char* HBn = smem + (bi^1)*8640;
      float* PSn = (float*)(smem + 17280 + (bi^1)*10240);
      if (tid<180){
        *(uint4*)(HBn + tid*48)      = make_uint4(hA.x,hA.y,hC.x,hC.y);
        *(uint4*)(HBn + tid*48 + 16) = make_uint4(hD.x,hD.y,0,0);
      }
      #pragma unroll
      for (int it=0; it<2; ++it)
        *(float4*)&PSn[it*1280 + pp*20 + pq*4] = pL[it];
    }
    __syncthreads();

    // --- coalesced b1-multiply + write from OS ---
    {
      const size_t gb = (size_t)b*HW_;
      for (int idx=tid; idx<384; idx+=256){
        const int cq = idx % 3;
        const int rest = idx / 3;
        const int p = rest & 63, sub = rest >> 6;
        const int py = p>>3, px = p&7;
        const size_t gi = (gb + (rh+(sub<<3)+py)*IW + (rw+px))*192 + g*12 + cq*4;
        const uint2 d = *(const uint2*)(dw1 + gi);
        const float* os = &OS[((sub<<6)+p)*12 + cq*4];
        uint2 pk;
        pk.x = f2bf(os[0]*bfl(d.x)) | (f2bf(os[1]*bfh(d.x))<<16);
        pk.y = f2bf(os[2]*bfl(d.y)) | (f2bf(os[3]*bfh(d.y))<<16);
        *(uint2*)(outb2 + gi) = pk;
      }
    }
    __syncthreads();
  }
}

// ---------------------------------------------------------------------------
// K7: shifted-window attention, 1 wave per (window, head). bf16 in/out.
// ---------------------------------------------------------------------------
__global__ __launch_bounds__(64) void attn_k(const u16* __restrict__ qkv,
                                             const float* __restrict__ relpos,
                                             u16* __restrict__ outa){
  __shared__ float k_s[2048];
  __shared__ float v_s[2048];
  __shared__ float rel_s[225];
  const int win = blockIdx.x, head = blockIdx.y, b = blockIdx.z;
  const int wi = win/12, wj = win%12;
  const int lane = threadIdx.x;
  for (int i=lane;i<225;i+=64) rel_s[i] = relpos[i*3+head];
  const int pi = lane>>3, pj = lane&7;
  const int hr = wi*8+pi, wr = wj*8+pj;
  const int sh = (hr+4)%96, sw = (wr+4)%96;
  const size_t pix = (size_t)b*HW_ + sh*96 + sw;
  const u16* base = qkv + pix*288;
  const float SC = 0.17677669529663687f;
  float q[32];
  #pragma unroll
  for (int i=0;i<4;i++){
    const uint4 r = *(const uint4*)(base + head*32 + i*8);
    q[i*8+0]=bfl(r.x)*SC; q[i*8+1]=bfh(r.x)*SC;
    q[i*8+2]=bfl(r.y)*SC; q[i*8+3]=bfh(r.y)*SC;
    q[i*8+4]=bfl(r.z)*SC; q[i*8+5]=bfh(r.z)*SC;
    q[i*8+6]=bfl(r.w)*SC; q[i*8+7]=bfh(r.w)*SC;
  }
  #pragma unroll
  for (int i=0;i<4;i++){
    const uint4 rk = *(const uint4*)(base + 96 + head*32 + i*8);
    const uint4 rv = *(const uint4*)(base + 192 + head*32 + i*8);
    *(float4*)&k_s[(lane<<5)+i*8]   = make_float4(bfl(rk.x),bfh(rk.x),bfl(rk.y),bfh(rk.y));
    *(float4*)&k_s[(lane<<5)+i*8+4] = make_float4(bfl(rk.z),bfh(rk.z),bfl(rk.w),bfh(rk.w));
    *(float4*)&v_s[(lane<<5)+i*8]   = make_float4(bfl(rv.x),bfh(rv.x),bfl(rv.y),bfh(rv.y));
    *(float4*)&v_s[(lane<<5)+i*8+4] = make_float4(bfl(rv.z),bfh(rv.z),bfl(rv.w),bfh(rv.w));
  }
  __syncthreads();
  const bool mi = (wi==11), mj = (wj==11);
  float sc[64];
  #pragma unroll
  for (int qq=0; qq<64; qq++){
    const float4* kr4 = (const float4*)&k_s[qq<<5];
    float s = 0.f;
    #pragma unroll
    for (int i=0;i<8;i++){
      const float4 kv = kr4[i];
      s += q[4*i]*kv.x + q[4*i+1]*kv.y + q[4*i+2]*kv.z + q[4*i+3]*kv.w;
    }
    const int qi = qq>>3, qj = qq&7;
    s += rel_s[(pi-qi+7)*15 + (pj-qj+7)];
    const bool msk = (mi && ((pi<4)!=(qi<4))) || (mj && ((pj<4)!=(qj<4)));
    sc[qq] = msk ? -1e30f : s;
  }
  float m = sc[0];
  #pragma unroll
  for (int qq=1;qq<64;qq++) m = fmaxf(m, sc[qq]);
  float sum = 0.f;
  #pragma unroll
  for (int qq=0;qq<64;qq++){ float e = __expf(sc[qq]-m); sc[qq]=e; sum+=e; }
  const float inv = 1.f/sum;
  float acc[32];
  #pragma unroll
  for (int i=0;i<32;i++) acc[i]=0.f;
  #pragma unroll
  for (int qq=0;qq<64;qq++){
    const float a = sc[qq]*inv;
    const float4* vr4 = (const float4*)&v_s[qq<<5];
    #pragma unroll
    for (int i=0;i<8;i++){
      const float4 vv = vr4[i];
      acc[4*i]+=a*vv.x; acc[4*i+1]+=a*vv.y; acc[4*i+2]+=a*vv.z; acc[4*i+3]+=a*vv.w;
    }
  }
  u16* orow = outa + pix*96 + head*32;
  #pragma unroll
  for (int i=0;i<4;i++){
    uint4 pk;
    pk.x = f2bf(acc[i*8+0])|(f2bf(acc[i*8+1])<<16);
    pk.y = f2bf(acc[i*8+2])|(f2bf(acc[i*8+3])<<16);
    pk.z = f2bf(acc[i*8+4])|(f2bf(acc[i*8+5])<<16);
    pk.w = f2bf(acc[i*8+6])|(f2bf(acc[i*8+7])<<16);
    *(uint4*)(orow + i*8) = pk;
  }
}

// ---------------------------------------------------------------------------
extern "C" void kernel_launch(void* const* d_in, const int* in_sizes, int n_in,
                              void* d_out, int out_size, void* d_ws, size_t ws_size,
                              hipStream_t stream)
{
  (void)in_sizes; (void)n_in; (void)out_size; (void)ws_size;
  const float* x        = (const float*)d_in[0];
  const float* cb_ln_g  = (const float*)d_in[1];
  const float* cb_ln_b  = (const float*)d_in[2];
  const float* cb_c1_pw = (const float*)d_in[3];
  const float* cb_c1_dw = (const float*)d_in[4];
  const float* cb_c2_pw = (const float*)d_in[5];
  const float* ada_w    = (const float*)d_in[6];
  const float* ada_p1_w = (const float*)d_in[7];
  const float* ada_p1_b = (const float*)d_in[8];
  const float* ada_p2_w = (const float*)d_in[9];
  const float* ada_p2_b = (const float*)d_in[10];
  const float* cb_c3_w  = (const float*)d_in[11];
  const float* ln1_g    = (const float*)d_in[12];
  const float* ln1_b    = (const float*)d_in[13];
  const float* qkv_w    = (const float*)d_in[14];
  const float* qkv_b    = (const float*)d_in[15];
  const float* rel_pos  = (const float*)d_in[16];
  const float* proj_w   = (const float*)d_in[17];
  const float* proj_b   = (const float*)d_in[18];
  const float* ln2_g    = (const float*)d_in[19];
  const float* ln2_b    = (const float*)d_in[20];
  const float* ffn_w1   = (const float*)d_in[21];
  const float* ffn_b1   = (const float*)d_in[22];
  const float* ffn_dw   = (const float*)d_in[23];
  const float* ffn_db   = (const float*)d_in[24];
  const float* ffn_w2   = (const float*)d_in[25];
  const float* ffn_b2   = (const float*)d_in[26];
  const float* out_w    = (const float*)d_in[27];
  const float* out_b    = (const float*)d_in[28];

  char* wsb = (char*)d_ws;
  // fp32 regions
  float* XC  = (float*)wsb;                                   // ST*96  raw conv residual
  float* U0f = (float*)(wsb + (size_t)ST*96*4);               // ST*288 f32 overlay region
  float* XT  = (float*)(wsb + (size_t)ST*384*4);              // ST*96  transformer residual
  float* PA2 = (float*)(wsb + (size_t)ST*480*4);              // ST*16
  // u16 regions
  u16* B2b  = (u16*)(wsb + (size_t)ST*496*4);                 // ST*192
  u16* LNCb = B2b  + (size_t)ST*192;                          // ST*96
  u16* R4b  = LNCb + (size_t)ST*96;                           // ST*96
  u16* R6b  = R4b  + (size_t)ST*96;                           // ST*96
  u16* PA1b = R6b  + (size_t)ST*96;                           // ST*16
  u16* Wbf  = PA1b + (size_t)ST*16;                           // 167424
  u16* Apre = Wbf + 167424;                                   // 491520
  // overlays on U0f (ST*288 f32 = ST*576 u16)
  u16* X12b = (u16*)U0f;                     // ST*384 u16 (c12 out, stride 384)
  u16* DWb  = (u16*)U0f + (size_t)ST*384;    // ST*192 u16 (dw1 out)
  u16* QKVb = (u16*)U0f;                     // ST*288 u16 (after conv branch dead)
  u16* FF1b = (u16*)U0f;                     // ST*192 u16 (after QKV dead)
  u16* DWOb = (u16*)U0f + (size_t)ST*192;

  const u16* W_qkv  = Wbf + 0;
  const u16* W_c12p = Wbf + 27648;   // [400][96]: c1, c2, P1eff
  const u16* W_c3   = Wbf + 66048;
  const u16* W_proj = Wbf + 84480;
  const u16* W_ffn1 = Wbf + 93696;
  const u16* W_ffn2 = Wbf + 112128;
  const u16* W_fin  = Wbf + 130560;

  // weight preps
  wprep_k<<<dim3(144, 8), 256, 0, stream>>>(qkv_w, cb_c1_pw, cb_c2_pw, cb_c3_w,
                                            proj_w, ffn_w1, ffn_w2, out_w, Wbf);
  p1eff_k<<<6, 256, 0, stream>>>(ada_p1_w, cb_c2_pw, Wbf + 64512);
  ada_prep_k<<<dim3(120, 16), 256, 0, stream>>>(ada_w, Apre);

  // fused dual LN from NCHW x
  ln12_k<<<ST/32, 256, 0, stream>>>(x, cb_ln_g, cb_ln_b, ln1_g, ln1_b, LNCb, R6b, XC, XT);

  // conv branch: fused c1+c2+p1eff: 96 -> 400 (0-191 c1, 192-383 c2, 384-399 p1)
  conv_mfma_k<0,false,false,false,false,true,true><<<dim3(ST/128, 7), 256, 0, stream>>>(LNCb, nullptr, 96, W_c12p, ada_p1_b, nullptr, 0, X12b, 384, 96, 400, PA1b);
  dw3x3_k<false,false><<<(ST*24)/256, 256, 0, stream>>>(X12b, 384, cb_c1_dw, nullptr, DWb, 192);
  p2conv_k<<<(ST*4)/256, 256, 0, stream>>>(PA1b, ada_p2_w, ada_p2_b, PA2);
  adaconv_mfma_k<<<dim3(18, 16, NB), 256, 0, stream>>>(X12b+192, PA2, Apre, DWb, B2b);
  conv_mfma_k<0,false,false,false,true,true,false><<<dim3(ST/128, 2), 256, 0, stream>>>(B2b, nullptr, 192, W_c3, nullptr, XC, 96, R4b, 96, 192, 96, nullptr);

  // transformer branch
  conv_mfma_k<0,false,false,true,false,true,false><<<dim3(ST/128, 5), 256, 0, stream>>>(R6b, nullptr, 96, W_qkv, qkv_b, nullptr, 0, QKVb, 288, 96, 288, nullptr);
  attn_k<<<dim3(144, 3, NB), 64, 0, stream>>>(QKVb, rel_pos, R6b);
  conv_mfma_k<0,false,false,true,true,false,false><<<dim3(ST/128, 2), 256, 0, stream>>>(R6b, nullptr, 96, W_proj, proj_b, XT, 96, XT, 96, 96, 96, nullptr);
  ln_k<<<ST/4, 256, 0, stream>>>(XT, 96, ln2_g, ln2_b, R6b);
  conv_mfma_k<0,false,false,true,false,true,false><<<dim3(ST/128, 3), 256, 0, stream>>>(R6b, nullptr, 96, W_ffn1, ffn_b1, nullptr, 0, FF1b, 192, 96, 192, nullptr);
  dw3x3_k<true,true><<<(ST*24)/256, 256, 0, stream>>>(FF1b, 192, ffn_dw, ffn_db, DWOb, 192);
  conv_mfma_k<0,false,false,true,true,false,false><<<dim3(ST/128, 2), 256, 0, stream>>>(DWOb, nullptr, 192, W_ffn2, ffn_b2, XT, 96, XT, 96, 192, 96, nullptr);

  // fuse: out = x + conv1x1(concat(convout bf16, xt f32), out_w) + out_b
  conv_mfma_k<0,true,true,true,true,false,false><<<dim3(ST/128, 3), 256, 0, stream>>>(R4b, XT, 96, W_fin, out_b, x, 0, (float*)d_out, 0, 192, 192, nullptr);
}

// Round 9
// 259.875 us; speedup vs baseline: 1.1052x; 1.1052x over previous
//
#include <hip/hip_runtime.h>
#include <math.h>

#define HW_ 9216
#define IH 96
#define IW 96
#define NB 2
#define ST (NB*HW_)   // 18432 pixels total

typedef __attribute__((ext_vector_type(8))) short bf16x8;
typedef __attribute__((ext_vector_type(4))) float f32x4;
typedef unsigned short u16;

__device__ __forceinline__ float gelu_f(float v){
  return 0.5f*v*(1.0f+erff(v*0.70710678118654752440f));
}
__device__ __forceinline__ unsigned f2bf(float f){
  unsigned u = __float_as_uint(f);
  return (u + 0x7FFF + ((u>>16)&1)) >> 16;
}
__device__ __forceinline__ float bfl(unsigned u){ return __uint_as_float(u<<16); }
__device__ __forceinline__ float bfh(unsigned u){ return __uint_as_float(u & 0xffff0000u); }

// ---------------------------------------------------------------------------
// K2: fused dual LayerNorm from NCHW input. Block: 32 px x 192 ch via LDS.
// ---------------------------------------------------------------------------
__global__ __launch_bounds__(256) void ln12_k(const float* __restrict__ x,
    const float* __restrict__ g1, const float* __restrict__ b1,
    const float* __restrict__ g2, const float* __restrict__ b2,
    u16* __restrict__ lnc, u16* __restrict__ ln1o,
    float* __restrict__ xc, float* __restrict__ xt)
{
  __shared__ float t[192][33];
  const int p0 = blockIdx.x<<5;
  const int bb = p0/HW_, hw0 = p0 - bb*HW_;
  const int tid = threadIdx.x;
  const int px = tid & 31, cr = tid >> 5;
  const float* xb = x + (size_t)bb*192*HW_ + hw0;
  #pragma unroll
  for (int k=0;k<24;k++){
    int c = cr + k*8;
    t[c][px] = xb[(size_t)c*HW_ + px];
  }
  __syncthreads();
  const int lane = tid&63, wv = tid>>6;
  #pragma unroll 1
  for (int i=0;i<8;i++){
    const int lp = wv*8+i;
    const size_t p = p0 + lp;
    float a0 = t[lane][lp];
    float a1 = (lane<32)? t[64+lane][lp] : 0.f;
    float c0 = t[96+lane][lp];
    float c1 = (lane<32)? t[160+lane][lp] : 0.f;
    float s1=a0+a1, s2=c0+c1;
    #pragma unroll
    for (int o=32;o;o>>=1){ s1+=__shfl_xor(s1,o); s2+=__shfl_xor(s2,o); }
    const float mu1=s1*(1.f/96.f), mu2=s2*(1.f/96.f);
    const float d0=a0-mu1, d1=a1-mu1, e0=c0-mu2, e1=c1-mu2;
    float q1=d0*d0+((lane<32)?d1*d1:0.f), q2=e0*e0+((lane<32)?e1*e1:0.f);
    #pragma unroll
    for (int o=32;o;o>>=1){ q1+=__shfl_xor(q1,o); q2+=__shfl_xor(q2,o); }
    const float r1=rsqrtf(q1*(1.f/96.f)+1e-5f), r2=rsqrtf(q2*(1.f/96.f)+1e-5f);
    lnc [p*96+lane] = (u16)f2bf(d0*r1*g1[lane]+b1[lane]);
    ln1o[p*96+lane] = (u16)f2bf(e0*r2*g2[lane]+b2[lane]);
    xc  [p*96+lane] = a0;
    xt  [p*96+lane] = c0;
    if (lane<32){
      lnc [p*96+64+lane] = (u16)f2bf(d1*r1*g1[64+lane]+b1[64+lane]);
      ln1o[p*96+64+lane] = (u16)f2bf(e1*r2*g2[64+lane]+b2[64+lane]);
      xc  [p*96+64+lane] = a1;
      xt  [p*96+64+lane] = c1;
    }
  }
}

// ---------------------------------------------------------------------------
// K2b: single LayerNorm (fp32 in, bf16 out) — ln2.
// ---------------------------------------------------------------------------
__global__ __launch_bounds__(256) void ln_k(const float* __restrict__ in, int istride,
                                            const float* __restrict__ gam, const float* __restrict__ bet,
                                            u16* __restrict__ out){
  int lane = threadIdx.x & 63;
  int wv   = threadIdx.x >> 6;
  int p    = (blockIdx.x << 2) + wv;
  const float* row = in + (size_t)p*istride;
  float v0 = row[lane];
  float v1 = (lane < 32) ? row[64+lane] : 0.0f;
  float s = v0 + v1;
  #pragma unroll
  for (int o=32;o;o>>=1) s += __shfl_xor(s,o);
  float mu = s * (1.0f/96.0f);
  float d0 = v0 - mu;
  float d1 = v1 - mu;
  float qv = d0*d0 + ((lane<32)? d1*d1 : 0.0f);
  #pragma unroll
  for (int o=32;o;o>>=1) qv += __shfl_xor(qv,o);
  float rstd = rsqrtf(qv*(1.0f/96.0f) + 1e-5f);
  u16* orow = out + (size_t)p*96;
  orow[lane] = (u16)f2bf(d0*rstd*gam[lane] + bet[lane]);
  if (lane < 32) orow[64+lane] = (u16)f2bf(d1*rstd*gam[64+lane] + bet[64+lane]);
}

// ---------------------------------------------------------------------------
// K3b: bf16-MFMA conv1x1.  Block: 128 px x 64 couts, 4 waves (2M x 2N).
// SPLIT: couts >=384 get bias(=p1 bias)+relu and go to out2 (stride 16, bf16).
// ---------------------------------------------------------------------------
template<int ACT, bool CONCAT, bool FINAL, bool HASB, bool HASR, bool OUTBF, bool SPLIT>
__global__ __launch_bounds__(256) void conv_mfma_k(
    const u16* __restrict__ in1, const float* __restrict__ in2f, int istride,
    const u16* __restrict__ wbf, const float* __restrict__ bias,
    const float* __restrict__ res, int rstride,
    void* __restrict__ out, int ostride, int Cin, int Cout,
    u16* __restrict__ out2)
{
  __shared__ __align__(16) unsigned char smem[39936];
  unsigned char* actl = smem;          // [128][208B]
  unsigned char* wl   = smem + 26624;  // [64][208B]
  const int tid=threadIdx.x, lane=tid&63, wv=tid>>6;
  const int lr=lane&15, g4=lane>>4, wm=wv>>1, wn=wv&1;
  const int p0=blockIdx.x<<7, co0=blockIdx.y<<6;

  f32x4 acc[2][4];
  #pragma unroll
  for (int m=0;m<2;m++)
    #pragma unroll
    for (int n=0;n<4;n++) acc[m][n]=(f32x4){0.f,0.f,0.f,0.f};

  for (int kc=0; kc<Cin; kc+=96){
    {
      const int row=tid>>1, half=tid&1;
      if (!CONCAT || kc==0){
        const u16* rp = in1 + (size_t)(p0+row)*istride + (CONCAT?0:kc) + half*48;
        #pragma unroll
        for (int s=0;s<6;s++)
          *(uint4*)(actl + row*208 + (half*6+s)*16) = *(const uint4*)(rp + s*8);
      } else {
        const float* rp = in2f + (size_t)(p0+row)*96 + half*48;
        #pragma unroll
        for (int s=0;s<6;s++){
          float4 a=*(const float4*)(rp+s*8), b=*(const float4*)(rp+s*8+4);
          uint4 pk;
          pk.x=f2bf(a.x)|(f2bf(a.y)<<16);
          pk.y=f2bf(a.z)|(f2bf(a.w)<<16);
          pk.z=f2bf(b.x)|(f2bf(b.y)<<16);
          pk.w=f2bf(b.z)|(f2bf(b.w)<<16);
          *(uint4*)(actl + row*208 + (half*6+s)*16) = pk;
        }
      }
    }
    {
      const int row=tid&63, grp=tid>>6;
      const int co=co0+row;
      const u16* wr = wbf + (size_t)co*Cin + kc;
      #pragma unroll
      for (int s=0;s<3;s++){
        int sl=grp*3+s;
        uint4 v={0,0,0,0};
        if (co<Cout) v=*(const uint4*)(wr + sl*8);
        *(uint4*)(wl + row*208 + sl*16)=v;
      }
    }
    __syncthreads();
    #pragma unroll
    for (int ks=0;ks<3;ks++){
      const int sl=ks*4+g4;
      bf16x8 afr[2], bfr[4];
      #pragma unroll
      for (int m=0;m<2;m++) afr[m]=*(const bf16x8*)(wl + ((wm*2+m)*16+lr)*208 + sl*16);
      #pragma unroll
      for (int n=0;n<4;n++) bfr[n]=*(const bf16x8*)(actl + (wn*64+n*16+lr)*208 + sl*16);
      #pragma unroll
      for (int m=0;m<2;m++)
        #pragma unroll
        for (int n=0;n<4;n++)
          acc[m][n]=__builtin_amdgcn_mfma_f32_16x16x32_bf16(afr[m], bfr[n], acc[m][n],0,0,0);
    }
    __syncthreads();
  }

  if (FINAL){
    float* outf = (float*)out;
    #pragma unroll
    for (int m=0;m<2;m++){
      const int cb=co0+(wm*2+m)*16+(g4<<2);
      float4 bv = make_float4(0.f,0.f,0.f,0.f);
      if (HASB) bv = *(const float4*)(bias+cb);
      #pragma unroll
      for (int n=0;n<4;n++){
        const int p=p0+wn*64+n*16+lr;
        const int bb=p/HW_, hw=p-bb*HW_;
        const float av[4]={acc[m][n].x,acc[m][n].y,acc[m][n].z,acc[m][n].w};
        const float bvv[4]={bv.x,bv.y,bv.z,bv.w};
        #pragma unroll
        for (int j=0;j<4;j++){
          size_t oi=((size_t)bb*192+cb+j)*HW_+hw;
          outf[oi]=av[j]+bvv[j]+res[oi];
        }
      }
    }
    return;
  }
  float* lt=(float*)smem;
  #pragma unroll
  for (int m=0;m<2;m++)
    #pragma unroll
    for (int n=0;n<4;n++){
      int px=wn*64+n*16+lr;
      int c=(wm*2+m)*16+(g4<<2);
      *(f32x4*)&lt[px*68+c]=acc[m][n];
    }
  __syncthreads();
  {
    const int pr=tid>>1, half=tid&1;
    const int p=p0+pr;
    #pragma unroll
    for (int s=0;s<8;s++){
      int cl=half*32+s*4;
      int co=co0+cl;
      if (co<Cout){
        float4 v=*(float4*)&lt[pr*68+cl];
        if (SPLIT && co>=384){
          const int c2 = co-384;
          const float4 bv=*(const float4*)(bias+c2);
          v.x=fmaxf(v.x+bv.x,0.f); v.y=fmaxf(v.y+bv.y,0.f);
          v.z=fmaxf(v.z+bv.z,0.f); v.w=fmaxf(v.w+bv.w,0.f);
          uint2 pk;
          pk.x = f2bf(v.x)|(f2bf(v.y)<<16);
          pk.y = f2bf(v.z)|(f2bf(v.w)<<16);
          *(uint2*)(out2 + (size_t)p*16 + c2) = pk;
          continue;
        }
        if (HASB){ const float4 bv=*(const float4*)(bias+co); v.x+=bv.x;v.y+=bv.y;v.z+=bv.z;v.w+=bv.w; }
        if (ACT==1){
          v.x=fmaxf(v.x,0.f); v.y=fmaxf(v.y,0.f); v.z=fmaxf(v.z,0.f); v.w=fmaxf(v.w,0.f);
        }
        if (HASR){ const float4 rv=*(const float4*)(res+(size_t)p*rstride+co); v.x+=rv.x;v.y+=rv.y;v.z+=rv.z;v.w+=rv.w; }
        if (OUTBF){
          uint2 pk;
          pk.x = f2bf(v.x)|(f2bf(v.y)<<16);
          pk.y = f2bf(v.z)|(f2bf(v.w)<<16);
          *(uint2*)((u16*)out + (size_t)p*ostride + co) = pk;
        } else {
          *(float4*)((float*)out + (size_t)p*ostride + co) = v;
        }
      }
    }
  }
}

// ---------------------------------------------------------------------------
// K4: depthwise 3x3, bf16 in/out, 4 ch/thread (uint2 I/O) — R6 proven version.
// ---------------------------------------------------------------------------
template<bool HASB, bool DOGELU>
__global__ __launch_bounds__(256) void dw3x3_k(const u16* __restrict__ in, int istride,
                                               const float* __restrict__ w,
                                               const float* __restrict__ bias,
                                               u16* __restrict__ out, int C){
  int t = blockIdx.x*256 + threadIdx.x;
  int cg = C >> 2;
  int p = t / cg;
  if (p >= ST) return;
  int c4 = (t - p*cg) << 2;
  int bb = p / HW_, hw = p - bb*HW_;
  int hy = hw / IW, wx = hw - hy*IW;
  float w0[9], w1[9], w2[9], w3[9];
  #pragma unroll
  for (int tp=0;tp<9;tp++){
    w0[tp]=w[(c4+0)*9+tp]; w1[tp]=w[(c4+1)*9+tp]; w2[tp]=w[(c4+2)*9+tp]; w3[tp]=w[(c4+3)*9+tp];
  }
  float ax=0.f, ay=0.f, az=0.f, aw=0.f;
  #pragma unroll
  for (int i=0;i<3;i++){
    int y = hy+i-1;
    if ((unsigned)y >= IH) continue;
    #pragma unroll
    for (int j=0;j<3;j++){
      int x2 = wx+j-1;
      if ((unsigned)x2 >= IW) continue;
      const uint2 r = *(const uint2*)(in + ((size_t)bb*HW_ + y*IW + x2)*istride + c4);
      int tp=i*3+j;
      ax += bfl(r.x)*w0[tp]; ay += bfh(r.x)*w1[tp];
      az += bfl(r.y)*w2[tp]; aw += bfh(r.y)*w3[tp];
    }
  }
  if (HASB){ ax+=bias[c4]; ay+=bias[c4+1]; az+=bias[c4+2]; aw+=bias[c4+3]; }
  if (DOGELU){ ax=gelu_f(ax); ay=gelu_f(ay); az=gelu_f(az); aw=gelu_f(aw); }
  uint2 pk;
  pk.x = f2bf(ax)|(f2bf(ay)<<16);
  pk.y = f2bf(az)|(f2bf(aw)<<16);
  *(uint2*)(out + (size_t)p*C + c4) = pk;
}

// ---------------------------------------------------------------------------
// K5: full 3x3 conv 16->16 (para branch), bf16 in / fp32 out. 4 thr/px.
// ---------------------------------------------------------------------------
__global__ __launch_bounds__(256) void p2conv_k(const u16* __restrict__ in, const float* __restrict__ w,
                                                const float* __restrict__ bias, float* __restrict__ out){
  __shared__ float ws[2304];
  int tid = threadIdx.x;
  for (int i=tid;i<2304;i+=256) ws[i]=w[i];
  __syncthreads();
  int gidx = blockIdx.x*256 + tid;
  int p = gidx >> 2, qq = gidx & 3;
  int bb = p / HW_, hw = p - bb*HW_;
  int hy = hw / IW, wx = hw - hy*IW;
  const int cb = qq<<2;
  float a0=bias[cb], a1=bias[cb+1], a2=bias[cb+2], a3=bias[cb+3];
  #pragma unroll
  for (int i=0;i<3;i++){
    int y=hy+i-1; if ((unsigned)y>=IH) continue;
    #pragma unroll
    for (int j=0;j<3;j++){
      int x2=wx+j-1; if ((unsigned)x2>=IW) continue;
      int tap=i*3+j;
      const uint4 r = *(const uint4*)(in + ((size_t)bb*HW_ + y*IW + x2)*16);
      const uint4 r2 = *(const uint4*)(in + ((size_t)bb*HW_ + y*IW + x2)*16 + 8);
      float vv[16]={bfl(r.x),bfh(r.x),bfl(r.y),bfh(r.y),bfl(r.z),bfh(r.z),bfl(r.w),bfh(r.w),
                    bfl(r2.x),bfh(r2.x),bfl(r2.y),bfh(r2.y),bfl(r2.z),bfh(r2.z),bfl(r2.w),bfh(r2.w)};
      #pragma unroll
      for (int ci=0;ci<16;ci++){
        float v = vv[ci];
        a0 += ws[(cb+0)*144 + ci*9 + tap]*v;
        a1 += ws[(cb+1)*144 + ci*9 + tap]*v;
        a2 += ws[(cb+2)*144 + ci*9 + tap]*v;
        a3 += ws[(cb+3)*144 + ci*9 + tap]*v;
      }
    }
  }
  *(float4*)(out + (size_t)p*16 + cb) = make_float4(a0,a1,a2,a3);
}

// ---------------------------------------------------------------------------
// K6a: prep ada_w -> bf16 Amat[g][row=o*16+r][k'=tap*16+cl], K'=160.
// ---------------------------------------------------------------------------
__global__ __launch_bounds__(256) void ada_prep_k(const float* __restrict__ aw,
                                                  u16* __restrict__ apre){
  int g = blockIdx.y;
  int e = blockIdx.x*256 + threadIdx.x;
  int row = e / 160, kp = e - row*160;
  int tap = kp >> 4, cl = kp & 15;
  int o = row >> 4, r = row & 15;
  float v = 0.f;
  if (tap < 9 && cl < 12)
    v = aw[(((size_t)(g*12+o)*108) + cl*9 + tap)*16 + r];
  apre[(size_t)g*30720 + e] = (u16)f2bf(v);
}

// ---------------------------------------------------------------------------
// K6c: fp32 -> bf16 weight prep (8 matrices)
// ---------------------------------------------------------------------------
__global__ __launch_bounds__(256) void wprep_k(
    const float* __restrict__ s0, const float* __restrict__ s1,
    const float* __restrict__ s2, const float* __restrict__ s3,
    const float* __restrict__ s4, const float* __restrict__ s5,
    const float* __restrict__ s6, const float* __restrict__ s7,
    u16* __restrict__ dst)
{
  const int sz[8]  = {27648,18432,18432,18432,9216,18432,18432,36864};
  const int off[8] = {0,27648,46080,66048,84480,93696,112128,130560};
  int m = blockIdx.y;
  int i = blockIdx.x*256 + threadIdx.x;
  const float* s = (m==0)?s0:(m==1)?s1:(m==2)?s2:(m==3)?s3:(m==4)?s4:(m==5)?s5:(m==6)?s6:s7;
  if (i < sz[m]) dst[off[m]+i] = (u16)f2bf(s[i]);
}

// ---------------------------------------------------------------------------
// K6d: P1eff[o][ci] = sum_k p1w[o][k] * c2w[k][ci]  (16x96, K=192) -> bf16
// ---------------------------------------------------------------------------
__global__ __launch_bounds__(256) void p1eff_k(const float* __restrict__ p1w,
                                               const float* __restrict__ c2w,
                                               u16* __restrict__ dst){
  int i = blockIdx.x*256 + threadIdx.x;
  if (i >= 1536) return;
  int o = i/96, ci = i - o*96;
  float s = 0.f;
  for (int k=0;k<192;k++) s += p1w[o*192+k]*c2w[k*96+ci];
  dst[o*96+ci] = (u16)f2bf(s);
}

// ---------------------------------------------------------------------------
// K6b v6 (reverted, measured-best): adaconv MFMA, bf16 in/out.
// Block: (b, g, 16x8 region) = 2304 blocks. LDS-collected coalesced epilogue.
// ---------------------------------------------------------------------------
__global__ __launch_bounds__(256) void adaconv_mfma_k(
    const u16* __restrict__ x2, const float* __restrict__ para,
    const u16* __restrict__ apre, const u16* __restrict__ dw1,
    u16* __restrict__ outb2)
{
  __shared__ __align__(16) unsigned char smem[25024];
  unsigned char* HB = smem;             // 18 rows x 10 cols x 48B = 8640
  float* PS = (float*)(smem + 8640);    // [2 sub][64 px][20] f32 = 10240
  float* OS = (float*)(smem + 18880);   // [2 sub][64 px][12] f32 = 6144

  const int tid=threadIdx.x, lane=tid&63, wv=tid>>6;
  const int lr=lane&15, g4=lane>>4;
  const int hi=(lane>>5)&1, lo16=(lane>>4)&1;
  const int b=blockIdx.z, g=blockIdx.y, reg=blockIdx.x;
  const int rh=(reg/12)<<4, rw=(reg%12)<<3;

  bf16x8 af[3][5];
  {
    const u16* ag = apre + (size_t)g*30720;
    #pragma unroll
    for (int oo=0;oo<3;oo++){
      const int row=(wv*3+oo)*16+lr;
      #pragma unroll
      for (int ks=0;ks<5;ks++)
        af[oo][ks] = *(const bf16x8*)(ag + row*160 + ks*32 + g4*8);
    }
  }
  if (tid < 180){
    int hy = tid/10, hx = tid - hy*10;
    int gy = rh+hy-1, gx = rw+hx-1;
    uint2 a={0,0}, c={0,0}, d={0,0};
    if ((unsigned)gy<IH && (unsigned)gx<IW){
      const uint2* s2 = (const uint2*)(x2 + ((size_t)b*HW_ + gy*IW + gx)*384 + g*12);
      a=s2[0]; c=s2[1]; d=s2[2];
    }
    *(uint4*)(HB + tid*48)      = make_uint4(a.x,a.y,c.x,c.y);
    *(uint4*)(HB + tid*48 + 16) = make_uint4(d.x,d.y,0,0);
  }
  #pragma unroll
  for (int it=0; it<2; ++it){
    int idx = tid + (it<<8);
    int sub = idx >> 8;
    int p = (idx>>2)&63, q = idx&3;
    int gy = rh + (sub<<3) + (p>>3), gx = rw + (p&7);
    float4 v = *(const float4*)(para + ((size_t)b*HW_+gy*IW+gx)*16 + q*4);
    *(float4*)&PS[sub*1280 + p*20 + q*4] = v;
  }
  __syncthreads();

  int tapoff[5];
  tapoff[0] = hi ? 48   : 0;
  tapoff[1] = hi ? 480  : 96;
  tapoff[2] = hi ? 576  : 528;
  tapoff[3] = hi ? 1008 : 960;
  tapoff[4] = 1056;

  #pragma unroll
  for (int sub=0; sub<2; ++sub){
    const int sy = sub<<3;
    const int base0 = ((sy + (lr>>3))*10 + (lr&7))*48 + lo16*16;

    f32x4 acc[3][4];
    #pragma unroll
    for (int oo=0;oo<3;oo++)
      #pragma unroll
      for (int n=0;n<4;n++) acc[oo][n]=(f32x4){0.f,0.f,0.f,0.f};

    #pragma unroll
    for (int ks=0;ks<5;ks++){
      bf16x8 bfr[4];
      #pragma unroll
      for (int n=0;n<4;n++)
        bfr[n] = *(const bf16x8*)(HB + base0 + n*960 + tapoff[ks]);
      #pragma unroll
      for (int oo=0;oo<3;oo++)
        #pragma unroll
        for (int n=0;n<4;n++)
          acc[oo][n]=__builtin_amdgcn_mfma_f32_16x16x32_bf16(af[oo][ks], bfr[n], acc[oo][n],0,0,0);
    }

    const float* ps = &PS[sub*1280];
    #pragma unroll
    for (int oo=0;oo<3;oo++){
      const int o=wv*3+oo;
      #pragma unroll
      for (int n=0;n<4;n++){
        const int p=(n<<4)+lr;
        const f32x4 prv = *(const f32x4*)&ps[p*20+(g4<<2)];
        float s=acc[oo][n].x*prv.x+acc[oo][n].y*prv.y+acc[oo][n].z*prv.z+acc[oo][n].w*prv.w;
        s += __shfl_xor(s,16); s += __shfl_xor(s,32);
        if (g4==n) OS[((sub<<6)+p)*12+o] = gelu_f(s);
      }
    }
  }
  __syncthreads();
  {
    const size_t gb = (size_t)b*HW_;
    for (int idx=tid; idx<384; idx+=256){
      const int cq = idx % 3;
      const int rest = idx / 3;
      const int p = rest & 63, sub = rest >> 6;
      const int py = p>>3, px = p&7;
      const size_t gi = (gb + (rh+(sub<<3)+py)*IW + (rw+px))*192 + g*12 + cq*4;
      const uint2 d = *(const uint2*)(dw1 + gi);
      const float* os = &OS[((sub<<6)+p)*12 + cq*4];
      uint2 pk;
      pk.x = f2bf(os[0]*bfl(d.x)) | (f2bf(os[1]*bfh(d.x))<<16);
      pk.y = f2bf(os[2]*bfl(d.y)) | (f2bf(os[3]*bfh(d.y))<<16);
      *(uint2*)(outb2 + gi) = pk;
    }
  }
}

// ---------------------------------------------------------------------------
// K7: shifted-window attention, 1 wave per (window, head). bf16 in/out.
// ---------------------------------------------------------------------------
__global__ __launch_bounds__(64) void attn_k(const u16* __restrict__ qkv,
                                             const float* __restrict__ relpos,
                                             u16* __restrict__ outa){
  __shared__ float k_s[2048];
  __shared__ float v_s[2048];
  __shared__ float rel_s[225];
  const int win = blockIdx.x, head = blockIdx.y, b = blockIdx.z;
  const int wi = win/12, wj = win%12;
  const int lane = threadIdx.x;
  for (int i=lane;i<225;i+=64) rel_s[i] = relpos[i*3+head];
  const int pi = lane>>3, pj = lane&7;
  const int hr = wi*8+pi, wr = wj*8+pj;
  const int sh = (hr+4)%96, sw = (wr+4)%96;
  const size_t pix = (size_t)b*HW_ + sh*96 + sw;
  const u16* base = qkv + pix*288;
  const float SC = 0.17677669529663687f;
  float q[32];
  #pragma unroll
  for (int i=0;i<4;i++){
    const uint4 r = *(const uint4*)(base + head*32 + i*8);
    q[i*8+0]=bfl(r.x)*SC; q[i*8+1]=bfh(r.x)*SC;
    q[i*8+2]=bfl(r.y)*SC; q[i*8+3]=bfh(r.y)*SC;
    q[i*8+4]=bfl(r.z)*SC; q[i*8+5]=bfh(r.z)*SC;
    q[i*8+6]=bfl(r.w)*SC; q[i*8+7]=bfh(r.w)*SC;
  }
  #pragma unroll
  for (int i=0;i<4;i++){
    const uint4 rk = *(const uint4*)(base + 96 + head*32 + i*8);
    const uint4 rv = *(const uint4*)(base + 192 + head*32 + i*8);
    *(float4*)&k_s[(lane<<5)+i*8]   = make_float4(bfl(rk.x),bfh(rk.x),bfl(rk.y),bfh(rk.y));
    *(float4*)&k_s[(lane<<5)+i*8+4] = make_float4(bfl(rk.z),bfh(rk.z),bfl(rk.w),bfh(rk.w));
    *(float4*)&v_s[(lane<<5)+i*8]   = make_float4(bfl(rv.x),bfh(rv.x),bfl(rv.y),bfh(rv.y));
    *(float4*)&v_s[(lane<<5)+i*8+4] = make_float4(bfl(rv.z),bfh(rv.z),bfl(rv.w),bfh(rv.w));
  }
  __syncthreads();
  const bool mi = (wi==11), mj = (wj==11);
  float sc[64];
  #pragma unroll
  for (int qq=0; qq<64; qq++){
    const float4* kr4 = (const float4*)&k_s[qq<<5];
    float s = 0.f;
    #pragma unroll
    for (int i=0;i<8;i++){
      const float4 kv = kr4[i];
      s += q[4*i]*kv.x + q[4*i+1]*kv.y + q[4*i+2]*kv.z + q[4*i+3]*kv.w;
    }
    const int qi = qq>>3, qj = qq&7;
    s += rel_s[(pi-qi+7)*15 + (pj-qj+7)];
    const bool msk = (mi && ((pi<4)!=(qi<4))) || (mj && ((pj<4)!=(qj<4)));
    sc[qq] = msk ? -1e30f : s;
  }
  float m = sc[0];
  #pragma unroll
  for (int qq=1;qq<64;qq++) m = fmaxf(m, sc[qq]);
  float sum = 0.f;
  #pragma unroll
  for (int qq=0;qq<64;qq++){ float e = __expf(sc[qq]-m); sc[qq]=e; sum+=e; }
  const float inv = 1.f/sum;
  float acc[32];
  #pragma unroll
  for (int i=0;i<32;i++) acc[i]=0.f;
  #pragma unroll
  for (int qq=0;qq<64;qq++){
    const float a = sc[qq]*inv;
    const float4* vr4 = (const float4*)&v_s[qq<<5];
    #pragma unroll
    for (int i=0;i<8;i++){
      const float4 vv = vr4[i];
      acc[4*i]+=a*vv.x; acc[4*i+1]+=a*vv.y; acc[4*i+2]+=a*vv.z; acc[4*i+3]+=a*vv.w;
    }
  }
  u16* orow = outa + pix*96 + head*32;
  #pragma unroll
  for (int i=0;i<4;i++){
    uint4 pk;
    pk.x = f2bf(acc[i*8+0])|(f2bf(acc[i*8+1])<<16);
    pk.y = f2bf(acc[i*8+2])|(f2bf(acc[i*8+3])<<16);
    pk.z = f2bf(acc[i*8+4])|(f2bf(acc[i*8+5])<<16);
    pk.w = f2bf(acc[i*8+6])|(f2bf(acc[i*8+7])<<16);
    *(uint4*)(orow + i*8) = pk;
  }
}

// ---------------------------------------------------------------------------
extern "C" void kernel_launch(void* const* d_in, const int* in_sizes, int n_in,
                              void* d_out, int out_size, void* d_ws, size_t ws_size,
                              hipStream_t stream)
{
  (void)in_sizes; (void)n_in; (void)out_size; (void)ws_size;
  const float* x        = (const float*)d_in[0];
  const float* cb_ln_g  = (const float*)d_in[1];
  const float* cb_ln_b  = (const float*)d_in[2];
  const float* cb_c1_pw = (const float*)d_in[3];
  const float* cb_c1_dw = (const float*)d_in[4];
  const float* cb_c2_pw = (const float*)d_in[5];
  const float* ada_w    = (const float*)d_in[6];
  const float* ada_p1_w = (const float*)d_in[7];
  const float* ada_p1_b = (const float*)d_in[8];
  const float* ada_p2_w = (const float*)d_in[9];
  const float* ada_p2_b = (const float*)d_in[10];
  const float* cb_c3_w  = (const float*)d_in[11];
  const float* ln1_g    = (const float*)d_in[12];
  const float* ln1_b    = (const float*)d_in[13];
  const float* qkv_w    = (const float*)d_in[14];
  const float* qkv_b    = (const float*)d_in[15];
  const float* rel_pos  = (const float*)d_in[16];
  const float* proj_w   = (const float*)d_in[17];
  const float* proj_b   = (const float*)d_in[18];
  const float* ln2_g    = (const float*)d_in[19];
  const float* ln2_b    = (const float*)d_in[20];
  const float* ffn_w1   = (const float*)d_in[21];
  const float* ffn_b1   = (const float*)d_in[22];
  const float* ffn_dw   = (const float*)d_in[23];
  const float* ffn_db   = (const float*)d_in[24];
  const float* ffn_w2   = (const float*)d_in[25];
  const float* ffn_b2   = (const float*)d_in[26];
  const float* out_w    = (const float*)d_in[27];
  const float* out_b    = (const float*)d_in[28];

  char* wsb = (char*)d_ws;
  // fp32 regions
  float* XC  = (float*)wsb;                                   // ST*96  raw conv residual
  float* U0f = (float*)(wsb + (size_t)ST*96*4);               // ST*288 f32 overlay region
  float* XT  = (float*)(wsb + (size_t)ST*384*4);              // ST*96  transformer residual
  float* PA2 = (float*)(wsb + (size_t)ST*480*4);              // ST*16
  // u16 regions
  u16* B2b  = (u16*)(wsb + (size_t)ST*496*4);                 // ST*192
  u16* LNCb = B2b  + (size_t)ST*192;                          // ST*96
  u16* R4b  = LNCb + (size_t)ST*96;                           // ST*96
  u16* R6b  = R4b  + (size_t)ST*96;                           // ST*96
  u16* PA1b = R6b  + (size_t)ST*96;                           // ST*16
  u16* Wbf  = PA1b + (size_t)ST*16;                           // 167424
  u16* Apre = Wbf + 167424;                                   // 491520
  // overlays on U0f (ST*288 f32 = ST*576 u16)
  u16* X12b = (u16*)U0f;                     // ST*384 u16 (c12 out, stride 384)
  u16* DWb  = (u16*)U0f + (size_t)ST*384;    // ST*192 u16 (dw1 out)
  u16* QKVb = (u16*)U0f;                     // ST*288 u16 (after conv branch dead)
  u16* FF1b = (u16*)U0f;                     // ST*192 u16 (after QKV dead)
  u16* DWOb = (u16*)U0f + (size_t)ST*192;

  const u16* W_qkv  = Wbf + 0;
  const u16* W_c12p = Wbf + 27648;   // [400][96]: c1, c2, P1eff
  const u16* W_c3   = Wbf + 66048;
  const u16* W_proj = Wbf + 84480;
  const u16* W_ffn1 = Wbf + 93696;
  const u16* W_ffn2 = Wbf + 112128;
  const u16* W_fin  = Wbf + 130560;

  // weight preps
  wprep_k<<<dim3(144, 8), 256, 0, stream>>>(qkv_w, cb_c1_pw, cb_c2_pw, cb_c3_w,
                                            proj_w, ffn_w1, ffn_w2, out_w, Wbf);
  p1eff_k<<<6, 256, 0, stream>>>(ada_p1_w, cb_c2_pw, Wbf + 64512);
  ada_prep_k<<<dim3(120, 16), 256, 0, stream>>>(ada_w, Apre);

  // fused dual LN from NCHW x
  ln12_k<<<ST/32, 256, 0, stream>>>(x, cb_ln_g, cb_ln_b, ln1_g, ln1_b, LNCb, R6b, XC, XT);

  // conv branch: fused c1+c2+p1eff: 96 -> 400 (0-191 c1, 192-383 c2, 384-399 p1)
  conv_mfma_k<0,false,false,false,false,true,true><<<dim3(ST/128, 7), 256, 0, stream>>>(LNCb, nullptr, 96, W_c12p, ada_p1_b, nullptr, 0, X12b, 384, 96, 400, PA1b);
  dw3x3_k<false,false><<<(ST*48)/256, 256, 0, stream>>>(X12b, 384, cb_c1_dw, nullptr, DWb, 192);
  p2conv_k<<<(ST*4)/256, 256, 0, stream>>>(PA1b, ada_p2_w, ada_p2_b, PA2);
  adaconv_mfma_k<<<dim3(72, 16, NB), 256, 0, stream>>>(X12b+192, PA2, Apre, DWb, B2b);
  conv_mfma_k<0,false,false,false,true,true,false><<<dim3(ST/128, 2), 256, 0, stream>>>(B2b, nullptr, 192, W_c3, nullptr, XC, 96, R4b, 96, 192, 96, nullptr);

  // transformer branch
  conv_mfma_k<0,false,false,true,false,true,false><<<dim3(ST/128, 5), 256, 0, stream>>>(R6b, nullptr, 96, W_qkv, qkv_b, nullptr, 0, QKVb, 288, 96, 288, nullptr);
  attn_k<<<dim3(144, 3, NB), 64, 0, stream>>>(QKVb, rel_pos, R6b);
  conv_mfma_k<0,false,false,true,true,false,false><<<dim3(ST/128, 2), 256, 0, stream>>>(R6b, nullptr, 96, W_proj, proj_b, XT, 96, XT, 96, 96, 96, nullptr);
  ln_k<<<ST/4, 256, 0, stream>>>(XT, 96, ln2_g, ln2_b, R6b);
  conv_mfma_k<0,false,false,true,false,true,false><<<dim3(ST/128, 3), 256, 0, stream>>>(R6b, nullptr, 96, W_ffn1, ffn_b1, nullptr, 0, FF1b, 192, 96, 192, nullptr);
  dw3x3_k<true,true><<<(ST*48)/256, 256, 0, stream>>>(FF1b, 192, ffn_dw, ffn_db, DWOb, 192);
  conv_mfma_k<0,false,false,true,true,false,false><<<dim3(ST/128, 2), 256, 0, stream>>>(DWOb, nullptr, 192, W_ffn2, ffn_b2, XT, 96, XT, 96, 192, 96, nullptr);

  // fuse: out = x + conv1x1(concat(convout bf16, xt f32), out_w) + out_b
  conv_mfma_k<0,true,true,true,true,false,false><<<dim3(ST/128, 3), 256, 0, stream>>>(R4b, XT, 96, W_fin, out_b, x, 0, (float*)d_out, 0, 192, 192, nullptr);
}

// Round 10
// 230.103 us; speedup vs baseline: 1.2482x; 1.1294x over previous
//
#include <hip/hip_runtime.h>
#include <math.h>

#define HW_ 9216
#define IH 96
#define IW 96
#define NB 2
#define ST (NB*HW_)   // 18432 pixels total

typedef __attribute__((ext_vector_type(8))) short bf16x8;
typedef __attribute__((ext_vector_type(4))) float f32x4;
typedef unsigned short u16;

__device__ __forceinline__ float gelu_f(float v){
  return 0.5f*v*(1.0f+erff(v*0.70710678118654752440f));
}
__device__ __forceinline__ unsigned f2bf(float f){
  unsigned u = __float_as_uint(f);
  return (u + 0x7FFF + ((u>>16)&1)) >> 16;
}
__device__ __forceinline__ float bfl(unsigned u){ return __uint_as_float(u<<16); }
__device__ __forceinline__ float bfh(unsigned u){ return __uint_as_float(u & 0xffff0000u); }

// ---------------------------------------------------------------------------
// K2: fused dual LayerNorm from NCHW input. Block: 32 px x 192 ch via LDS.
// ---------------------------------------------------------------------------
__global__ __launch_bounds__(256) void ln12_k(const float* __restrict__ x,
    const float* __restrict__ g1, const float* __restrict__ b1,
    const float* __restrict__ g2, const float* __restrict__ b2,
    u16* __restrict__ lnc, u16* __restrict__ ln1o,
    float* __restrict__ xc, float* __restrict__ xt)
{
  __shared__ float t[192][33];
  const int p0 = blockIdx.x<<5;
  const int bb = p0/HW_, hw0 = p0 - bb*HW_;
  const int tid = threadIdx.x;
  const int px = tid & 31, cr = tid >> 5;
  const float* xb = x + (size_t)bb*192*HW_ + hw0;
  #pragma unroll
  for (int k=0;k<24;k++){
    int c = cr + k*8;
    t[c][px] = xb[(size_t)c*HW_ + px];
  }
  __syncthreads();
  const int lane = tid&63, wv = tid>>6;
  #pragma unroll 1
  for (int i=0;i<8;i++){
    const int lp = wv*8+i;
    const size_t p = p0 + lp;
    float a0 = t[lane][lp];
    float a1 = (lane<32)? t[64+lane][lp] : 0.f;
    float c0 = t[96+lane][lp];
    float c1 = (lane<32)? t[160+lane][lp] : 0.f;
    float s1=a0+a1, s2=c0+c1;
    #pragma unroll
    for (int o=32;o;o>>=1){ s1+=__shfl_xor(s1,o); s2+=__shfl_xor(s2,o); }
    const float mu1=s1*(1.f/96.f), mu2=s2*(1.f/96.f);
    const float d0=a0-mu1, d1=a1-mu1, e0=c0-mu2, e1=c1-mu2;
    float q1=d0*d0+((lane<32)?d1*d1:0.f), q2=e0*e0+((lane<32)?e1*e1:0.f);
    #pragma unroll
    for (int o=32;o;o>>=1){ q1+=__shfl_xor(q1,o); q2+=__shfl_xor(q2,o); }
    const float r1=rsqrtf(q1*(1.f/96.f)+1e-5f), r2=rsqrtf(q2*(1.f/96.f)+1e-5f);
    lnc [p*96+lane] = (u16)f2bf(d0*r1*g1[lane]+b1[lane]);
    ln1o[p*96+lane] = (u16)f2bf(e0*r2*g2[lane]+b2[lane]);
    xc  [p*96+lane] = a0;
    xt  [p*96+lane] = c0;
    if (lane<32){
      lnc [p*96+64+lane] = (u16)f2bf(d1*r1*g1[64+lane]+b1[64+lane]);
      ln1o[p*96+64+lane] = (u16)f2bf(e1*r2*g2[64+lane]+b2[64+lane]);
      xc  [p*96+64+lane] = a1;
      xt  [p*96+64+lane] = c1;
    }
  }
}

// ---------------------------------------------------------------------------
// K2b: single LayerNorm (fp32 in, bf16 out) — ln2.
// ---------------------------------------------------------------------------
__global__ __launch_bounds__(256) void ln_k(const float* __restrict__ in, int istride,
                                            const float* __restrict__ gam, const float* __restrict__ bet,
                                            u16* __restrict__ out){
  int lane = threadIdx.x & 63;
  int wv   = threadIdx.x >> 6;
  int p    = (blockIdx.x << 2) + wv;
  const float* row = in + (size_t)p*istride;
  float v0 = row[lane];
  float v1 = (lane < 32) ? row[64+lane] : 0.0f;
  float s = v0 + v1;
  #pragma unroll
  for (int o=32;o;o>>=1) s += __shfl_xor(s,o);
  float mu = s * (1.0f/96.0f);
  float d0 = v0 - mu;
  float d1 = v1 - mu;
  float qv = d0*d0 + ((lane<32)? d1*d1 : 0.0f);
  #pragma unroll
  for (int o=32;o;o>>=1) qv += __shfl_xor(qv,o);
  float rstd = rsqrtf(qv*(1.0f/96.0f) + 1e-5f);
  u16* orow = out + (size_t)p*96;
  orow[lane] = (u16)f2bf(d0*rstd*gam[lane] + bet[lane]);
  if (lane < 32) orow[64+lane] = (u16)f2bf(d1*rstd*gam[64+lane] + bet[64+lane]);
}

// ---------------------------------------------------------------------------
// K3b: bf16-MFMA conv1x1.  Block: 128 px x 64 couts, 4 waves (2M x 2N).
// SPLIT: co<192 -> X1G group-major (out2), 192..383 -> X2G group-major
// (out2+ST*192), co>=384 -> bias+relu bf16 to out (PA1, stride 16).
// ---------------------------------------------------------------------------
template<int ACT, bool CONCAT, bool FINAL, bool HASB, bool HASR, bool OUTBF, bool SPLIT>
__global__ __launch_bounds__(256) void conv_mfma_k(
    const u16* __restrict__ in1, const float* __restrict__ in2f, int istride,
    const u16* __restrict__ wbf, const float* __restrict__ bias,
    const float* __restrict__ res, int rstride,
    void* __restrict__ out, int ostride, int Cin, int Cout,
    u16* __restrict__ out2)
{
  __shared__ __align__(16) unsigned char smem[39936];
  unsigned char* actl = smem;          // [128][208B]
  unsigned char* wl   = smem + 26624;  // [64][208B]
  const int tid=threadIdx.x, lane=tid&63, wv=tid>>6;
  const int lr=lane&15, g4=lane>>4, wm=wv>>1, wn=wv&1;
  const int p0=blockIdx.x<<7, co0=blockIdx.y<<6;

  f32x4 acc[2][4];
  #pragma unroll
  for (int m=0;m<2;m++)
    #pragma unroll
    for (int n=0;n<4;n++) acc[m][n]=(f32x4){0.f,0.f,0.f,0.f};

  for (int kc=0; kc<Cin; kc+=96){
    {
      const int row=tid>>1, half=tid&1;
      if (!CONCAT || kc==0){
        const u16* rp = in1 + (size_t)(p0+row)*istride + (CONCAT?0:kc) + half*48;
        #pragma unroll
        for (int s=0;s<6;s++)
          *(uint4*)(actl + row*208 + (half*6+s)*16) = *(const uint4*)(rp + s*8);
      } else {
        const float* rp = in2f + (size_t)(p0+row)*96 + half*48;
        #pragma unroll
        for (int s=0;s<6;s++){
          float4 a=*(const float4*)(rp+s*8), b=*(const float4*)(rp+s*8+4);
          uint4 pk;
          pk.x=f2bf(a.x)|(f2bf(a.y)<<16);
          pk.y=f2bf(a.z)|(f2bf(a.w)<<16);
          pk.z=f2bf(b.x)|(f2bf(b.y)<<16);
          pk.w=f2bf(b.z)|(f2bf(b.w)<<16);
          *(uint4*)(actl + row*208 + (half*6+s)*16) = pk;
        }
      }
    }
    {
      const int row=tid&63, grp=tid>>6;
      const int co=co0+row;
      const u16* wr = wbf + (size_t)co*Cin + kc;
      #pragma unroll
      for (int s=0;s<3;s++){
        int sl=grp*3+s;
        uint4 v={0,0,0,0};
        if (co<Cout) v=*(const uint4*)(wr + sl*8);
        *(uint4*)(wl + row*208 + sl*16)=v;
      }
    }
    __syncthreads();
    #pragma unroll
    for (int ks=0;ks<3;ks++){
      const int sl=ks*4+g4;
      bf16x8 afr[2], bfr[4];
      #pragma unroll
      for (int m=0;m<2;m++) afr[m]=*(const bf16x8*)(wl + ((wm*2+m)*16+lr)*208 + sl*16);
      #pragma unroll
      for (int n=0;n<4;n++) bfr[n]=*(const bf16x8*)(actl + (wn*64+n*16+lr)*208 + sl*16);
      #pragma unroll
      for (int m=0;m<2;m++)
        #pragma unroll
        for (int n=0;n<4;n++)
          acc[m][n]=__builtin_amdgcn_mfma_f32_16x16x32_bf16(afr[m], bfr[n], acc[m][n],0,0,0);
    }
    __syncthreads();
  }

  if (FINAL){
    float* outf = (float*)out;
    #pragma unroll
    for (int m=0;m<2;m++){
      const int cb=co0+(wm*2+m)*16+(g4<<2);
      float4 bv = make_float4(0.f,0.f,0.f,0.f);
      if (HASB) bv = *(const float4*)(bias+cb);
      #pragma unroll
      for (int n=0;n<4;n++){
        const int p=p0+wn*64+n*16+lr;
        const int bb=p/HW_, hw=p-bb*HW_;
        const float av[4]={acc[m][n].x,acc[m][n].y,acc[m][n].z,acc[m][n].w};
        const float bvv[4]={bv.x,bv.y,bv.z,bv.w};
        #pragma unroll
        for (int j=0;j<4;j++){
          size_t oi=((size_t)bb*192+cb+j)*HW_+hw;
          outf[oi]=av[j]+bvv[j]+res[oi];
        }
      }
    }
    return;
  }
  float* lt=(float*)smem;
  #pragma unroll
  for (int m=0;m<2;m++)
    #pragma unroll
    for (int n=0;n<4;n++){
      int px=wn*64+n*16+lr;
      int c=(wm*2+m)*16+(g4<<2);
      *(f32x4*)&lt[px*68+c]=acc[m][n];
    }
  __syncthreads();
  {
    const int pr=tid>>1, half=tid&1;
    const int p=p0+pr;
    #pragma unroll
    for (int s=0;s<8;s++){
      int cl=half*32+s*4;
      int co=co0+cl;
      if (co<Cout){
        float4 v=*(float4*)&lt[pr*68+cl];
        if (SPLIT){
          if (co>=384){
            const int c2 = co-384;
            const float4 bv=*(const float4*)(bias+c2);
            v.x=fmaxf(v.x+bv.x,0.f); v.y=fmaxf(v.y+bv.y,0.f);
            v.z=fmaxf(v.z+bv.z,0.f); v.w=fmaxf(v.w+bv.w,0.f);
            uint2 pk;
            pk.x = f2bf(v.x)|(f2bf(v.y)<<16);
            pk.y = f2bf(v.z)|(f2bf(v.w)<<16);
            *(uint2*)((u16*)out + (size_t)p*16 + c2) = pk;
          } else {
            const int cc = (co<192)? co : co-192;
            const int gg = cc/12, cll = cc - gg*12;
            u16* dst = out2 + ((co<192)? (size_t)0 : (size_t)ST*192)
                     + ((size_t)gg*ST + p)*12 + cll;
            uint2 pk;
            pk.x = f2bf(v.x)|(f2bf(v.y)<<16);
            pk.y = f2bf(v.z)|(f2bf(v.w)<<16);
            *(uint2*)dst = pk;
          }
          continue;
        }
        if (HASB){ const float4 bv=*(const float4*)(bias+co); v.x+=bv.x;v.y+=bv.y;v.z+=bv.z;v.w+=bv.w; }
        if (ACT==1){
          v.x=fmaxf(v.x,0.f); v.y=fmaxf(v.y,0.f); v.z=fmaxf(v.z,0.f); v.w=fmaxf(v.w,0.f);
        }
        if (HASR){ const float4 rv=*(const float4*)(res+(size_t)p*rstride+co); v.x+=rv.x;v.y+=rv.y;v.z+=rv.z;v.w+=rv.w; }
        if (OUTBF){
          uint2 pk;
          pk.x = f2bf(v.x)|(f2bf(v.y)<<16);
          pk.y = f2bf(v.z)|(f2bf(v.w)<<16);
          *(uint2*)((u16*)out + (size_t)p*ostride + co) = pk;
        } else {
          *(float4*)((float*)out + (size_t)p*ostride + co) = v;
        }
      }
    }
  }
}

// ---------------------------------------------------------------------------
// K4: depthwise 3x3, bf16 in/out, 4 ch/thread — only used for the FFN dw now.
// ---------------------------------------------------------------------------
template<bool HASB, bool DOGELU>
__global__ __launch_bounds__(256) void dw3x3_k(const u16* __restrict__ in, int istride,
                                               const float* __restrict__ w,
                                               const float* __restrict__ bias,
                                               u16* __restrict__ out, int C){
  int t = blockIdx.x*256 + threadIdx.x;
  int cg = C >> 2;
  int p = t / cg;
  if (p >= ST) return;
  int c4 = (t - p*cg) << 2;
  int bb = p / HW_, hw = p - bb*HW_;
  int hy = hw / IW, wx = hw - hy*IW;
  float w0[9], w1[9], w2[9], w3[9];
  #pragma unroll
  for (int tp=0;tp<9;tp++){
    w0[tp]=w[(c4+0)*9+tp]; w1[tp]=w[(c4+1)*9+tp]; w2[tp]=w[(c4+2)*9+tp]; w3[tp]=w[(c4+3)*9+tp];
  }
  float ax=0.f, ay=0.f, az=0.f, aw=0.f;
  #pragma unroll
  for (int i=0;i<3;i++){
    int y = hy+i-1;
    if ((unsigned)y >= IH) continue;
    #pragma unroll
    for (int j=0;j<3;j++){
      int x2 = wx+j-1;
      if ((unsigned)x2 >= IW) continue;
      const uint2 r = *(const uint2*)(in + ((size_t)bb*HW_ + y*IW + x2)*istride + c4);
      int tp=i*3+j;
      ax += bfl(r.x)*w0[tp]; ay += bfh(r.x)*w1[tp];
      az += bfl(r.y)*w2[tp]; aw += bfh(r.y)*w3[tp];
    }
  }
  if (HASB){ ax+=bias[c4]; ay+=bias[c4+1]; az+=bias[c4+2]; aw+=bias[c4+3]; }
  if (DOGELU){ ax=gelu_f(ax); ay=gelu_f(ay); az=gelu_f(az); aw=gelu_f(aw); }
  uint2 pk;
  pk.x = f2bf(ax)|(f2bf(ay)<<16);
  pk.y = f2bf(az)|(f2bf(aw)<<16);
  *(uint2*)(out + (size_t)p*C + c4) = pk;
}

// ---------------------------------------------------------------------------
// K5: full 3x3 conv 16->16 (para branch), bf16 in / fp32 out. 4 thr/px.
// ---------------------------------------------------------------------------
__global__ __launch_bounds__(256) void p2conv_k(const u16* __restrict__ in, const float* __restrict__ w,
                                                const float* __restrict__ bias, float* __restrict__ out){
  __shared__ float ws[2304];
  int tid = threadIdx.x;
  for (int i=tid;i<2304;i+=256) ws[i]=w[i];
  __syncthreads();
  int gidx = blockIdx.x*256 + tid;
  int p = gidx >> 2, qq = gidx & 3;
  int bb = p / HW_, hw = p - bb*HW_;
  int hy = hw / IW, wx = hw - hy*IW;
  const int cb = qq<<2;
  float a0=bias[cb], a1=bias[cb+1], a2=bias[cb+2], a3=bias[cb+3];
  #pragma unroll
  for (int i=0;i<3;i++){
    int y=hy+i-1; if ((unsigned)y>=IH) continue;
    #pragma unroll
    for (int j=0;j<3;j++){
      int x2=wx+j-1; if ((unsigned)x2>=IW) continue;
      int tap=i*3+j;
      const uint4 r = *(const uint4*)(in + ((size_t)bb*HW_ + y*IW + x2)*16);
      const uint4 r2 = *(const uint4*)(in + ((size_t)bb*HW_ + y*IW + x2)*16 + 8);
      float vv[16]={bfl(r.x),bfh(r.x),bfl(r.y),bfh(r.y),bfl(r.z),bfh(r.z),bfl(r.w),bfh(r.w),
                    bfl(r2.x),bfh(r2.x),bfl(r2.y),bfh(r2.y),bfl(r2.z),bfh(r2.z),bfl(r2.w),bfh(r2.w)};
      #pragma unroll
      for (int ci=0;ci<16;ci++){
        float v = vv[ci];
        a0 += ws[(cb+0)*144 + ci*9 + tap]*v;
        a1 += ws[(cb+1)*144 + ci*9 + tap]*v;
        a2 += ws[(cb+2)*144 + ci*9 + tap]*v;
        a3 += ws[(cb+3)*144 + ci*9 + tap]*v;
      }
    }
  }
  *(float4*)(out + (size_t)p*16 + cb) = make_float4(a0,a1,a2,a3);
}

// ---------------------------------------------------------------------------
// K6: all weight preps in ONE launch (flattened 1D grid = 2574 blocks):
//  blocks [0,648)    : fp32->bf16 copies of 8 matrices
//  blocks [648,654)  : P1eff = p1w @ c2w (16x96, K=192)
//  blocks [654,2574) : ada_w -> Amat[g][row][k'=tap*16+cl], K'=160
// ---------------------------------------------------------------------------
__global__ __launch_bounds__(256) void allprep_k(
    const float* __restrict__ s0, const float* __restrict__ s1,
    const float* __restrict__ s2, const float* __restrict__ s3,
    const float* __restrict__ s4, const float* __restrict__ s5,
    const float* __restrict__ s6, const float* __restrict__ s7,
    const float* __restrict__ p1w, const float* __restrict__ aw,
    u16* __restrict__ wdst, u16* __restrict__ apre)
{
  const int bid = blockIdx.x, tid = threadIdx.x;
  if (bid < 648){
    const int blks[8]={108,72,72,72,36,72,72,144};
    const int off[8] ={0,27648,46080,66048,84480,93696,112128,130560};
    const int sz[8]  ={27648,18432,18432,18432,9216,18432,18432,36864};
    int m=0, acc=0;
    #pragma unroll
    for (int k=0;k<8;k++){ if (bid >= acc + blks[k]){ acc += blks[k]; m=k+1; } }
    const float* s = (m==0)?s0:(m==1)?s1:(m==2)?s2:(m==3)?s3:(m==4)?s4:(m==5)?s5:(m==6)?s6:s7;
    int i = (bid-acc)*256 + tid;
    if (i < sz[m]) wdst[off[m]+i] = (u16)f2bf(s[i]);
  } else if (bid < 654){
    int i = (bid-648)*256 + tid;
    if (i < 1536){
      int o = i/96, ci = i - o*96;
      float s = 0.f;
      for (int k=0;k<192;k++) s += p1w[o*192+k]*s2[k*96+ci];
      wdst[64512+i] = (u16)f2bf(s);
    }
  } else {
    int E = (bid-654)*256 + tid;
    int g = E / 30720, e = E - g*30720;
    int row = e / 160, kp = e - row*160;
    int tap = kp >> 4, cl = kp & 15;
    int o = row >> 4, r = row & 15;
    float v = 0.f;
    if (tap < 9 && cl < 12)
      v = aw[(((size_t)(g*12+o)*108) + cl*9 + tap)*16 + r];
    apre[(size_t)g*30720 + e] = (u16)f2bf(v);
  }
}

// ---------------------------------------------------------------------------
// K6b v8: adaconv MFMA + fused dw1.  Block: (b, g, 16x8 region) = 2304 blocks.
// Inputs x1g/x2g are GROUP-MAJOR [(g*ST+p)*12+cl] -> coalesced halo staging.
// Epilogue computes b1 = dw3x3(c1) from the X1 halo in LDS (fp32) and writes
// B2b = bf16(gelu(adaconv)*b1). One dw3x3 kernel + 14MB round-trip removed.
// ---------------------------------------------------------------------------
__global__ __launch_bounds__(256) void adaconv_mfma_k(
    const u16* __restrict__ x1g, const u16* __restrict__ x2g,
    const float* __restrict__ para, const u16* __restrict__ apre,
    const float* __restrict__ dww, u16* __restrict__ outb2)
{
  __shared__ __align__(16) unsigned char smem[34096];
  unsigned char* HB2 = smem;              // x2 halo 18x10 x 48B = 8640
  unsigned char* HB1 = smem + 8640;       // x1 halo 18x10 x 48B = 8640
  float* PS = (float*)(smem + 17280);     // [2 sub][64 px][20] f32 = 10240
  float* OS = (float*)(smem + 27520);     // [2 sub][64 px][12] f32 = 6144
  float* WDW = (float*)(smem + 33664);    // 12ch x 9 taps f32 = 432

  const int tid=threadIdx.x, lane=tid&63, wv=tid>>6;
  const int lr=lane&15, g4=lane>>4;
  const int hi=(lane>>5)&1, lo16=(lane>>4)&1;
  const int b=blockIdx.z, g=blockIdx.y, reg=blockIdx.x;
  const int rh=(reg/12)<<4, rw=(reg%12)<<3;

  bf16x8 af[3][5];
  {
    const u16* ag = apre + (size_t)g*30720;
    #pragma unroll
    for (int oo=0;oo<3;oo++){
      const int row=(wv*3+oo)*16+lr;
      #pragma unroll
      for (int ks=0;ks<5;ks++)
        af[oo][ks] = *(const bf16x8*)(ag + row*160 + ks*32 + g4*8);
    }
  }
  // --- stage both halos (coalesced 24B/px streams) + dw weights ---
  if (tid < 180){
    int hy = tid/10, hx = tid - hy*10;
    int gy = rh+hy-1, gx = rw+hx-1;
    uint2 a2={0,0},b2={0,0},c2={0,0}, a1={0,0},b1={0,0},c1={0,0};
    if ((unsigned)gy<IH && (unsigned)gx<IW){
      const size_t base = ((size_t)g*ST + (size_t)b*HW_ + gy*IW + gx)*12;
      const u16* s2 = x2g + base;
      a2=*(const uint2*)s2; b2=*(const uint2*)(s2+4); c2=*(const uint2*)(s2+8);
      const u16* s1 = x1g + base;
      a1=*(const uint2*)s1; b1=*(const uint2*)(s1+4); c1=*(const uint2*)(s1+8);
    }
    *(uint4*)(HB2 + tid*48)      = make_uint4(a2.x,a2.y,b2.x,b2.y);
    *(uint4*)(HB2 + tid*48 + 16) = make_uint4(c2.x,c2.y,0,0);
    *(uint4*)(HB1 + tid*48)      = make_uint4(a1.x,a1.y,b1.x,b1.y);
    *(uint4*)(HB1 + tid*48 + 16) = make_uint4(c1.x,c1.y,0,0);
  }
  if (tid < 108) WDW[tid] = dww[g*108 + tid];
  // --- stage para for both subtiles ---
  #pragma unroll
  for (int it=0; it<2; ++it){
    int idx = tid + (it<<8);
    int sub = idx >> 8;
    int p = (idx>>2)&63, q = idx&3;
    int gy = rh + (sub<<3) + (p>>3), gx = rw + (p&7);
    float4 v = *(const float4*)(para + ((size_t)b*HW_+gy*IW+gx)*16 + q*4);
    *(float4*)&PS[sub*1280 + p*20 + q*4] = v;
  }
  __syncthreads();

  int tapoff[5];
  tapoff[0] = hi ? 48   : 0;
  tapoff[1] = hi ? 480  : 96;
  tapoff[2] = hi ? 576  : 528;
  tapoff[3] = hi ? 1008 : 960;
  tapoff[4] = 1056;

  #pragma unroll
  for (int sub=0; sub<2; ++sub){
    const int sy = sub<<3;
    const int base0 = ((sy + (lr>>3))*10 + (lr&7))*48 + lo16*16;

    f32x4 acc[3][4];
    #pragma unroll
    for (int oo=0;oo<3;oo++)
      #pragma unroll
      for (int n=0;n<4;n++) acc[oo][n]=(f32x4){0.f,0.f,0.f,0.f};

    #pragma unroll
    for (int ks=0;ks<5;ks++){
      bf16x8 bfr[4];
      #pragma unroll
      for (int n=0;n<4;n++)
        bfr[n] = *(const bf16x8*)(HB2 + base0 + n*960 + tapoff[ks]);
      #pragma unroll
      for (int oo=0;oo<3;oo++)
        #pragma unroll
        for (int n=0;n<4;n++)
          acc[oo][n]=__builtin_amdgcn_mfma_f32_16x16x32_bf16(af[oo][ks], bfr[n], acc[oo][n],0,0,0);
    }

    const float* ps = &PS[sub*1280];
    #pragma unroll
    for (int oo=0;oo<3;oo++){
      const int o=wv*3+oo;
      #pragma unroll
      for (int n=0;n<4;n++){
        const int p=(n<<4)+lr;
        const f32x4 prv = *(const f32x4*)&ps[p*20+(g4<<2)];
        float s=acc[oo][n].x*prv.x+acc[oo][n].y*prv.y+acc[oo][n].z*prv.z+acc[oo][n].w*prv.w;
        s += __shfl_xor(s,16); s += __shfl_xor(s,32);
        if (g4==n) OS[((sub<<6)+p)*12+o] = gelu_f(s);
      }
    }
  }
  __syncthreads();
  // --- coalesced epilogue: b1 = dw3x3(c1 halo), write gelu*b1 ---
  {
    const size_t gb = (size_t)b*HW_;
    for (int idx=tid; idx<384; idx+=256){
      const int cq = idx % 3;
      const int rest = idx / 3;
      const int p = rest & 63, sub = rest >> 6;
      const int py = p>>3, px = p&7;
      const int Y = (sub<<3)+py, X = px;
      const unsigned char* hb1 = HB1 + (Y*10+X)*48 + cq*8;
      const float* wd = &WDW[cq*36];   // channels cq*4..cq*4+3, 9 taps each
      float v0=0.f,v1=0.f,v2=0.f,v3=0.f;
      #pragma unroll
      for (int i=0;i<3;i++){
        #pragma unroll
        for (int j=0;j<3;j++){
          const uint2 r = *(const uint2*)(hb1 + (i*10+j)*48);
          const int tp=i*3+j;
          v0 += bfl(r.x)*wd[tp];      v1 += bfh(r.x)*wd[9+tp];
          v2 += bfl(r.y)*wd[18+tp];   v3 += bfh(r.y)*wd[27+tp];
        }
      }
      const size_t gi = (gb + (rh+(sub<<3)+py)*IW + (rw+px))*192 + g*12 + cq*4;
      const float* os = &OS[((sub<<6)+p)*12 + cq*4];
      uint2 pk;
      pk.x = f2bf(os[0]*v0) | (f2bf(os[1]*v1)<<16);
      pk.y = f2bf(os[2]*v2) | (f2bf(os[3]*v3)<<16);
      *(uint2*)(outb2 + gi) = pk;
    }
  }
}

// ---------------------------------------------------------------------------
// K7: shifted-window attention, 1 wave per (window, head). bf16 in/out.
// ---------------------------------------------------------------------------
__global__ __launch_bounds__(64) void attn_k(const u16* __restrict__ qkv,
                                             const float* __restrict__ relpos,
                                             u16* __restrict__ outa){
  __shared__ float k_s[2048];
  __shared__ float v_s[2048];
  __shared__ float rel_s[225];
  const int win = blockIdx.x, head = blockIdx.y, b = blockIdx.z;
  const int wi = win/12, wj = win%12;
  const int lane = threadIdx.x;
  for (int i=lane;i<225;i+=64) rel_s[i] = relpos[i*3+head];
  const int pi = lane>>3, pj = lane&7;
  const int hr = wi*8+pi, wr = wj*8+pj;
  const int sh = (hr+4)%96, sw = (wr+4)%96;
  const size_t pix = (size_t)b*HW_ + sh*96 + sw;
  const u16* base = qkv + pix*288;
  const float SC = 0.17677669529663687f;
  float q[32];
  #pragma unroll
  for (int i=0;i<4;i++){
    const uint4 r = *(const uint4*)(base + head*32 + i*8);
    q[i*8+0]=bfl(r.x)*SC; q[i*8+1]=bfh(r.x)*SC;
    q[i*8+2]=bfl(r.y)*SC; q[i*8+3]=bfh(r.y)*SC;
    q[i*8+4]=bfl(r.z)*SC; q[i*8+5]=bfh(r.z)*SC;
    q[i*8+6]=bfl(r.w)*SC; q[i*8+7]=bfh(r.w)*SC;
  }
  #pragma unroll
  for (int i=0;i<4;i++){
    const uint4 rk = *(const uint4*)(base + 96 + head*32 + i*8);
    const uint4 rv = *(const uint4*)(base + 192 + head*32 + i*8);
    *(float4*)&k_s[(lane<<5)+i*8]   = make_float4(bfl(rk.x),bfh(rk.x),bfl(rk.y),bfh(rk.y));
    *(float4*)&k_s[(lane<<5)+i*8+4] = make_float4(bfl(rk.z),bfh(rk.z),bfl(rk.w),bfh(rk.w));
    *(float4*)&v_s[(lane<<5)+i*8]   = make_float4(bfl(rv.x),bfh(rv.x),bfl(rv.y),bfh(rv.y));
    *(float4*)&v_s[(lane<<5)+i*8+4] = make_float4(bfl(rv.z),bfh(rv.z),bfl(rv.w),bfh(rv.w));
  }
  __syncthreads();
  const bool mi = (wi==11), mj = (wj==11);
  float sc[64];
  #pragma unroll
  for (int qq=0; qq<64; qq++){
    const float4* kr4 = (const float4*)&k_s[qq<<5];
    float s = 0.f;
    #pragma unroll
    for (int i=0;i<8;i++){
      const float4 kv = kr4[i];
      s += q[4*i]*kv.x + q[4*i+1]*kv.y + q[4*i+2]*kv.z + q[4*i+3]*kv.w;
    }
    const int qi = qq>>3, qj = qq&7;
    s += rel_s[(pi-qi+7)*15 + (pj-qj+7)];
    const bool msk = (mi && ((pi<4)!=(qi<4))) || (mj && ((pj<4)!=(qj<4)));
    sc[qq] = msk ? -1e30f : s;
  }
  float m = sc[0];
  #pragma unroll
  for (int qq=1;qq<64;qq++) m = fmaxf(m, sc[qq]);
  float sum = 0.f;
  #pragma unroll
  for (int qq=0;qq<64;qq++){ float e = __expf(sc[qq]-m); sc[qq]=e; sum+=e; }
  const float inv = 1.f/sum;
  float acc[32];
  #pragma unroll
  for (int i=0;i<32;i++) acc[i]=0.f;
  #pragma unroll
  for (int qq=0;qq<64;qq++){
    const float a = sc[qq]*inv;
    const float4* vr4 = (const float4*)&v_s[qq<<5];
    #pragma unroll
    for (int i=0;i<8;i++){
      const float4 vv = vr4[i];
      acc[4*i]+=a*vv.x; acc[4*i+1]+=a*vv.y; acc[4*i+2]+=a*vv.z; acc[4*i+3]+=a*vv.w;
    }
  }
  u16* orow = outa + pix*96 + head*32;
  #pragma unroll
  for (int i=0;i<4;i++){
    uint4 pk;
    pk.x = f2bf(acc[i*8+0])|(f2bf(acc[i*8+1])<<16);
    pk.y = f2bf(acc[i*8+2])|(f2bf(acc[i*8+3])<<16);
    pk.z = f2bf(acc[i*8+4])|(f2bf(acc[i*8+5])<<16);
    pk.w = f2bf(acc[i*8+6])|(f2bf(acc[i*8+7])<<16);
    *(uint4*)(orow + i*8) = pk;
  }
}

// ---------------------------------------------------------------------------
extern "C" void kernel_launch(void* const* d_in, const int* in_sizes, int n_in,
                              void* d_out, int out_size, void* d_ws, size_t ws_size,
                              hipStream_t stream)
{
  (void)in_sizes; (void)n_in; (void)out_size; (void)ws_size;
  const float* x        = (const float*)d_in[0];
  const float* cb_ln_g  = (const float*)d_in[1];
  const float* cb_ln_b  = (const float*)d_in[2];
  const float* cb_c1_pw = (const float*)d_in[3];
  const float* cb_c1_dw = (const float*)d_in[4];
  const float* cb_c2_pw = (const float*)d_in[5];
  const float* ada_w    = (const float*)d_in[6];
  const float* ada_p1_w = (const float*)d_in[7];
  const float* ada_p1_b = (const float*)d_in[8];
  const float* ada_p2_w = (const float*)d_in[9];
  const float* ada_p2_b = (const float*)d_in[10];
  const float* cb_c3_w  = (const float*)d_in[11];
  const float* ln1_g    = (const float*)d_in[12];
  const float* ln1_b    = (const float*)d_in[13];
  const float* qkv_w    = (const float*)d_in[14];
  const float* qkv_b    = (const float*)d_in[15];
  const float* rel_pos  = (const float*)d_in[16];
  const float* proj_w   = (const float*)d_in[17];
  const float* proj_b   = (const float*)d_in[18];
  const float* ln2_g    = (const float*)d_in[19];
  const float* ln2_b    = (const float*)d_in[20];
  const float* ffn_w1   = (const float*)d_in[21];
  const float* ffn_b1   = (const float*)d_in[22];
  const float* ffn_dw   = (const float*)d_in[23];
  const float* ffn_db   = (const float*)d_in[24];
  const float* ffn_w2   = (const float*)d_in[25];
  const float* ffn_b2   = (const float*)d_in[26];
  const float* out_w    = (const float*)d_in[27];
  const float* out_b    = (const float*)d_in[28];

  char* wsb = (char*)d_ws;
  // fp32 regions
  float* XC  = (float*)wsb;                                   // ST*96  raw conv residual
  float* U0f = (float*)(wsb + (size_t)ST*96*4);               // ST*288 f32 overlay region
  float* XT  = (float*)(wsb + (size_t)ST*384*4);              // ST*96  transformer residual
  float* PA2 = (float*)(wsb + (size_t)ST*480*4);              // ST*16
  // u16 regions
  u16* B2b  = (u16*)(wsb + (size_t)ST*496*4);                 // ST*192
  u16* LNCb = B2b  + (size_t)ST*192;                          // ST*96
  u16* R4b  = LNCb + (size_t)ST*96;                           // ST*96
  u16* R6b  = R4b  + (size_t)ST*96;                           // ST*96
  u16* PA1b = R6b  + (size_t)ST*96;                           // ST*16
  u16* Wbf  = PA1b + (size_t)ST*16;                           // 167424
  u16* Apre = Wbf + 167424;                                   // 491520
  // overlays on U0f (capacity ST*576 u16):
  u16* X1G  = (u16*)U0f;                     // ST*192 u16, group-major c1
  u16* X2G  = X1G + (size_t)ST*192;          // ST*192 u16, group-major c2
  u16* QKVb = (u16*)U0f;                     // ST*288 u16 (after conv branch dead)
  u16* FF1b = (u16*)U0f;                     // ST*192 u16 (after QKV dead)
  u16* DWOb = (u16*)U0f + (size_t)ST*192;

  const u16* W_qkv  = Wbf + 0;
  const u16* W_c12p = Wbf + 27648;   // [400][96]: c1, c2, P1eff
  const u16* W_c3   = Wbf + 66048;
  const u16* W_proj = Wbf + 84480;
  const u16* W_ffn1 = Wbf + 93696;
  const u16* W_ffn2 = Wbf + 112128;
  const u16* W_fin  = Wbf + 130560;

  // all weight preps in one launch
  allprep_k<<<2574, 256, 0, stream>>>(qkv_w, cb_c1_pw, cb_c2_pw, cb_c3_w,
                                      proj_w, ffn_w1, ffn_w2, out_w,
                                      ada_p1_w, ada_w, Wbf, Apre);

  // fused dual LN from NCHW x
  ln12_k<<<ST/32, 256, 0, stream>>>(x, cb_ln_g, cb_ln_b, ln1_g, ln1_b, LNCb, R6b, XC, XT);

  // conv branch: fused c1+c2+p1eff -> group-major X1G/X2G + PA1
  conv_mfma_k<0,false,false,false,false,true,true><<<dim3(ST/128, 7), 256, 0, stream>>>(LNCb, nullptr, 96, W_c12p, ada_p1_b, nullptr, 0, PA1b, 16, 96, 400, X1G);
  p2conv_k<<<(ST*4)/256, 256, 0, stream>>>(PA1b, ada_p2_w, ada_p2_b, PA2);
  adaconv_mfma_k<<<dim3(72, 16, NB), 256, 0, stream>>>(X1G, X2G, PA2, Apre, cb_c1_dw, B2b);
  conv_mfma_k<0,false,false,false,true,true,false><<<dim3(ST/128, 2), 256, 0, stream>>>(B2b, nullptr, 192, W_c3, nullptr, XC, 96, R4b, 96, 192, 96, nullptr);

  // transformer branch
  conv_mfma_k<0,false,false,true,false,true,false><<<dim3(ST/128, 5), 256, 0, stream>>>(R6b, nullptr, 96, W_qkv, qkv_b, nullptr, 0, QKVb, 288, 96, 288, nullptr);
  attn_k<<<dim3(144, 3, NB), 64, 0, stream>>>(QKVb, rel_pos, R6b);
  conv_mfma_k<0,false,false,true,true,false,false><<<dim3(ST/128, 2), 256, 0, stream>>>(R6b, nullptr, 96, W_proj, proj_b, XT, 96, XT, 96, 96, 96, nullptr);
  ln_k<<<ST/4, 256, 0, stream>>>(XT, 96, ln2_g, ln2_b, R6b);
  conv_mfma_k<0,false,false,true,false,true,false><<<dim3(ST/128, 3), 256, 0, stream>>>(R6b, nullptr, 96, W_ffn1, ffn_b1, nullptr, 0, FF1b, 192, 96, 192, nullptr);
  dw3x3_k<true,true><<<(ST*48)/256, 256, 0, stream>>>(FF1b, 192, ffn_dw, ffn_db, DWOb, 192);
  conv_mfma_k<0,false,false,true,true,false,false><<<dim3(ST/128, 2), 256, 0, stream>>>(DWOb, nullptr, 192, W_ffn2, ffn_b2, XT, 96, XT, 96, 192, 96, nullptr);

  // fuse: out = x + conv1x1(concat(convout bf16, xt f32), out_w) + out_b
  conv_mfma_k<0,true,true,true,true,false,false><<<dim3(ST/128, 3), 256, 0, stream>>>(R4b, XT, 96, W_fin, out_b, x, 0, (float*)d_out, 0, 192, 192, nullptr);
}

// Round 11
// 207.014 us; speedup vs baseline: 1.3874x; 1.1115x over previous
//
#include <hip/hip_runtime.h>
#include <math.h>

#define HW_ 9216
#define IH 96
#define IW 96
#define NB 2
#define ST (NB*HW_)   // 18432 pixels total

typedef __attribute__((ext_vector_type(8))) short bf16x8;
typedef __attribute__((ext_vector_type(4))) float f32x4;
typedef unsigned short u16;

__device__ __forceinline__ float gelu_f(float v){
  return 0.5f*v*(1.0f+erff(v*0.70710678118654752440f));
}
__device__ __forceinline__ unsigned f2bf(float f){
  unsigned u = __float_as_uint(f);
  return (u + 0x7FFF + ((u>>16)&1)) >> 16;
}
__device__ __forceinline__ float bfl(unsigned u){ return __uint_as_float(u<<16); }
__device__ __forceinline__ float bfh(unsigned u){ return __uint_as_float(u & 0xffff0000u); }

// ---------------------------------------------------------------------------
// ln12 body: fused dual LayerNorm from NCHW input (32 px per block-index).
// ---------------------------------------------------------------------------
__device__ __forceinline__ void ln12_body(const float* __restrict__ x,
    const float* __restrict__ g1, const float* __restrict__ b1,
    const float* __restrict__ g2, const float* __restrict__ b2,
    u16* __restrict__ lnc, u16* __restrict__ ln1o,
    float* __restrict__ xc, float* __restrict__ xt, int bidx)
{
  __shared__ float t[192][33];
  const int p0 = bidx<<5;
  const int bb = p0/HW_, hw0 = p0 - bb*HW_;
  const int tid = threadIdx.x;
  const int px = tid & 31, cr = tid >> 5;
  const float* xb = x + (size_t)bb*192*HW_ + hw0;
  #pragma unroll
  for (int k=0;k<24;k++){
    int c = cr + k*8;
    t[c][px] = xb[(size_t)c*HW_ + px];
  }
  __syncthreads();
  const int lane = tid&63, wv = tid>>6;
  #pragma unroll 1
  for (int i=0;i<8;i++){
    const int lp = wv*8+i;
    const size_t p = p0 + lp;
    float a0 = t[lane][lp];
    float a1 = (lane<32)? t[64+lane][lp] : 0.f;
    float c0 = t[96+lane][lp];
    float c1 = (lane<32)? t[160+lane][lp] : 0.f;
    float s1=a0+a1, s2=c0+c1;
    #pragma unroll
    for (int o=32;o;o>>=1){ s1+=__shfl_xor(s1,o); s2+=__shfl_xor(s2,o); }
    const float mu1=s1*(1.f/96.f), mu2=s2*(1.f/96.f);
    const float d0=a0-mu1, d1=a1-mu1, e0=c0-mu2, e1=c1-mu2;
    float q1=d0*d0+((lane<32)?d1*d1:0.f), q2=e0*e0+((lane<32)?e1*e1:0.f);
    #pragma unroll
    for (int o=32;o;o>>=1){ q1+=__shfl_xor(q1,o); q2+=__shfl_xor(q2,o); }
    const float r1=rsqrtf(q1*(1.f/96.f)+1e-5f), r2=rsqrtf(q2*(1.f/96.f)+1e-5f);
    lnc [p*96+lane] = (u16)f2bf(d0*r1*g1[lane]+b1[lane]);
    ln1o[p*96+lane] = (u16)f2bf(e0*r2*g2[lane]+b2[lane]);
    xc  [p*96+lane] = a0;
    xt  [p*96+lane] = c0;
    if (lane<32){
      lnc [p*96+64+lane] = (u16)f2bf(d1*r1*g1[64+lane]+b1[64+lane]);
      ln1o[p*96+64+lane] = (u16)f2bf(e1*r2*g2[64+lane]+b2[64+lane]);
      xc  [p*96+64+lane] = a1;
      xt  [p*96+64+lane] = c1;
    }
  }
}

// ---------------------------------------------------------------------------
// ln body: single LayerNorm (fp32 in, bf16 out), 4 px per block-index.
// ---------------------------------------------------------------------------
__device__ __forceinline__ void ln_body(const float* __restrict__ in, int istride,
    const float* __restrict__ gam, const float* __restrict__ bet,
    u16* __restrict__ out, int bidx)
{
  int lane = threadIdx.x & 63;
  int wv   = threadIdx.x >> 6;
  int p    = (bidx << 2) + wv;
  const float* row = in + (size_t)p*istride;
  float v0 = row[lane];
  float v1 = (lane < 32) ? row[64+lane] : 0.0f;
  float s = v0 + v1;
  #pragma unroll
  for (int o=32;o;o>>=1) s += __shfl_xor(s,o);
  float mu = s * (1.0f/96.0f);
  float d0 = v0 - mu;
  float d1 = v1 - mu;
  float qv = d0*d0 + ((lane<32)? d1*d1 : 0.0f);
  #pragma unroll
  for (int o=32;o;o>>=1) qv += __shfl_xor(qv,o);
  float rstd = rsqrtf(qv*(1.0f/96.0f) + 1e-5f);
  u16* orow = out + (size_t)p*96;
  orow[lane] = (u16)f2bf(d0*rstd*gam[lane] + bet[lane]);
  if (lane < 32) orow[64+lane] = (u16)f2bf(d1*rstd*gam[64+lane] + bet[64+lane]);
}

// ---------------------------------------------------------------------------
// conv body: bf16-MFMA conv1x1. 128 px x 64 couts per (bx,by).
// ---------------------------------------------------------------------------
template<int ACT, bool CONCAT, bool FINAL, bool HASB, bool HASR, bool OUTBF, bool SPLIT>
__device__ __forceinline__ void conv_body(unsigned char* smem,
    const u16* __restrict__ in1, const float* __restrict__ in2f, int istride,
    const u16* __restrict__ wbf, const float* __restrict__ bias,
    const float* __restrict__ res, int rstride,
    void* __restrict__ out, int ostride, int Cin, int Cout,
    u16* __restrict__ out2, int bx, int by)
{
  unsigned char* actl = smem;          // [128][208B]
  unsigned char* wl   = smem + 26624;  // [64][208B]
  const int tid=threadIdx.x, lane=tid&63, wv=tid>>6;
  const int lr=lane&15, g4=lane>>4, wm=wv>>1, wn=wv&1;
  const int p0=bx<<7, co0=by<<6;

  f32x4 acc[2][4];
  #pragma unroll
  for (int m=0;m<2;m++)
    #pragma unroll
    for (int n=0;n<4;n++) acc[m][n]=(f32x4){0.f,0.f,0.f,0.f};

  for (int kc=0; kc<Cin; kc+=96){
    {
      const int row=tid>>1, half=tid&1;
      if (!CONCAT || kc==0){
        const u16* rp = in1 + (size_t)(p0+row)*istride + (CONCAT?0:kc) + half*48;
        #pragma unroll
        for (int s=0;s<6;s++)
          *(uint4*)(actl + row*208 + (half*6+s)*16) = *(const uint4*)(rp + s*8);
      } else {
        const float* rp = in2f + (size_t)(p0+row)*96 + half*48;
        #pragma unroll
        for (int s=0;s<6;s++){
          float4 a=*(const float4*)(rp+s*8), b=*(const float4*)(rp+s*8+4);
          uint4 pk;
          pk.x=f2bf(a.x)|(f2bf(a.y)<<16);
          pk.y=f2bf(a.z)|(f2bf(a.w)<<16);
          pk.z=f2bf(b.x)|(f2bf(b.y)<<16);
          pk.w=f2bf(b.z)|(f2bf(b.w)<<16);
          *(uint4*)(actl + row*208 + (half*6+s)*16) = pk;
        }
      }
    }
    {
      const int row=tid&63, grp=tid>>6;
      const int co=co0+row;
      const u16* wr = wbf + (size_t)co*Cin + kc;
      #pragma unroll
      for (int s=0;s<3;s++){
        int sl=grp*3+s;
        uint4 v={0,0,0,0};
        if (co<Cout) v=*(const uint4*)(wr + sl*8);
        *(uint4*)(wl + row*208 + sl*16)=v;
      }
    }
    __syncthreads();
    #pragma unroll
    for (int ks=0;ks<3;ks++){
      const int sl=ks*4+g4;
      bf16x8 afr[2], bfr[4];
      #pragma unroll
      for (int m=0;m<2;m++) afr[m]=*(const bf16x8*)(wl + ((wm*2+m)*16+lr)*208 + sl*16);
      #pragma unroll
      for (int n=0;n<4;n++) bfr[n]=*(const bf16x8*)(actl + (wn*64+n*16+lr)*208 + sl*16);
      #pragma unroll
      for (int m=0;m<2;m++)
        #pragma unroll
        for (int n=0;n<4;n++)
          acc[m][n]=__builtin_amdgcn_mfma_f32_16x16x32_bf16(afr[m], bfr[n], acc[m][n],0,0,0);
    }
    __syncthreads();
  }

  if (FINAL){
    float* outf = (float*)out;
    #pragma unroll
    for (int m=0;m<2;m++){
      const int cb=co0+(wm*2+m)*16+(g4<<2);
      float4 bv = make_float4(0.f,0.f,0.f,0.f);
      if (HASB) bv = *(const float4*)(bias+cb);
      #pragma unroll
      for (int n=0;n<4;n++){
        const int p=p0+wn*64+n*16+lr;
        const int bb=p/HW_, hw=p-bb*HW_;
        const float av[4]={acc[m][n].x,acc[m][n].y,acc[m][n].z,acc[m][n].w};
        const float bvv[4]={bv.x,bv.y,bv.z,bv.w};
        #pragma unroll
        for (int j=0;j<4;j++){
          size_t oi=((size_t)bb*192+cb+j)*HW_+hw;
          outf[oi]=av[j]+bvv[j]+res[oi];
        }
      }
    }
    return;
  }
  float* lt=(float*)smem;
  #pragma unroll
  for (int m=0;m<2;m++)
    #pragma unroll
    for (int n=0;n<4;n++){
      int px=wn*64+n*16+lr;
      int c=(wm*2+m)*16+(g4<<2);
      *(f32x4*)&lt[px*68+c]=acc[m][n];
    }
  __syncthreads();
  {
    const int pr=tid>>1, half=tid&1;
    const int p=p0+pr;
    #pragma unroll
    for (int s=0;s<8;s++){
      int cl=half*32+s*4;
      int co=co0+cl;
      if (co<Cout){
        float4 v=*(float4*)&lt[pr*68+cl];
        if (SPLIT){
          if (co>=384){
            const int c2 = co-384;
            const float4 bv=*(const float4*)(bias+c2);
            v.x=fmaxf(v.x+bv.x,0.f); v.y=fmaxf(v.y+bv.y,0.f);
            v.z=fmaxf(v.z+bv.z,0.f); v.w=fmaxf(v.w+bv.w,0.f);
            uint2 pk;
            pk.x = f2bf(v.x)|(f2bf(v.y)<<16);
            pk.y = f2bf(v.z)|(f2bf(v.w)<<16);
            *(uint2*)((u16*)out + (size_t)p*16 + c2) = pk;
          } else {
            const int cc = (co<192)? co : co-192;
            const int gg = cc/12, cll = cc - gg*12;
            u16* dst = out2 + ((co<192)? (size_t)0 : (size_t)ST*192)
                     + ((size_t)gg*ST + p)*12 + cll;
            uint2 pk;
            pk.x = f2bf(v.x)|(f2bf(v.y)<<16);
            pk.y = f2bf(v.z)|(f2bf(v.w)<<16);
            *(uint2*)dst = pk;
          }
          continue;
        }
        if (HASB){ const float4 bv=*(const float4*)(bias+co); v.x+=bv.x;v.y+=bv.y;v.z+=bv.z;v.w+=bv.w; }
        if (ACT==1){
          v.x=fmaxf(v.x,0.f); v.y=fmaxf(v.y,0.f); v.z=fmaxf(v.z,0.f); v.w=fmaxf(v.w,0.f);
        }
        if (HASR){ const float4 rv=*(const float4*)(res+(size_t)p*rstride+co); v.x+=rv.x;v.y+=rv.y;v.z+=rv.z;v.w+=rv.w; }
        if (OUTBF){
          uint2 pk;
          pk.x = f2bf(v.x)|(f2bf(v.y)<<16);
          pk.y = f2bf(v.z)|(f2bf(v.w)<<16);
          *(uint2*)((u16*)out + (size_t)p*ostride + co) = pk;
        } else {
          *(float4*)((float*)out + (size_t)p*ostride + co) = v;
        }
      }
    }
  }
}

template<int ACT, bool CONCAT, bool FINAL, bool HASB, bool HASR, bool OUTBF, bool SPLIT>
__global__ __launch_bounds__(256) void conv_mfma_k(
    const u16* __restrict__ in1, const float* __restrict__ in2f, int istride,
    const u16* __restrict__ wbf, const float* __restrict__ bias,
    const float* __restrict__ res, int rstride,
    void* __restrict__ out, int ostride, int Cin, int Cout,
    u16* __restrict__ out2)
{
  __shared__ __align__(16) unsigned char smem[39936];
  conv_body<ACT,CONCAT,FINAL,HASB,HASR,OUTBF,SPLIT>(smem, in1, in2f, istride, wbf, bias,
      res, rstride, out, ostride, Cin, Cout, out2, blockIdx.x, blockIdx.y);
}

// ---------------------------------------------------------------------------
// adaconv body: MFMA + fused dw1 (group-major inputs).
// ---------------------------------------------------------------------------
__device__ __forceinline__ void adaconv_body(unsigned char* smem,
    const u16* __restrict__ x1g, const u16* __restrict__ x2g,
    const float* __restrict__ para, const u16* __restrict__ apre,
    const float* __restrict__ dww, u16* __restrict__ outb2,
    int b, int g, int reg)
{
  unsigned char* HB2 = smem;              // x2 halo 18x10 x 48B = 8640
  unsigned char* HB1 = smem + 8640;       // x1 halo 18x10 x 48B = 8640
  float* PS = (float*)(smem + 17280);     // [2 sub][64 px][20] f32 = 10240
  float* OS = (float*)(smem + 27520);     // [2 sub][64 px][12] f32 = 6144
  float* WDW = (float*)(smem + 33664);    // 12ch x 9 taps f32 = 432

  const int tid=threadIdx.x, lane=tid&63, wv=tid>>6;
  const int lr=lane&15, g4=lane>>4;
  const int hi=(lane>>5)&1, lo16=(lane>>4)&1;
  const int rh=(reg/12)<<4, rw=(reg%12)<<3;

  bf16x8 af[3][5];
  {
    const u16* ag = apre + (size_t)g*30720;
    #pragma unroll
    for (int oo=0;oo<3;oo++){
      const int row=(wv*3+oo)*16+lr;
      #pragma unroll
      for (int ks=0;ks<5;ks++)
        af[oo][ks] = *(const bf16x8*)(ag + row*160 + ks*32 + g4*8);
    }
  }
  if (tid < 180){
    int hy = tid/10, hx = tid - hy*10;
    int gy = rh+hy-1, gx = rw+hx-1;
    uint2 a2={0,0},b2={0,0},c2={0,0}, a1={0,0},b1={0,0},c1={0,0};
    if ((unsigned)gy<IH && (unsigned)gx<IW){
      const size_t base = ((size_t)g*ST + (size_t)b*HW_ + gy*IW + gx)*12;
      const u16* s2 = x2g + base;
      a2=*(const uint2*)s2; b2=*(const uint2*)(s2+4); c2=*(const uint2*)(s2+8);
      const u16* s1 = x1g + base;
      a1=*(const uint2*)s1; b1=*(const uint2*)(s1+4); c1=*(const uint2*)(s1+8);
    }
    *(uint4*)(HB2 + tid*48)      = make_uint4(a2.x,a2.y,b2.x,b2.y);
    *(uint4*)(HB2 + tid*48 + 16) = make_uint4(c2.x,c2.y,0,0);
    *(uint4*)(HB1 + tid*48)      = make_uint4(a1.x,a1.y,b1.x,b1.y);
    *(uint4*)(HB1 + tid*48 + 16) = make_uint4(c1.x,c1.y,0,0);
  }
  if (tid < 108) WDW[tid] = dww[g*108 + tid];
  #pragma unroll
  for (int it=0; it<2; ++it){
    int idx = tid + (it<<8);
    int sub = idx >> 8;
    int p = (idx>>2)&63, q = idx&3;
    int gy = rh + (sub<<3) + (p>>3), gx = rw + (p&7);
    float4 v = *(const float4*)(para + ((size_t)b*HW_+gy*IW+gx)*16 + q*4);
    *(float4*)&PS[sub*1280 + p*20 + q*4] = v;
  }
  __syncthreads();

  int tapoff[5];
  tapoff[0] = hi ? 48   : 0;
  tapoff[1] = hi ? 480  : 96;
  tapoff[2] = hi ? 576  : 528;
  tapoff[3] = hi ? 1008 : 960;
  tapoff[4] = 1056;

  #pragma unroll
  for (int sub=0; sub<2; ++sub){
    const int sy = sub<<3;
    const int base0 = ((sy + (lr>>3))*10 + (lr&7))*48 + lo16*16;

    f32x4 acc[3][4];
    #pragma unroll
    for (int oo=0;oo<3;oo++)
      #pragma unroll
      for (int n=0;n<4;n++) acc[oo][n]=(f32x4){0.f,0.f,0.f,0.f};

    #pragma unroll
    for (int ks=0;ks<5;ks++){
      bf16x8 bfr[4];
      #pragma unroll
      for (int n=0;n<4;n++)
        bfr[n] = *(const bf16x8*)(HB2 + base0 + n*960 + tapoff[ks]);
      #pragma unroll
      for (int oo=0;oo<3;oo++)
        #pragma unroll
        for (int n=0;n<4;n++)
          acc[oo][n]=__builtin_amdgcn_mfma_f32_16x16x32_bf16(af[oo][ks], bfr[n], acc[oo][n],0,0,0);
    }

    const float* ps = &PS[sub*1280];
    #pragma unroll
    for (int oo=0;oo<3;oo++){
      const int o=wv*3+oo;
      #pragma unroll
      for (int n=0;n<4;n++){
        const int p=(n<<4)+lr;
        const f32x4 prv = *(const f32x4*)&ps[p*20+(g4<<2)];
        float s=acc[oo][n].x*prv.x+acc[oo][n].y*prv.y+acc[oo][n].z*prv.z+acc[oo][n].w*prv.w;
        s += __shfl_xor(s,16); s += __shfl_xor(s,32);
        if (g4==n) OS[((sub<<6)+p)*12+o] = gelu_f(s);
      }
    }
  }
  __syncthreads();
  {
    const size_t gb = (size_t)b*HW_;
    for (int idx=tid; idx<384; idx+=256){
      const int cq = idx % 3;
      const int rest = idx / 3;
      const int p = rest & 63, sub = rest >> 6;
      const int py = p>>3, px = p&7;
      const int Y = (sub<<3)+py, X = px;
      const unsigned char* hb1 = HB1 + (Y*10+X)*48 + cq*8;
      const float* wd = &WDW[cq*36];
      float v0=0.f,v1=0.f,v2=0.f,v3=0.f;
      #pragma unroll
      for (int i=0;i<3;i++){
        #pragma unroll
        for (int j=0;j<3;j++){
          const uint2 r = *(const uint2*)(hb1 + (i*10+j)*48);
          const int tp=i*3+j;
          v0 += bfl(r.x)*wd[tp];      v1 += bfh(r.x)*wd[9+tp];
          v2 += bfl(r.y)*wd[18+tp];   v3 += bfh(r.y)*wd[27+tp];
        }
      }
      const size_t gi = (gb + (rh+(sub<<3)+py)*IW + (rw+px))*192 + g*12 + cq*4;
      const float* os = &OS[((sub<<6)+p)*12 + cq*4];
      uint2 pk;
      pk.x = f2bf(os[0]*v0) | (f2bf(os[1]*v1)<<16);
      pk.y = f2bf(os[2]*v2) | (f2bf(os[3]*v3)<<16);
      *(uint2*)(outb2 + gi) = pk;
    }
  }
}

// ---------------------------------------------------------------------------
// allprep body (bid roles: [0,648) wcopy, [648,654) P1eff, [654,2574) ada)
// ---------------------------------------------------------------------------
__device__ __forceinline__ void allprep_body(
    const float* __restrict__ s0, const float* __restrict__ s1,
    const float* __restrict__ s2, const float* __restrict__ s3,
    const float* __restrict__ s4, const float* __restrict__ s5,
    const float* __restrict__ s6, const float* __restrict__ s7,
    const float* __restrict__ p1w, const float* __restrict__ aw,
    u16* __restrict__ wdst, u16* __restrict__ apre, int bid)
{
  const int tid = threadIdx.x;
  if (bid < 648){
    const int blks[8]={108,72,72,72,36,72,72,144};
    const int off[8] ={0,27648,46080,66048,84480,93696,112128,130560};
    const int sz[8]  ={27648,18432,18432,18432,9216,18432,18432,36864};
    int m=0, acc=0;
    #pragma unroll
    for (int k=0;k<8;k++){ if (bid >= acc + blks[k]){ acc += blks[k]; m=k+1; } }
    const float* s = (m==0)?s0:(m==1)?s1:(m==2)?s2:(m==3)?s3:(m==4)?s4:(m==5)?s5:(m==6)?s6:s7;
    int i = (bid-acc)*256 + tid;
    if (i < sz[m]) wdst[off[m]+i] = (u16)f2bf(s[i]);
  } else if (bid < 654){
    int i = (bid-648)*256 + tid;
    if (i < 1536){
      int o = i/96, ci = i - o*96;
      float s = 0.f;
      for (int k=0;k<192;k++) s += p1w[o*192+k]*s2[k*96+ci];
      wdst[64512+i] = (u16)f2bf(s);
    }
  } else {
    int E = (bid-654)*256 + tid;
    int g = E / 30720, e = E - g*30720;
    int row = e / 160, kp = e - row*160;
    int tap = kp >> 4, cl = kp & 15;
    int o = row >> 4, r = row & 15;
    float v = 0.f;
    if (tap < 9 && cl < 12)
      v = aw[(((size_t)(g*12+o)*108) + cl*9 + tap)*16 + r];
    apre[(size_t)g*30720 + e] = (u16)f2bf(v);
  }
}

// ---------------------------------------------------------------------------
// M0: allprep (2574) + ln12 (576)
// ---------------------------------------------------------------------------
__global__ __launch_bounds__(256) void prep_ln12_k(
    const float* s0, const float* s1, const float* s2, const float* s3,
    const float* s4, const float* s5, const float* s6, const float* s7,
    const float* p1w, const float* aw, u16* wdst, u16* apre,
    const float* x, const float* g1, const float* b1,
    const float* g2, const float* b2,
    u16* lnc, u16* ln1o, float* xc, float* xt)
{
  const int bid = blockIdx.x;
  if (bid < 2574)
    allprep_body(s0,s1,s2,s3,s4,s5,s6,s7,p1w,aw,wdst,apre,bid);
  else
    ln12_body(x,g1,b1,g2,b2,lnc,ln1o,xc,xt,bid-2574);
}

// ---------------------------------------------------------------------------
// M1: c12p GEMM (y<7) + qkv GEMM (y>=7)
// ---------------------------------------------------------------------------
__global__ __launch_bounds__(256) void gemm12_k(
    const u16* lnc, const u16* r6, const u16* wc12p, const float* p1b,
    const u16* wqkv, const float* qkvb, u16* pa1, u16* x1g, u16* qkv)
{
  __shared__ __align__(16) unsigned char smem[39936];
  if (blockIdx.y < 7)
    conv_body<0,false,false,false,false,true,true>(smem, lnc, nullptr, 96, wc12p, p1b,
        nullptr, 0, pa1, 16, 96, 400, x1g, blockIdx.x, blockIdx.y);
  else
    conv_body<0,false,false,true,false,true,false>(smem, r6, nullptr, 96, wqkv, qkvb,
        nullptr, 0, qkv, 288, 96, 288, nullptr, blockIdx.x, blockIdx.y-7);
}

// ---------------------------------------------------------------------------
// M2: adaconv (bid<2304) + proj GEMM (288)
// ---------------------------------------------------------------------------
__global__ __launch_bounds__(256) void ada_proj_k(
    const u16* x1g, const u16* x2g, const float* para, const u16* apre,
    const float* dww, u16* outb2,
    const u16* r6, const u16* wproj, const float* projb, float* xt)
{
  __shared__ __align__(16) unsigned char smem[39936];
  const int bid = blockIdx.x;
  if (bid < 2304){
    const int b = bid / 1152, rem = bid - b*1152;
    const int g = rem / 72, reg = rem - g*72;
    adaconv_body(smem, x1g, x2g, para, apre, dww, outb2, b, g, reg);
  } else {
    const int bx = bid - 2304;
    conv_body<0,false,false,true,true,false,false>(smem, r6, nullptr, 96, wproj, projb,
        xt, 96, xt, 96, 96, 96, nullptr, bx % 144, bx / 144);
  }
}

// ---------------------------------------------------------------------------
// M3: c3 GEMM (bid<288) + ln2 (4608)
// ---------------------------------------------------------------------------
__global__ __launch_bounds__(256) void c3_ln2_k(
    const u16* b2b, const u16* wc3, const float* xc, u16* r4,
    const float* xt, const float* g2, const float* bt2, u16* r6)
{
  __shared__ __align__(16) unsigned char smem[39936];
  const int bid = blockIdx.x;
  if (bid < 288)
    conv_body<0,false,false,false,true,true,false>(smem, b2b, nullptr, 192, wc3, nullptr,
        xc, 96, r4, 96, 192, 96, nullptr, bid % 144, bid / 144);
  else
    ln_body(xt, 96, g2, bt2, r6, bid-288);
}

// ---------------------------------------------------------------------------
// K4: depthwise 3x3, bf16 in/out, 4 ch/thread — FFN dw.
// ---------------------------------------------------------------------------
template<bool HASB, bool DOGELU>
__global__ __launch_bounds__(256) void dw3x3_k(const u16* __restrict__ in, int istride,
                                               const float* __restrict__ w,
                                               const float* __restrict__ bias,
                                               u16* __restrict__ out, int C){
  int t = blockIdx.x*256 + threadIdx.x;
  int cg = C >> 2;
  int p = t / cg;
  if (p >= ST) return;
  int c4 = (t - p*cg) << 2;
  int bb = p / HW_, hw = p - bb*HW_;
  int hy = hw / IW, wx = hw - hy*IW;
  float w0[9], w1[9], w2[9], w3[9];
  #pragma unroll
  for (int tp=0;tp<9;tp++){
    w0[tp]=w[(c4+0)*9+tp]; w1[tp]=w[(c4+1)*9+tp]; w2[tp]=w[(c4+2)*9+tp]; w3[tp]=w[(c4+3)*9+tp];
  }
  float ax=0.f, ay=0.f, az=0.f, aw=0.f;
  #pragma unroll
  for (int i=0;i<3;i++){
    int y = hy+i-1;
    if ((unsigned)y >= IH) continue;
    #pragma unroll
    for (int j=0;j<3;j++){
      int x2 = wx+j-1;
      if ((unsigned)x2 >= IW) continue;
      const uint2 r = *(const uint2*)(in + ((size_t)bb*HW_ + y*IW + x2)*istride + c4);
      int tp=i*3+j;
      ax += bfl(r.x)*w0[tp]; ay += bfh(r.x)*w1[tp];
      az += bfl(r.y)*w2[tp]; aw += bfh(r.y)*w3[tp];
    }
  }
  if (HASB){ ax+=bias[c4]; ay+=bias[c4+1]; az+=bias[c4+2]; aw+=bias[c4+3]; }
  if (DOGELU){ ax=gelu_f(ax); ay=gelu_f(ay); az=gelu_f(az); aw=gelu_f(aw); }
  uint2 pk;
  pk.x = f2bf(ax)|(f2bf(ay)<<16);
  pk.y = f2bf(az)|(f2bf(aw)<<16);
  *(uint2*)(out + (size_t)p*C + c4) = pk;
}

// ---------------------------------------------------------------------------
// K5: full 3x3 conv 16->16 (para branch), bf16 in / fp32 out. 4 thr/px.
// ---------------------------------------------------------------------------
__global__ __launch_bounds__(256) void p2conv_k(const u16* __restrict__ in, const float* __restrict__ w,
                                                const float* __restrict__ bias, float* __restrict__ out){
  __shared__ float ws[2304];
  int tid = threadIdx.x;
  for (int i=tid;i<2304;i+=256) ws[i]=w[i];
  __syncthreads();
  int gidx = blockIdx.x*256 + tid;
  int p = gidx >> 2, qq = gidx & 3;
  int bb = p / HW_, hw = p - bb*HW_;
  int hy = hw / IW, wx = hw - hy*IW;
  const int cb = qq<<2;
  float a0=bias[cb], a1=bias[cb+1], a2=bias[cb+2], a3=bias[cb+3];
  #pragma unroll
  for (int i=0;i<3;i++){
    int y=hy+i-1; if ((unsigned)y>=IH) continue;
    #pragma unroll
    for (int j=0;j<3;j++){
      int x2=wx+j-1; if ((unsigned)x2>=IW) continue;
      int tap=i*3+j;
      const uint4 r = *(const uint4*)(in + ((size_t)bb*HW_ + y*IW + x2)*16);
      const uint4 r2 = *(const uint4*)(in + ((size_t)bb*HW_ + y*IW + x2)*16 + 8);
      float vv[16]={bfl(r.x),bfh(r.x),bfl(r.y),bfh(r.y),bfl(r.z),bfh(r.z),bfl(r.w),bfh(r.w),
                    bfl(r2.x),bfh(r2.x),bfl(r2.y),bfh(r2.y),bfl(r2.z),bfh(r2.z),bfl(r2.w),bfh(r2.w)};
      #pragma unroll
      for (int ci=0;ci<16;ci++){
        float v = vv[ci];
        a0 += ws[(cb+0)*144 + ci*9 + tap]*v;
        a1 += ws[(cb+1)*144 + ci*9 + tap]*v;
        a2 += ws[(cb+2)*144 + ci*9 + tap]*v;
        a3 += ws[(cb+3)*144 + ci*9 + tap]*v;
      }
    }
  }
  *(float4*)(out + (size_t)p*16 + cb) = make_float4(a0,a1,a2,a3);
}

// ---------------------------------------------------------------------------
// K7: shifted-window attention, 1 wave per (window, head). bf16 in/out.
// ---------------------------------------------------------------------------
__global__ __launch_bounds__(64) void attn_k(const u16* __restrict__ qkv,
                                             const float* __restrict__ relpos,
                                             u16* __restrict__ outa){
  __shared__ float k_s[2048];
  __shared__ float v_s[2048];
  __shared__ float rel_s[225];
  const int win = blockIdx.x, head = blockIdx.y, b = blockIdx.z;
  const int wi = win/12, wj = win%12;
  const int lane = threadIdx.x;
  for (int i=lane;i<225;i+=64) rel_s[i] = relpos[i*3+head];
  const int pi = lane>>3, pj = lane&7;
  const int hr = wi*8+pi, wr = wj*8+pj;
  const int sh = (hr+4)%96, sw = (wr+4)%96;
  const size_t pix = (size_t)b*HW_ + sh*96 + sw;
  const u16* base = qkv + pix*288;
  const float SC = 0.17677669529663687f;
  float q[32];
  #pragma unroll
  for (int i=0;i<4;i++){
    const uint4 r = *(const uint4*)(base + head*32 + i*8);
    q[i*8+0]=bfl(r.x)*SC; q[i*8+1]=bfh(r.x)*SC;
    q[i*8+2]=bfl(r.y)*SC; q[i*8+3]=bfh(r.y)*SC;
    q[i*8+4]=bfl(r.z)*SC; q[i*8+5]=bfh(r.z)*SC;
    q[i*8+6]=bfl(r.w)*SC; q[i*8+7]=bfh(r.w)*SC;
  }
  #pragma unroll
  for (int i=0;i<4;i++){
    const uint4 rk = *(const uint4*)(base + 96 + head*32 + i*8);
    const uint4 rv = *(const uint4*)(base + 192 + head*32 + i*8);
    *(float4*)&k_s[(lane<<5)+i*8]   = make_float4(bfl(rk.x),bfh(rk.x),bfl(rk.y),bfh(rk.y));
    *(float4*)&k_s[(lane<<5)+i*8+4] = make_float4(bfl(rk.z),bfh(rk.z),bfl(rk.w),bfh(rk.w));
    *(float4*)&v_s[(lane<<5)+i*8]   = make_float4(bfl(rv.x),bfh(rv.x),bfl(rv.y),bfh(rv.y));
    *(float4*)&v_s[(lane<<5)+i*8+4] = make_float4(bfl(rv.z),bfh(rv.z),bfl(rv.w),bfh(rv.w));
  }
  __syncthreads();
  const bool mi = (wi==11), mj = (wj==11);
  float sc[64];
  #pragma unroll
  for (int qq=0; qq<64; qq++){
    const float4* kr4 = (const float4*)&k_s[qq<<5];
    float s = 0.f;
    #pragma unroll
    for (int i=0;i<8;i++){
      const float4 kv = kr4[i];
      s += q[4*i]*kv.x + q[4*i+1]*kv.y + q[4*i+2]*kv.z + q[4*i+3]*kv.w;
    }
    const int qi = qq>>3, qj = qq&7;
    s += rel_s[(pi-qi+7)*15 + (pj-qj+7)];
    const bool msk = (mi && ((pi<4)!=(qi<4))) || (mj && ((pj<4)!=(qj<4)));
    sc[qq] = msk ? -1e30f : s;
  }
  float m = sc[0];
  #pragma unroll
  for (int qq=1;qq<64;qq++) m = fmaxf(m, sc[qq]);
  float sum = 0.f;
  #pragma unroll
  for (int qq=0;qq<64;qq++){ float e = __expf(sc[qq]-m); sc[qq]=e; sum+=e; }
  const float inv = 1.f/sum;
  float acc[32];
  #pragma unroll
  for (int i=0;i<32;i++) acc[i]=0.f;
  #pragma unroll
  for (int qq=0;qq<64;qq++){
    const float a = sc[qq]*inv;
    const float4* vr4 = (const float4*)&v_s[qq<<5];
    #pragma unroll
    for (int i=0;i<8;i++){
      const float4 vv = vr4[i];
      acc[4*i]+=a*vv.x; acc[4*i+1]+=a*vv.y; acc[4*i+2]+=a*vv.z; acc[4*i+3]+=a*vv.w;
    }
  }
  u16* orow = outa + pix*96 + head*32;
  #pragma unroll
  for (int i=0;i<4;i++){
    uint4 pk;
    pk.x = f2bf(acc[i*8+0])|(f2bf(acc[i*8+1])<<16);
    pk.y = f2bf(acc[i*8+2])|(f2bf(acc[i*8+3])<<16);
    pk.z = f2bf(acc[i*8+4])|(f2bf(acc[i*8+5])<<16);
    pk.w = f2bf(acc[i*8+6])|(f2bf(acc[i*8+7])<<16);
    *(uint4*)(orow + i*8) = pk;
  }
}

// ---------------------------------------------------------------------------
extern "C" void kernel_launch(void* const* d_in, const int* in_sizes, int n_in,
                              void* d_out, int out_size, void* d_ws, size_t ws_size,
                              hipStream_t stream)
{
  (void)in_sizes; (void)n_in; (void)out_size; (void)ws_size;
  const float* x        = (const float*)d_in[0];
  const float* cb_ln_g  = (const float*)d_in[1];
  const float* cb_ln_b  = (const float*)d_in[2];
  const float* cb_c1_pw = (const float*)d_in[3];
  const float* cb_c1_dw = (const float*)d_in[4];
  const float* cb_c2_pw = (const float*)d_in[5];
  const float* ada_w    = (const float*)d_in[6];
  const float* ada_p1_w = (const float*)d_in[7];
  const float* ada_p1_b = (const float*)d_in[8];
  const float* ada_p2_w = (const float*)d_in[9];
  const float* ada_p2_b = (const float*)d_in[10];
  const float* cb_c3_w  = (const float*)d_in[11];
  const float* ln1_g    = (const float*)d_in[12];
  const float* ln1_b    = (const float*)d_in[13];
  const float* qkv_w    = (const float*)d_in[14];
  const float* qkv_b    = (const float*)d_in[15];
  const float* rel_pos  = (const float*)d_in[16];
  const float* proj_w   = (const float*)d_in[17];
  const float* proj_b   = (const float*)d_in[18];
  const float* ln2_g    = (const float*)d_in[19];
  const float* ln2_b    = (const float*)d_in[20];
  const float* ffn_w1   = (const float*)d_in[21];
  const float* ffn_b1   = (const float*)d_in[22];
  const float* ffn_dw   = (const float*)d_in[23];
  const float* ffn_db   = (const float*)d_in[24];
  const float* ffn_w2   = (const float*)d_in[25];
  const float* ffn_b2   = (const float*)d_in[26];
  const float* out_w    = (const float*)d_in[27];
  const float* out_b    = (const float*)d_in[28];

  char* wsb = (char*)d_ws;
  // fp32 regions
  float* XC  = (float*)wsb;                                   // ST*96  raw conv residual
  float* U0f = (float*)(wsb + (size_t)ST*96*4);               // ST*288 f32 overlay region
  float* XT  = (float*)(wsb + (size_t)ST*384*4);              // ST*96  transformer residual
  float* PA2 = (float*)(wsb + (size_t)ST*480*4);              // ST*16
  // u16 regions
  u16* B2b  = (u16*)(wsb + (size_t)ST*496*4);                 // ST*192
  u16* LNCb = B2b  + (size_t)ST*192;                          // ST*96
  u16* R4b  = LNCb + (size_t)ST*96;                           // ST*96
  u16* R6b  = R4b  + (size_t)ST*96;                           // ST*96
  u16* PA1b = R6b  + (size_t)ST*96;                           // ST*16
  u16* Wbf  = PA1b + (size_t)ST*16;                           // 167424
  u16* Apre = Wbf + 167424;                                   // 491520
  u16* QKVb = Apre + 491520;                                  // ST*288 (dedicated now)
  // overlays on U0f (capacity ST*576 u16):
  u16* X1G  = (u16*)U0f;                     // ST*192 u16, group-major c1
  u16* X2G  = X1G + (size_t)ST*192;          // ST*192 u16, group-major c2
  u16* FF1b = (u16*)U0f;                     // ST*192 u16 (after adaconv consumed X1G/X2G)
  u16* DWOb = (u16*)U0f + (size_t)ST*192;

  const u16* W_qkv  = Wbf + 0;
  const u16* W_c12p = Wbf + 27648;   // [400][96]: c1, c2, P1eff
  const u16* W_c3   = Wbf + 66048;
  const u16* W_proj = Wbf + 84480;
  const u16* W_ffn1 = Wbf + 93696;
  const u16* W_ffn2 = Wbf + 112128;
  const u16* W_fin  = Wbf + 130560;

  // M0: all weight preps + fused dual LN  (2574 + 576 blocks)
  prep_ln12_k<<<3150, 256, 0, stream>>>(qkv_w, cb_c1_pw, cb_c2_pw, cb_c3_w,
                                        proj_w, ffn_w1, ffn_w2, out_w,
                                        ada_p1_w, ada_w, Wbf, Apre,
                                        x, cb_ln_g, cb_ln_b, ln1_g, ln1_b,
                                        LNCb, R6b, XC, XT);

  // M1: c12p GEMM + qkv GEMM
  gemm12_k<<<dim3(144, 12), 256, 0, stream>>>(LNCb, R6b, W_c12p, ada_p1_b,
                                              W_qkv, qkv_b, PA1b, X1G, QKVb);

  // attention (consumes QKVb, writes R6b)
  attn_k<<<dim3(144, 3, NB), 64, 0, stream>>>(QKVb, rel_pos, R6b);
  // para conv (consumes PA1b)
  p2conv_k<<<(ST*4)/256, 256, 0, stream>>>(PA1b, ada_p2_w, ada_p2_b, PA2);

  // M2: adaconv (+fused dw1) + proj GEMM  (2304 + 288)
  ada_proj_k<<<2592, 256, 0, stream>>>(X1G, X2G, PA2, Apre, cb_c1_dw, B2b,
                                       R6b, W_proj, proj_b, XT);

  // M3: c3 GEMM + ln2  (288 + 4608)
  c3_ln2_k<<<4896, 256, 0, stream>>>(B2b, W_c3, XC, R4b, XT, ln2_g, ln2_b, R6b);

  // FFN chain
  conv_mfma_k<0,false,false,true,false,true,false><<<dim3(144, 3), 256, 0, stream>>>(R6b, nullptr, 96, W_ffn1, ffn_b1, nullptr, 0, FF1b, 192, 96, 192, nullptr);
  dw3x3_k<true,true><<<(ST*48)/256, 256, 0, stream>>>(FF1b, 192, ffn_dw, ffn_db, DWOb, 192);
  conv_mfma_k<0,false,false,true,true,false,false><<<dim3(144, 2), 256, 0, stream>>>(DWOb, nullptr, 192, W_ffn2, ffn_b2, XT, 96, XT, 96, 192, 96, nullptr);

  // final: out = x + conv1x1(concat(convout bf16, xt f32), out_w) + out_b
  conv_mfma_k<0,true,true,true,true,false,false><<<dim3(144, 3), 256, 0, stream>>>(R4b, XT, 96, W_fin, out_b, x, 0, (float*)d_out, 0, 192, 192, nullptr);
}

// Round 12
// 191.698 us; speedup vs baseline: 1.4982x; 1.0799x over previous
//
#include <hip/hip_runtime.h>
#include <math.h>

#define HW_ 9216
#define IH 96
#define IW 96
#define NB 2
#define ST (NB*HW_)   // 18432 pixels total

typedef __attribute__((ext_vector_type(8))) short bf16x8;
typedef __attribute__((ext_vector_type(4))) float f32x4;
typedef unsigned short u16;

__device__ __forceinline__ float gelu_f(float v){
  return 0.5f*v*(1.0f+erff(v*0.70710678118654752440f));
}
__device__ __forceinline__ unsigned f2bf(float f){
  unsigned u = __float_as_uint(f);
  return (u + 0x7FFF + ((u>>16)&1)) >> 16;
}
__device__ __forceinline__ float bfl(unsigned u){ return __uint_as_float(u<<16); }
__device__ __forceinline__ float bfh(unsigned u){ return __uint_as_float(u & 0xffff0000u); }

// ---------------------------------------------------------------------------
// ln12 body: fused dual LayerNorm from NCHW input (32 px per block-index).
// ---------------------------------------------------------------------------
__device__ __forceinline__ void ln12_body(const float* __restrict__ x,
    const float* __restrict__ g1, const float* __restrict__ b1,
    const float* __restrict__ g2, const float* __restrict__ b2,
    u16* __restrict__ lnc, u16* __restrict__ ln1o,
    float* __restrict__ xc, float* __restrict__ xt, int bidx)
{
  __shared__ float t[192][33];
  const int p0 = bidx<<5;
  const int bb = p0/HW_, hw0 = p0 - bb*HW_;
  const int tid = threadIdx.x;
  const int px = tid & 31, cr = tid >> 5;
  const float* xb = x + (size_t)bb*192*HW_ + hw0;
  #pragma unroll
  for (int k=0;k<24;k++){
    int c = cr + k*8;
    t[c][px] = xb[(size_t)c*HW_ + px];
  }
  __syncthreads();
  const int lane = tid&63, wv = tid>>6;
  #pragma unroll 1
  for (int i=0;i<8;i++){
    const int lp = wv*8+i;
    const size_t p = p0 + lp;
    float a0 = t[lane][lp];
    float a1 = (lane<32)? t[64+lane][lp] : 0.f;
    float c0 = t[96+lane][lp];
    float c1 = (lane<32)? t[160+lane][lp] : 0.f;
    float s1=a0+a1, s2=c0+c1;
    #pragma unroll
    for (int o=32;o;o>>=1){ s1+=__shfl_xor(s1,o); s2+=__shfl_xor(s2,o); }
    const float mu1=s1*(1.f/96.f), mu2=s2*(1.f/96.f);
    const float d0=a0-mu1, d1=a1-mu1, e0=c0-mu2, e1=c1-mu2;
    float q1=d0*d0+((lane<32)?d1*d1:0.f), q2=e0*e0+((lane<32)?e1*e1:0.f);
    #pragma unroll
    for (int o=32;o;o>>=1){ q1+=__shfl_xor(q1,o); q2+=__shfl_xor(q2,o); }
    const float r1=rsqrtf(q1*(1.f/96.f)+1e-5f), r2=rsqrtf(q2*(1.f/96.f)+1e-5f);
    lnc [p*96+lane] = (u16)f2bf(d0*r1*g1[lane]+b1[lane]);
    ln1o[p*96+lane] = (u16)f2bf(e0*r2*g2[lane]+b2[lane]);
    xc  [p*96+lane] = a0;
    xt  [p*96+lane] = c0;
    if (lane<32){
      lnc [p*96+64+lane] = (u16)f2bf(d1*r1*g1[64+lane]+b1[64+lane]);
      ln1o[p*96+64+lane] = (u16)f2bf(e1*r2*g2[64+lane]+b2[64+lane]);
      xc  [p*96+64+lane] = a1;
      xt  [p*96+64+lane] = c1;
    }
  }
}

// ---------------------------------------------------------------------------
// ln body: single LayerNorm (fp32 in, bf16 out), 4 px per block-index.
// ---------------------------------------------------------------------------
__device__ __forceinline__ void ln_body(const float* __restrict__ in, int istride,
    const float* __restrict__ gam, const float* __restrict__ bet,
    u16* __restrict__ out, int bidx)
{
  int lane = threadIdx.x & 63;
  int wv   = threadIdx.x >> 6;
  int p    = (bidx << 2) + wv;
  const float* row = in + (size_t)p*istride;
  float v0 = row[lane];
  float v1 = (lane < 32) ? row[64+lane] : 0.0f;
  float s = v0 + v1;
  #pragma unroll
  for (int o=32;o;o>>=1) s += __shfl_xor(s,o);
  float mu = s * (1.0f/96.0f);
  float d0 = v0 - mu;
  float d1 = v1 - mu;
  float qv = d0*d0 + ((lane<32)? d1*d1 : 0.0f);
  #pragma unroll
  for (int o=32;o;o>>=1) qv += __shfl_xor(qv,o);
  float rstd = rsqrtf(qv*(1.0f/96.0f) + 1e-5f);
  u16* orow = out + (size_t)p*96;
  orow[lane] = (u16)f2bf(d0*rstd*gam[lane] + bet[lane]);
  if (lane < 32) orow[64+lane] = (u16)f2bf(d1*rstd*gam[64+lane] + bet[64+lane]);
}

// ---------------------------------------------------------------------------
// conv body: bf16-MFMA conv1x1. 128 px x 64 couts per (bx,by).
// ---------------------------------------------------------------------------
template<int ACT, bool CONCAT, bool FINAL, bool HASB, bool HASR, bool OUTBF, bool SPLIT>
__device__ __forceinline__ void conv_body(unsigned char* smem,
    const u16* __restrict__ in1, const float* __restrict__ in2f, int istride,
    const u16* __restrict__ wbf, const float* __restrict__ bias,
    const float* __restrict__ res, int rstride,
    void* __restrict__ out, int ostride, int Cin, int Cout,
    u16* __restrict__ out2, int bx, int by)
{
  unsigned char* actl = smem;          // [128][208B]
  unsigned char* wl   = smem + 26624;  // [64][208B]
  const int tid=threadIdx.x, lane=tid&63, wv=tid>>6;
  const int lr=lane&15, g4=lane>>4, wm=wv>>1, wn=wv&1;
  const int p0=bx<<7, co0=by<<6;

  f32x4 acc[2][4];
  #pragma unroll
  for (int m=0;m<2;m++)
    #pragma unroll
    for (int n=0;n<4;n++) acc[m][n]=(f32x4){0.f,0.f,0.f,0.f};

  for (int kc=0; kc<Cin; kc+=96){
    {
      const int row=tid>>1, half=tid&1;
      if (!CONCAT || kc==0){
        const u16* rp = in1 + (size_t)(p0+row)*istride + (CONCAT?0:kc) + half*48;
        #pragma unroll
        for (int s=0;s<6;s++)
          *(uint4*)(actl + row*208 + (half*6+s)*16) = *(const uint4*)(rp + s*8);
      } else {
        const float* rp = in2f + (size_t)(p0+row)*96 + half*48;
        #pragma unroll
        for (int s=0;s<6;s++){
          float4 a=*(const float4*)(rp+s*8), b=*(const float4*)(rp+s*8+4);
          uint4 pk;
          pk.x=f2bf(a.x)|(f2bf(a.y)<<16);
          pk.y=f2bf(a.z)|(f2bf(a.w)<<16);
          pk.z=f2bf(b.x)|(f2bf(b.y)<<16);
          pk.w=f2bf(b.z)|(f2bf(b.w)<<16);
          *(uint4*)(actl + row*208 + (half*6+s)*16) = pk;
        }
      }
    }
    {
      const int row=tid&63, grp=tid>>6;
      const int co=co0+row;
      const u16* wr = wbf + (size_t)co*Cin + kc;
      #pragma unroll
      for (int s=0;s<3;s++){
        int sl=grp*3+s;
        uint4 v={0,0,0,0};
        if (co<Cout) v=*(const uint4*)(wr + sl*8);
        *(uint4*)(wl + row*208 + sl*16)=v;
      }
    }
    __syncthreads();
    #pragma unroll
    for (int ks=0;ks<3;ks++){
      const int sl=ks*4+g4;
      bf16x8 afr[2], bfr[4];
      #pragma unroll
      for (int m=0;m<2;m++) afr[m]=*(const bf16x8*)(wl + ((wm*2+m)*16+lr)*208 + sl*16);
      #pragma unroll
      for (int n=0;n<4;n++) bfr[n]=*(const bf16x8*)(actl + (wn*64+n*16+lr)*208 + sl*16);
      #pragma unroll
      for (int m=0;m<2;m++)
        #pragma unroll
        for (int n=0;n<4;n++)
          acc[m][n]=__builtin_amdgcn_mfma_f32_16x16x32_bf16(afr[m], bfr[n], acc[m][n],0,0,0);
    }
    __syncthreads();
  }

  if (FINAL){
    float* outf = (float*)out;
    #pragma unroll
    for (int m=0;m<2;m++){
      const int cb=co0+(wm*2+m)*16+(g4<<2);
      float4 bv = make_float4(0.f,0.f,0.f,0.f);
      if (HASB) bv = *(const float4*)(bias+cb);
      #pragma unroll
      for (int n=0;n<4;n++){
        const int p=p0+wn*64+n*16+lr;
        const int bb=p/HW_, hw=p-bb*HW_;
        const float av[4]={acc[m][n].x,acc[m][n].y,acc[m][n].z,acc[m][n].w};
        const float bvv[4]={bv.x,bv.y,bv.z,bv.w};
        #pragma unroll
        for (int j=0;j<4;j++){
          size_t oi=((size_t)bb*192+cb+j)*HW_+hw;
          outf[oi]=av[j]+bvv[j]+res[oi];
        }
      }
    }
    return;
  }
  float* lt=(float*)smem;
  #pragma unroll
  for (int m=0;m<2;m++)
    #pragma unroll
    for (int n=0;n<4;n++){
      int px=wn*64+n*16+lr;
      int c=(wm*2+m)*16+(g4<<2);
      *(f32x4*)&lt[px*68+c]=acc[m][n];
    }
  __syncthreads();
  {
    const int pr=tid>>1, half=tid&1;
    const int p=p0+pr;
    #pragma unroll
    for (int s=0;s<8;s++){
      int cl=half*32+s*4;
      int co=co0+cl;
      if (co<Cout){
        float4 v=*(float4*)&lt[pr*68+cl];
        if (SPLIT){
          if (co>=384){
            const int c2 = co-384;
            const float4 bv=*(const float4*)(bias+c2);
            v.x=fmaxf(v.x+bv.x,0.f); v.y=fmaxf(v.y+bv.y,0.f);
            v.z=fmaxf(v.z+bv.z,0.f); v.w=fmaxf(v.w+bv.w,0.f);
            uint2 pk;
            pk.x = f2bf(v.x)|(f2bf(v.y)<<16);
            pk.y = f2bf(v.z)|(f2bf(v.w)<<16);
            *(uint2*)((u16*)out + (size_t)p*16 + c2) = pk;
          } else {
            const int cc = (co<192)? co : co-192;
            const int gg = cc/12, cll = cc - gg*12;
            u16* dst = out2 + ((co<192)? (size_t)0 : (size_t)ST*192)
                     + ((size_t)gg*ST + p)*12 + cll;
            uint2 pk;
            pk.x = f2bf(v.x)|(f2bf(v.y)<<16);
            pk.y = f2bf(v.z)|(f2bf(v.w)<<16);
            *(uint2*)dst = pk;
          }
          continue;
        }
        if (HASB){ const float4 bv=*(const float4*)(bias+co); v.x+=bv.x;v.y+=bv.y;v.z+=bv.z;v.w+=bv.w; }
        if (ACT==1){
          v.x=fmaxf(v.x,0.f); v.y=fmaxf(v.y,0.f); v.z=fmaxf(v.z,0.f); v.w=fmaxf(v.w,0.f);
        }
        if (HASR){ const float4 rv=*(const float4*)(res+(size_t)p*rstride+co); v.x+=rv.x;v.y+=rv.y;v.z+=rv.z;v.w+=rv.w; }
        if (OUTBF){
          uint2 pk;
          pk.x = f2bf(v.x)|(f2bf(v.y)<<16);
          pk.y = f2bf(v.z)|(f2bf(v.w)<<16);
          *(uint2*)((u16*)out + (size_t)p*ostride + co) = pk;
        } else {
          *(float4*)((float*)out + (size_t)p*ostride + co) = v;
        }
      }
    }
  }
}

template<int ACT, bool CONCAT, bool FINAL, bool HASB, bool HASR, bool OUTBF, bool SPLIT>
__global__ __launch_bounds__(256) void conv_mfma_k(
    const u16* __restrict__ in1, const float* __restrict__ in2f, int istride,
    const u16* __restrict__ wbf, const float* __restrict__ bias,
    const float* __restrict__ res, int rstride,
    void* __restrict__ out, int ostride, int Cin, int Cout,
    u16* __restrict__ out2)
{
  __shared__ __align__(16) unsigned char smem[39936];
  conv_body<ACT,CONCAT,FINAL,HASB,HASR,OUTBF,SPLIT>(smem, in1, in2f, istride, wbf, bias,
      res, rstride, out, ostride, Cin, Cout, out2, blockIdx.x, blockIdx.y);
}

// ---------------------------------------------------------------------------
// adaconv body: MFMA + fused dw1 (group-major inputs).
// ---------------------------------------------------------------------------
__device__ __forceinline__ void adaconv_body(unsigned char* smem,
    const u16* __restrict__ x1g, const u16* __restrict__ x2g,
    const float* __restrict__ para, const u16* __restrict__ apre,
    const float* __restrict__ dww, u16* __restrict__ outb2,
    int b, int g, int reg)
{
  unsigned char* HB2 = smem;              // x2 halo 18x10 x 48B = 8640
  unsigned char* HB1 = smem + 8640;       // x1 halo 18x10 x 48B = 8640
  float* PS = (float*)(smem + 17280);     // [2 sub][64 px][20] f32 = 10240
  float* OS = (float*)(smem + 27520);     // [2 sub][64 px][12] f32 = 6144
  float* WDW = (float*)(smem + 33664);    // 12ch x 9 taps f32 = 432

  const int tid=threadIdx.x, lane=tid&63, wv=tid>>6;
  const int lr=lane&15, g4=lane>>4;
  const int hi=(lane>>5)&1, lo16=(lane>>4)&1;
  const int rh=(reg/12)<<4, rw=(reg%12)<<3;

  bf16x8 af[3][5];
  {
    const u16* ag = apre + (size_t)g*30720;
    #pragma unroll
    for (int oo=0;oo<3;oo++){
      const int row=(wv*3+oo)*16+lr;
      #pragma unroll
      for (int ks=0;ks<5;ks++)
        af[oo][ks] = *(const bf16x8*)(ag + row*160 + ks*32 + g4*8);
    }
  }
  if (tid < 180){
    int hy = tid/10, hx = tid - hy*10;
    int gy = rh+hy-1, gx = rw+hx-1;
    uint2 a2={0,0},b2={0,0},c2={0,0}, a1={0,0},b1={0,0},c1={0,0};
    if ((unsigned)gy<IH && (unsigned)gx<IW){
      const size_t base = ((size_t)g*ST + (size_t)b*HW_ + gy*IW + gx)*12;
      const u16* s2 = x2g + base;
      a2=*(const uint2*)s2; b2=*(const uint2*)(s2+4); c2=*(const uint2*)(s2+8);
      const u16* s1 = x1g + base;
      a1=*(const uint2*)s1; b1=*(const uint2*)(s1+4); c1=*(const uint2*)(s1+8);
    }
    *(uint4*)(HB2 + tid*48)      = make_uint4(a2.x,a2.y,b2.x,b2.y);
    *(uint4*)(HB2 + tid*48 + 16) = make_uint4(c2.x,c2.y,0,0);
    *(uint4*)(HB1 + tid*48)      = make_uint4(a1.x,a1.y,b1.x,b1.y);
    *(uint4*)(HB1 + tid*48 + 16) = make_uint4(c1.x,c1.y,0,0);
  }
  if (tid < 108) WDW[tid] = dww[g*108 + tid];
  #pragma unroll
  for (int it=0; it<2; ++it){
    int idx = tid + (it<<8);
    int sub = idx >> 8;
    int p = (idx>>2)&63, q = idx&3;
    int gy = rh + (sub<<3) + (p>>3), gx = rw + (p&7);
    float4 v = *(const float4*)(para + ((size_t)b*HW_+gy*IW+gx)*16 + q*4);
    *(float4*)&PS[sub*1280 + p*20 + q*4] = v;
  }
  __syncthreads();

  int tapoff[5];
  tapoff[0] = hi ? 48   : 0;
  tapoff[1] = hi ? 480  : 96;
  tapoff[2] = hi ? 576  : 528;
  tapoff[3] = hi ? 1008 : 960;
  tapoff[4] = 1056;

  #pragma unroll
  for (int sub=0; sub<2; ++sub){
    const int sy = sub<<3;
    const int base0 = ((sy + (lr>>3))*10 + (lr&7))*48 + lo16*16;

    f32x4 acc[3][4];
    #pragma unroll
    for (int oo=0;oo<3;oo++)
      #pragma unroll
      for (int n=0;n<4;n++) acc[oo][n]=(f32x4){0.f,0.f,0.f,0.f};

    #pragma unroll
    for (int ks=0;ks<5;ks++){
      bf16x8 bfr[4];
      #pragma unroll
      for (int n=0;n<4;n++)
        bfr[n] = *(const bf16x8*)(HB2 + base0 + n*960 + tapoff[ks]);
      #pragma unroll
      for (int oo=0;oo<3;oo++)
        #pragma unroll
        for (int n=0;n<4;n++)
          acc[oo][n]=__builtin_amdgcn_mfma_f32_16x16x32_bf16(af[oo][ks], bfr[n], acc[oo][n],0,0,0);
    }

    const float* ps = &PS[sub*1280];
    #pragma unroll
    for (int oo=0;oo<3;oo++){
      const int o=wv*3+oo;
      #pragma unroll
      for (int n=0;n<4;n++){
        const int p=(n<<4)+lr;
        const f32x4 prv = *(const f32x4*)&ps[p*20+(g4<<2)];
        float s=acc[oo][n].x*prv.x+acc[oo][n].y*prv.y+acc[oo][n].z*prv.z+acc[oo][n].w*prv.w;
        s += __shfl_xor(s,16); s += __shfl_xor(s,32);
        if (g4==n) OS[((sub<<6)+p)*12+o] = gelu_f(s);
      }
    }
  }
  __syncthreads();
  {
    const size_t gb = (size_t)b*HW_;
    for (int idx=tid; idx<384; idx+=256){
      const int cq = idx % 3;
      const int rest = idx / 3;
      const int p = rest & 63, sub = rest >> 6;
      const int py = p>>3, px = p&7;
      const int Y = (sub<<3)+py, X = px;
      const unsigned char* hb1 = HB1 + (Y*10+X)*48 + cq*8;
      const float* wd = &WDW[cq*36];
      float v0=0.f,v1=0.f,v2=0.f,v3=0.f;
      #pragma unroll
      for (int i=0;i<3;i++){
        #pragma unroll
        for (int j=0;j<3;j++){
          const uint2 r = *(const uint2*)(hb1 + (i*10+j)*48);
          const int tp=i*3+j;
          v0 += bfl(r.x)*wd[tp];      v1 += bfh(r.x)*wd[9+tp];
          v2 += bfl(r.y)*wd[18+tp];   v3 += bfh(r.y)*wd[27+tp];
        }
      }
      const size_t gi = (gb + (rh+(sub<<3)+py)*IW + (rw+px))*192 + g*12 + cq*4;
      const float* os = &OS[((sub<<6)+p)*12 + cq*4];
      uint2 pk;
      pk.x = f2bf(os[0]*v0) | (f2bf(os[1]*v1)<<16);
      pk.y = f2bf(os[2]*v2) | (f2bf(os[3]*v3)<<16);
      *(uint2*)(outb2 + gi) = pk;
    }
  }
}

// ---------------------------------------------------------------------------
// allprep body (bid roles: [0,648) wcopy, [648,654) P1eff, [654,2574) ada)
// ---------------------------------------------------------------------------
__device__ __forceinline__ void allprep_body(
    const float* __restrict__ s0, const float* __restrict__ s1,
    const float* __restrict__ s2, const float* __restrict__ s3,
    const float* __restrict__ s4, const float* __restrict__ s5,
    const float* __restrict__ s6, const float* __restrict__ s7,
    const float* __restrict__ p1w, const float* __restrict__ aw,
    u16* __restrict__ wdst, u16* __restrict__ apre, int bid)
{
  const int tid = threadIdx.x;
  if (bid < 648){
    const int blks[8]={108,72,72,72,36,72,72,144};
    const int off[8] ={0,27648,46080,66048,84480,93696,112128,130560};
    const int sz[8]  ={27648,18432,18432,18432,9216,18432,18432,36864};
    int m=0, acc=0;
    #pragma unroll
    for (int k=0;k<8;k++){ if (bid >= acc + blks[k]){ acc += blks[k]; m=k+1; } }
    const float* s = (m==0)?s0:(m==1)?s1:(m==2)?s2:(m==3)?s3:(m==4)?s4:(m==5)?s5:(m==6)?s6:s7;
    int i = (bid-acc)*256 + tid;
    if (i < sz[m]) wdst[off[m]+i] = (u16)f2bf(s[i]);
  } else if (bid < 654){
    int i = (bid-648)*256 + tid;
    if (i < 1536){
      int o = i/96, ci = i - o*96;
      float s = 0.f;
      for (int k=0;k<192;k++) s += p1w[o*192+k]*s2[k*96+ci];
      wdst[64512+i] = (u16)f2bf(s);
    }
  } else {
    int E = (bid-654)*256 + tid;
    int g = E / 30720, e = E - g*30720;
    int row = e / 160, kp = e - row*160;
    int tap = kp >> 4, cl = kp & 15;
    int o = row >> 4, r = row & 15;
    float v = 0.f;
    if (tap < 9 && cl < 12)
      v = aw[(((size_t)(g*12+o)*108) + cl*9 + tap)*16 + r];
    apre[(size_t)g*30720 + e] = (u16)f2bf(v);
  }
}

// ---------------------------------------------------------------------------
// M0: allprep (2574) + ln12 (576)
// ---------------------------------------------------------------------------
__global__ __launch_bounds__(256) void prep_ln12_k(
    const float* s0, const float* s1, const float* s2, const float* s3,
    const float* s4, const float* s5, const float* s6, const float* s7,
    const float* p1w, const float* aw, u16* wdst, u16* apre,
    const float* x, const float* g1, const float* b1,
    const float* g2, const float* b2,
    u16* lnc, u16* ln1o, float* xc, float* xt)
{
  const int bid = blockIdx.x;
  if (bid < 2574)
    allprep_body(s0,s1,s2,s3,s4,s5,s6,s7,p1w,aw,wdst,apre,bid);
  else
    ln12_body(x,g1,b1,g2,b2,lnc,ln1o,xc,xt,bid-2574);
}

// ---------------------------------------------------------------------------
// M1: c12p GEMM (y<7) + qkv GEMM (y>=7)
// ---------------------------------------------------------------------------
__global__ __launch_bounds__(256) void gemm12_k(
    const u16* lnc, const u16* r6, const u16* wc12p, const float* p1b,
    const u16* wqkv, const float* qkvb, u16* pa1, u16* x1g, u16* qkv)
{
  __shared__ __align__(16) unsigned char smem[39936];
  if (blockIdx.y < 7)
    conv_body<0,false,false,false,false,true,true>(smem, lnc, nullptr, 96, wc12p, p1b,
        nullptr, 0, pa1, 16, 96, 400, x1g, blockIdx.x, blockIdx.y);
  else
    conv_body<0,false,false,true,false,true,false>(smem, r6, nullptr, 96, wqkv, qkvb,
        nullptr, 0, qkv, 288, 96, 288, nullptr, blockIdx.x, blockIdx.y-7);
}

// ---------------------------------------------------------------------------
// attn body: 1 wave per (window, head). bf16 in/out.
// ---------------------------------------------------------------------------
__device__ __forceinline__ void attn_body(const u16* __restrict__ qkv,
    const float* __restrict__ relpos, u16* __restrict__ outa, int bid)
{
  __shared__ float k_s[2048];
  __shared__ float v_s[2048];
  __shared__ float rel_s[225];
  const int win = bid % 144, head = (bid/144)%3, b = bid/432;
  const int wi = win/12, wj = win%12;
  const int lane = threadIdx.x;
  for (int i=lane;i<225;i+=64) rel_s[i] = relpos[i*3+head];
  const int pi = lane>>3, pj = lane&7;
  const int hr = wi*8+pi, wr = wj*8+pj;
  const int sh = (hr+4)%96, sw = (wr+4)%96;
  const size_t pix = (size_t)b*HW_ + sh*96 + sw;
  const u16* base = qkv + pix*288;
  const float SC = 0.17677669529663687f;
  float q[32];
  #pragma unroll
  for (int i=0;i<4;i++){
    const uint4 r = *(const uint4*)(base + head*32 + i*8);
    q[i*8+0]=bfl(r.x)*SC; q[i*8+1]=bfh(r.x)*SC;
    q[i*8+2]=bfl(r.y)*SC; q[i*8+3]=bfh(r.y)*SC;
    q[i*8+4]=bfl(r.z)*SC; q[i*8+5]=bfh(r.z)*SC;
    q[i*8+6]=bfl(r.w)*SC; q[i*8+7]=bfh(r.w)*SC;
  }
  #pragma unroll
  for (int i=0;i<4;i++){
    const uint4 rk = *(const uint4*)(base + 96 + head*32 + i*8);
    const uint4 rv = *(const uint4*)(base + 192 + head*32 + i*8);
    *(float4*)&k_s[(lane<<5)+i*8]   = make_float4(bfl(rk.x),bfh(rk.x),bfl(rk.y),bfh(rk.y));
    *(float4*)&k_s[(lane<<5)+i*8+4] = make_float4(bfl(rk.z),bfh(rk.z),bfl(rk.w),bfh(rk.w));
    *(float4*)&v_s[(lane<<5)+i*8]   = make_float4(bfl(rv.x),bfh(rv.x),bfl(rv.y),bfh(rv.y));
    *(float4*)&v_s[(lane<<5)+i*8+4] = make_float4(bfl(rv.z),bfh(rv.z),bfl(rv.w),bfh(rv.w));
  }
  __syncthreads();
  const bool mi = (wi==11), mj = (wj==11);
  float sc[64];
  #pragma unroll
  for (int qq=0; qq<64; qq++){
    const float4* kr4 = (const float4*)&k_s[qq<<5];
    float s = 0.f;
    #pragma unroll
    for (int i=0;i<8;i++){
      const float4 kv = kr4[i];
      s += q[4*i]*kv.x + q[4*i+1]*kv.y + q[4*i+2]*kv.z + q[4*i+3]*kv.w;
    }
    const int qi = qq>>3, qj = qq&7;
    s += rel_s[(pi-qi+7)*15 + (pj-qj+7)];
    const bool msk = (mi && ((pi<4)!=(qi<4))) || (mj && ((pj<4)!=(qj<4)));
    sc[qq] = msk ? -1e30f : s;
  }
  float m = sc[0];
  #pragma unroll
  for (int qq=1;qq<64;qq++) m = fmaxf(m, sc[qq]);
  float sum = 0.f;
  #pragma unroll
  for (int qq=0;qq<64;qq++){ float e = __expf(sc[qq]-m); sc[qq]=e; sum+=e; }
  const float inv = 1.f/sum;
  float acc[32];
  #pragma unroll
  for (int i=0;i<32;i++) acc[i]=0.f;
  #pragma unroll
  for (int qq=0;qq<64;qq++){
    const float a = sc[qq]*inv;
    const float4* vr4 = (const float4*)&v_s[qq<<5];
    #pragma unroll
    for (int i=0;i<8;i++){
      const float4 vv = vr4[i];
      acc[4*i]+=a*vv.x; acc[4*i+1]+=a*vv.y; acc[4*i+2]+=a*vv.z; acc[4*i+3]+=a*vv.w;
    }
  }
  u16* orow = outa + pix*96 + head*32;
  #pragma unroll
  for (int i=0;i<4;i++){
    uint4 pk;
    pk.x = f2bf(acc[i*8+0])|(f2bf(acc[i*8+1])<<16);
    pk.y = f2bf(acc[i*8+2])|(f2bf(acc[i*8+3])<<16);
    pk.z = f2bf(acc[i*8+4])|(f2bf(acc[i*8+5])<<16);
    pk.w = f2bf(acc[i*8+6])|(f2bf(acc[i*8+7])<<16);
    *(uint4*)(orow + i*8) = pk;
  }
}

// ---------------------------------------------------------------------------
// p2conv body (64-thread variant): full 3x3 conv 16->16, bf16 in / fp32 out.
// ---------------------------------------------------------------------------
__device__ __forceinline__ void p2conv_body(const u16* __restrict__ in,
    const float* __restrict__ w, const float* __restrict__ bias,
    float* __restrict__ out, int bid)
{
  __shared__ float ws[2304];
  int tid = threadIdx.x;
  for (int i=tid;i<2304;i+=64) ws[i]=w[i];
  __syncthreads();
  int gidx = bid*64 + tid;
  int p = gidx >> 2, qq = gidx & 3;
  int bb = p / HW_, hw = p - bb*HW_;
  int hy = hw / IW, wx = hw - hy*IW;
  const int cb = qq<<2;
  float a0=bias[cb], a1=bias[cb+1], a2=bias[cb+2], a3=bias[cb+3];
  #pragma unroll
  for (int i=0;i<3;i++){
    int y=hy+i-1; if ((unsigned)y>=IH) continue;
    #pragma unroll
    for (int j=0;j<3;j++){
      int x2=wx+j-1; if ((unsigned)x2>=IW) continue;
      int tap=i*3+j;
      const uint4 r = *(const uint4*)(in + ((size_t)bb*HW_ + y*IW + x2)*16);
      const uint4 r2 = *(const uint4*)(in + ((size_t)bb*HW_ + y*IW + x2)*16 + 8);
      float vv[16]={bfl(r.x),bfh(r.x),bfl(r.y),bfh(r.y),bfl(r.z),bfh(r.z),bfl(r.w),bfh(r.w),
                    bfl(r2.x),bfh(r2.x),bfl(r2.y),bfh(r2.y),bfl(r2.z),bfh(r2.z),bfl(r2.w),bfh(r2.w)};
      #pragma unroll
      for (int ci=0;ci<16;ci++){
        float v = vv[ci];
        a0 += ws[(cb+0)*144 + ci*9 + tap]*v;
        a1 += ws[(cb+1)*144 + ci*9 + tap]*v;
        a2 += ws[(cb+2)*144 + ci*9 + tap]*v;
        a3 += ws[(cb+3)*144 + ci*9 + tap]*v;
      }
    }
  }
  *(float4*)(out + (size_t)p*16 + cb) = make_float4(a0,a1,a2,a3);
}

// ---------------------------------------------------------------------------
// M1.5: attn (bid<864) + p2conv (1152 blocks of 64 threads)
// ---------------------------------------------------------------------------
__global__ __launch_bounds__(64) void attn_p2_k(
    const u16* __restrict__ qkv, const float* __restrict__ relpos,
    u16* __restrict__ outa,
    const u16* __restrict__ pa1, const float* __restrict__ p2w,
    const float* __restrict__ p2b, float* __restrict__ pa2)
{
  const int bid = blockIdx.x;
  if (bid < 864) attn_body(qkv, relpos, outa, bid);
  else           p2conv_body(pa1, p2w, p2b, pa2, bid-864);
}

// ---------------------------------------------------------------------------
// M2: adaconv (bid<2304, XCD-locality swizzled) + proj GEMM (288)
// ---------------------------------------------------------------------------
__global__ __launch_bounds__(256) void ada_proj_k(
    const u16* x1g, const u16* x2g, const float* para, const u16* apre,
    const float* dww, u16* outb2,
    const u16* r6, const u16* wproj, const float* projb, float* xt)
{
  __shared__ __align__(16) unsigned char smem[39936];
  const int bid = blockIdx.x;
  if (bid < 2304){
    // XCD-locality swizzle: blocks dispatch round-robin over 8 XCDs (bid%8).
    // Map so each XCD sees only 2 groups -> A slab + halo slab L2-resident.
    const int xcd = bid & 7, j = bid >> 3;
    const int g = xcd + ((j & 1) << 3);
    const int t = j >> 1;                 // 0..143
    const int b = t / 72, reg = t - b*72;
    adaconv_body(smem, x1g, x2g, para, apre, dww, outb2, b, g, reg);
  } else {
    const int bx = bid - 2304;
    conv_body<0,false,false,true,true,false,false>(smem, r6, nullptr, 96, wproj, projb,
        xt, 96, xt, 96, 96, 96, nullptr, bx % 144, bx / 144);
  }
}

// ---------------------------------------------------------------------------
// M3: c3 GEMM (bid<288) + ln2 (4608)
// ---------------------------------------------------------------------------
__global__ __launch_bounds__(256) void c3_ln2_k(
    const u16* b2b, const u16* wc3, const float* xc, u16* r4,
    const float* xt, const float* g2, const float* bt2, u16* r6)
{
  __shared__ __align__(16) unsigned char smem[39936];
  const int bid = blockIdx.x;
  if (bid < 288)
    conv_body<0,false,false,false,true,true,false>(smem, b2b, nullptr, 192, wc3, nullptr,
        xc, 96, r4, 96, 192, 96, nullptr, bid % 144, bid / 144);
  else
    ln_body(xt, 96, g2, bt2, r6, bid-288);
}

// ---------------------------------------------------------------------------
// K4: depthwise 3x3, bf16 in/out, 4 ch/thread — FFN dw.
// ---------------------------------------------------------------------------
template<bool HASB, bool DOGELU>
__global__ __launch_bounds__(256) void dw3x3_k(const u16* __restrict__ in, int istride,
                                               const float* __restrict__ w,
                                               const float* __restrict__ bias,
                                               u16* __restrict__ out, int C){
  int t = blockIdx.x*256 + threadIdx.x;
  int cg = C >> 2;
  int p = t / cg;
  if (p >= ST) return;
  int c4 = (t - p*cg) << 2;
  int bb = p / HW_, hw = p - bb*HW_;
  int hy = hw / IW, wx = hw - hy*IW;
  float w0[9], w1[9], w2[9], w3[9];
  #pragma unroll
  for (int tp=0;tp<9;tp++){
    w0[tp]=w[(c4+0)*9+tp]; w1[tp]=w[(c4+1)*9+tp]; w2[tp]=w[(c4+2)*9+tp]; w3[tp]=w[(c4+3)*9+tp];
  }
  float ax=0.f, ay=0.f, az=0.f, aw=0.f;
  #pragma unroll
  for (int i=0;i<3;i++){
    int y = hy+i-1;
    if ((unsigned)y >= IH) continue;
    #pragma unroll
    for (int j=0;j<3;j++){
      int x2 = wx+j-1;
      if ((unsigned)x2 >= IW) continue;
      const uint2 r = *(const uint2*)(in + ((size_t)bb*HW_ + y*IW + x2)*istride + c4);
      int tp=i*3+j;
      ax += bfl(r.x)*w0[tp]; ay += bfh(r.x)*w1[tp];
      az += bfl(r.y)*w2[tp]; aw += bfh(r.y)*w3[tp];
    }
  }
  if (HASB){ ax+=bias[c4]; ay+=bias[c4+1]; az+=bias[c4+2]; aw+=bias[c4+3]; }
  if (DOGELU){ ax=gelu_f(ax); ay=gelu_f(ay); az=gelu_f(az); aw=gelu_f(aw); }
  uint2 pk;
  pk.x = f2bf(ax)|(f2bf(ay)<<16);
  pk.y = f2bf(az)|(f2bf(aw)<<16);
  *(uint2*)(out + (size_t)p*C + c4) = pk;
}

// ---------------------------------------------------------------------------
extern "C" void kernel_launch(void* const* d_in, const int* in_sizes, int n_in,
                              void* d_out, int out_size, void* d_ws, size_t ws_size,
                              hipStream_t stream)
{
  (void)in_sizes; (void)n_in; (void)out_size; (void)ws_size;
  const float* x        = (const float*)d_in[0];
  const float* cb_ln_g  = (const float*)d_in[1];
  const float* cb_ln_b  = (const float*)d_in[2];
  const float* cb_c1_pw = (const float*)d_in[3];
  const float* cb_c1_dw = (const float*)d_in[4];
  const float* cb_c2_pw = (const float*)d_in[5];
  const float* ada_w    = (const float*)d_in[6];
  const float* ada_p1_w = (const float*)d_in[7];
  const float* ada_p1_b = (const float*)d_in[8];
  const float* ada_p2_w = (const float*)d_in[9];
  const float* ada_p2_b = (const float*)d_in[10];
  const float* cb_c3_w  = (const float*)d_in[11];
  const float* ln1_g    = (const float*)d_in[12];
  const float* ln1_b    = (const float*)d_in[13];
  const float* qkv_w    = (const float*)d_in[14];
  const float* qkv_b    = (const float*)d_in[15];
  const float* rel_pos  = (const float*)d_in[16];
  const float* proj_w   = (const float*)d_in[17];
  const float* proj_b   = (const float*)d_in[18];
  const float* ln2_g    = (const float*)d_in[19];
  const float* ln2_b    = (const float*)d_in[20];
  const float* ffn_w1   = (const float*)d_in[21];
  const float* ffn_b1   = (const float*)d_in[22];
  const float* ffn_dw   = (const float*)d_in[23];
  const float* ffn_db   = (const float*)d_in[24];
  const float* ffn_w2   = (const float*)d_in[25];
  const float* ffn_b2   = (const float*)d_in[26];
  const float* out_w    = (const float*)d_in[27];
  const float* out_b    = (const float*)d_in[28];

  char* wsb = (char*)d_ws;
  // fp32 regions
  float* XC  = (float*)wsb;                                   // ST*96  raw conv residual
  float* U0f = (float*)(wsb + (size_t)ST*96*4);               // ST*288 f32 overlay region
  float* XT  = (float*)(wsb + (size_t)ST*384*4);              // ST*96  transformer residual
  float* PA2 = (float*)(wsb + (size_t)ST*480*4);              // ST*16
  // u16 regions
  u16* B2b  = (u16*)(wsb + (size_t)ST*496*4);                 // ST*192
  u16* LNCb = B2b  + (size_t)ST*192;                          // ST*96
  u16* R4b  = LNCb + (size_t)ST*96;                           // ST*96
  u16* R6b  = R4b  + (size_t)ST*96;                           // ST*96
  u16* PA1b = R6b  + (size_t)ST*96;                           // ST*16
  u16* Wbf  = PA1b + (size_t)ST*16;                           // 167424
  u16* Apre = Wbf + 167424;                                   // 491520
  u16* QKVb = Apre + 491520;                                  // ST*288 (dedicated)
  // overlays on U0f (capacity ST*576 u16):
  u16* X1G  = (u16*)U0f;                     // ST*192 u16, group-major c1
  u16* X2G  = X1G + (size_t)ST*192;          // ST*192 u16, group-major c2
  u16* FF1b = (u16*)U0f;                     // ST*192 u16 (after adaconv consumed X1G/X2G)
  u16* DWOb = (u16*)U0f + (size_t)ST*192;

  const u16* W_qkv  = Wbf + 0;
  const u16* W_c12p = Wbf + 27648;   // [400][96]: c1, c2, P1eff
  const u16* W_c3   = Wbf + 66048;
  const u16* W_proj = Wbf + 84480;
  const u16* W_ffn1 = Wbf + 93696;
  const u16* W_ffn2 = Wbf + 112128;
  const u16* W_fin  = Wbf + 130560;

  // M0: all weight preps + fused dual LN  (2574 + 576 blocks)
  prep_ln12_k<<<3150, 256, 0, stream>>>(qkv_w, cb_c1_pw, cb_c2_pw, cb_c3_w,
                                        proj_w, ffn_w1, ffn_w2, out_w,
                                        ada_p1_w, ada_w, Wbf, Apre,
                                        x, cb_ln_g, cb_ln_b, ln1_g, ln1_b,
                                        LNCb, R6b, XC, XT);

  // M1: c12p GEMM + qkv GEMM
  gemm12_k<<<dim3(144, 12), 256, 0, stream>>>(LNCb, R6b, W_c12p, ada_p1_b,
                                              W_qkv, qkv_b, PA1b, X1G, QKVb);

  // M1.5: attention + para conv (independent; both dep gemm12 only)
  attn_p2_k<<<2016, 64, 0, stream>>>(QKVb, rel_pos, R6b,
                                     PA1b, ada_p2_w, ada_p2_b, PA2);

  // M2: adaconv (+fused dw1, XCD-swizzled) + proj GEMM  (2304 + 288)
  ada_proj_k<<<2592, 256, 0, stream>>>(X1G, X2G, PA2, Apre, cb_c1_dw, B2b,
                                       R6b, W_proj, proj_b, XT);

  // M3: c3 GEMM + ln2  (288 + 4608)
  c3_ln2_k<<<4896, 256, 0, stream>>>(B2b, W_c3, XC, R4b, XT, ln2_g, ln2_b, R6b);

  // FFN chain
  conv_mfma_k<0,false,false,true,false,true,false><<<dim3(144, 3), 256, 0, stream>>>(R6b, nullptr, 96, W_ffn1, ffn_b1, nullptr, 0, FF1b, 192, 96, 192, nullptr);
  dw3x3_k<true,true><<<(ST*48)/256, 256, 0, stream>>>(FF1b, 192, ffn_dw, ffn_db, DWOb, 192);
  conv_mfma_k<0,false,false,true,true,false,false><<<dim3(144, 2), 256, 0, stream>>>(DWOb, nullptr, 192, W_ffn2, ffn_b2, XT, 96, XT, 96, 192, 96, nullptr);

  // final: out = x + conv1x1(concat(convout bf16, xt f32), out_w) + out_b
  conv_mfma_k<0,true,true,true,true,false,false><<<dim3(144, 3), 256, 0, stream>>>(R4b, XT, 96, W_fin, out_b, x, 0, (float*)d_out, 0, 192, 192, nullptr);
}

// Round 13
// 190.895 us; speedup vs baseline: 1.5045x; 1.0042x over previous
//
#include <hip/hip_runtime.h>
#include <math.h>

#define HW_ 9216
#define IH 96
#define IW 96
#define NB 2
#define ST (NB*HW_)   // 18432 pixels total

typedef __attribute__((ext_vector_type(8))) short bf16x8;
typedef __attribute__((ext_vector_type(4))) float f32x4;
typedef unsigned short u16;

__device__ __forceinline__ float gelu_f(float v){
  return 0.5f*v*(1.0f+erff(v*0.70710678118654752440f));
}
__device__ __forceinline__ unsigned f2bf(float f){
  unsigned u = __float_as_uint(f);
  return (u + 0x7FFF + ((u>>16)&1)) >> 16;
}
__device__ __forceinline__ float bfl(unsigned u){ return __uint_as_float(u<<16); }
__device__ __forceinline__ float bfh(unsigned u){ return __uint_as_float(u & 0xffff0000u); }

// ---------------------------------------------------------------------------
// ln12 body: fused dual LayerNorm from NCHW input (32 px per block-index).
// ---------------------------------------------------------------------------
__device__ __forceinline__ void ln12_body(const float* __restrict__ x,
    const float* __restrict__ g1, const float* __restrict__ b1,
    const float* __restrict__ g2, const float* __restrict__ b2,
    u16* __restrict__ lnc, u16* __restrict__ ln1o,
    float* __restrict__ xc, float* __restrict__ xt, int bidx)
{
  __shared__ float t[192][33];
  const int p0 = bidx<<5;
  const int bb = p0/HW_, hw0 = p0 - bb*HW_;
  const int tid = threadIdx.x;
  const int px = tid & 31, cr = tid >> 5;
  const float* xb = x + (size_t)bb*192*HW_ + hw0;
  #pragma unroll
  for (int k=0;k<24;k++){
    int c = cr + k*8;
    t[c][px] = xb[(size_t)c*HW_ + px];
  }
  __syncthreads();
  const int lane = tid&63, wv = tid>>6;
  #pragma unroll 1
  for (int i=0;i<8;i++){
    const int lp = wv*8+i;
    const size_t p = p0 + lp;
    float a0 = t[lane][lp];
    float a1 = (lane<32)? t[64+lane][lp] : 0.f;
    float c0 = t[96+lane][lp];
    float c1 = (lane<32)? t[160+lane][lp] : 0.f;
    float s1=a0+a1, s2=c0+c1;
    #pragma unroll
    for (int o=32;o;o>>=1){ s1+=__shfl_xor(s1,o); s2+=__shfl_xor(s2,o); }
    const float mu1=s1*(1.f/96.f), mu2=s2*(1.f/96.f);
    const float d0=a0-mu1, d1=a1-mu1, e0=c0-mu2, e1=c1-mu2;
    float q1=d0*d0+((lane<32)?d1*d1:0.f), q2=e0*e0+((lane<32)?e1*e1:0.f);
    #pragma unroll
    for (int o=32;o;o>>=1){ q1+=__shfl_xor(q1,o); q2+=__shfl_xor(q2,o); }
    const float r1=rsqrtf(q1*(1.f/96.f)+1e-5f), r2=rsqrtf(q2*(1.f/96.f)+1e-5f);
    lnc [p*96+lane] = (u16)f2bf(d0*r1*g1[lane]+b1[lane]);
    ln1o[p*96+lane] = (u16)f2bf(e0*r2*g2[lane]+b2[lane]);
    xc  [p*96+lane] = a0;
    xt  [p*96+lane] = c0;
    if (lane<32){
      lnc [p*96+64+lane] = (u16)f2bf(d1*r1*g1[64+lane]+b1[64+lane]);
      ln1o[p*96+64+lane] = (u16)f2bf(e1*r2*g2[64+lane]+b2[64+lane]);
      xc  [p*96+64+lane] = a1;
      xt  [p*96+64+lane] = c1;
    }
  }
}

// ---------------------------------------------------------------------------
// ln body: single LayerNorm (fp32 in, bf16 out), 4 px per block-index.
// ---------------------------------------------------------------------------
__device__ __forceinline__ void ln_body(const float* __restrict__ in, int istride,
    const float* __restrict__ gam, const float* __restrict__ bet,
    u16* __restrict__ out, int bidx)
{
  int lane = threadIdx.x & 63;
  int wv   = threadIdx.x >> 6;
  int p    = (bidx << 2) + wv;
  const float* row = in + (size_t)p*istride;
  float v0 = row[lane];
  float v1 = (lane < 32) ? row[64+lane] : 0.0f;
  float s = v0 + v1;
  #pragma unroll
  for (int o=32;o;o>>=1) s += __shfl_xor(s,o);
  float mu = s * (1.0f/96.0f);
  float d0 = v0 - mu;
  float d1 = v1 - mu;
  float qv = d0*d0 + ((lane<32)? d1*d1 : 0.0f);
  #pragma unroll
  for (int o=32;o;o>>=1) qv += __shfl_xor(qv,o);
  float rstd = rsqrtf(qv*(1.0f/96.0f) + 1e-5f);
  u16* orow = out + (size_t)p*96;
  orow[lane] = (u16)f2bf(d0*rstd*gam[lane] + bet[lane]);
  if (lane < 32) orow[64+lane] = (u16)f2bf(d1*rstd*gam[64+lane] + bet[64+lane]);
}

// ---------------------------------------------------------------------------
// conv body: bf16-MFMA conv1x1. 128 px x 64 couts per (bx,by).
// ---------------------------------------------------------------------------
template<int ACT, bool CONCAT, bool FINAL, bool HASB, bool HASR, bool OUTBF, bool SPLIT>
__device__ __forceinline__ void conv_body(unsigned char* smem,
    const u16* __restrict__ in1, const float* __restrict__ in2f, int istride,
    const u16* __restrict__ wbf, const float* __restrict__ bias,
    const float* __restrict__ res, int rstride,
    void* __restrict__ out, int ostride, int Cin, int Cout,
    u16* __restrict__ out2, int bx, int by)
{
  unsigned char* actl = smem;          // [128][208B]
  unsigned char* wl   = smem + 26624;  // [64][208B]
  const int tid=threadIdx.x, lane=tid&63, wv=tid>>6;
  const int lr=lane&15, g4=lane>>4, wm=wv>>1, wn=wv&1;
  const int p0=bx<<7, co0=by<<6;

  f32x4 acc[2][4];
  #pragma unroll
  for (int m=0;m<2;m++)
    #pragma unroll
    for (int n=0;n<4;n++) acc[m][n]=(f32x4){0.f,0.f,0.f,0.f};

  for (int kc=0; kc<Cin; kc+=96){
    {
      const int row=tid>>1, half=tid&1;
      if (!CONCAT || kc==0){
        const u16* rp = in1 + (size_t)(p0+row)*istride + (CONCAT?0:kc) + half*48;
        #pragma unroll
        for (int s=0;s<6;s++)
          *(uint4*)(actl + row*208 + (half*6+s)*16) = *(const uint4*)(rp + s*8);
      } else {
        const float* rp = in2f + (size_t)(p0+row)*96 + half*48;
        #pragma unroll
        for (int s=0;s<6;s++){
          float4 a=*(const float4*)(rp+s*8), b=*(const float4*)(rp+s*8+4);
          uint4 pk;
          pk.x=f2bf(a.x)|(f2bf(a.y)<<16);
          pk.y=f2bf(a.z)|(f2bf(a.w)<<16);
          pk.z=f2bf(b.x)|(f2bf(b.y)<<16);
          pk.w=f2bf(b.z)|(f2bf(b.w)<<16);
          *(uint4*)(actl + row*208 + (half*6+s)*16) = pk;
        }
      }
    }
    {
      const int row=tid&63, grp=tid>>6;
      const int co=co0+row;
      const u16* wr = wbf + (size_t)co*Cin + kc;
      #pragma unroll
      for (int s=0;s<3;s++){
        int sl=grp*3+s;
        uint4 v={0,0,0,0};
        if (co<Cout) v=*(const uint4*)(wr + sl*8);
        *(uint4*)(wl + row*208 + sl*16)=v;
      }
    }
    __syncthreads();
    #pragma unroll
    for (int ks=0;ks<3;ks++){
      const int sl=ks*4+g4;
      bf16x8 afr[2], bfr[4];
      #pragma unroll
      for (int m=0;m<2;m++) afr[m]=*(const bf16x8*)(wl + ((wm*2+m)*16+lr)*208 + sl*16);
      #pragma unroll
      for (int n=0;n<4;n++) bfr[n]=*(const bf16x8*)(actl + (wn*64+n*16+lr)*208 + sl*16);
      #pragma unroll
      for (int m=0;m<2;m++)
        #pragma unroll
        for (int n=0;n<4;n++)
          acc[m][n]=__builtin_amdgcn_mfma_f32_16x16x32_bf16(afr[m], bfr[n], acc[m][n],0,0,0);
    }
    __syncthreads();
  }

  if (FINAL){
    float* outf = (float*)out;
    #pragma unroll
    for (int m=0;m<2;m++){
      const int cb=co0+(wm*2+m)*16+(g4<<2);
      float4 bv = make_float4(0.f,0.f,0.f,0.f);
      if (HASB) bv = *(const float4*)(bias+cb);
      #pragma unroll
      for (int n=0;n<4;n++){
        const int p=p0+wn*64+n*16+lr;
        const int bb=p/HW_, hw=p-bb*HW_;
        const float av[4]={acc[m][n].x,acc[m][n].y,acc[m][n].z,acc[m][n].w};
        const float bvv[4]={bv.x,bv.y,bv.z,bv.w};
        #pragma unroll
        for (int j=0;j<4;j++){
          size_t oi=((size_t)bb*192+cb+j)*HW_+hw;
          outf[oi]=av[j]+bvv[j]+res[oi];
        }
      }
    }
    return;
  }
  float* lt=(float*)smem;
  #pragma unroll
  for (int m=0;m<2;m++)
    #pragma unroll
    for (int n=0;n<4;n++){
      int px=wn*64+n*16+lr;
      int c=(wm*2+m)*16+(g4<<2);
      *(f32x4*)&lt[px*68+c]=acc[m][n];
    }
  __syncthreads();
  {
    const int pr=tid>>1, half=tid&1;
    const int p=p0+pr;
    #pragma unroll
    for (int s=0;s<8;s++){
      int cl=half*32+s*4;
      int co=co0+cl;
      if (co<Cout){
        float4 v=*(float4*)&lt[pr*68+cl];
        if (SPLIT){
          if (co>=384){
            const int c2 = co-384;
            const float4 bv=*(const float4*)(bias+c2);
            v.x=fmaxf(v.x+bv.x,0.f); v.y=fmaxf(v.y+bv.y,0.f);
            v.z=fmaxf(v.z+bv.z,0.f); v.w=fmaxf(v.w+bv.w,0.f);
            uint2 pk;
            pk.x = f2bf(v.x)|(f2bf(v.y)<<16);
            pk.y = f2bf(v.z)|(f2bf(v.w)<<16);
            *(uint2*)((u16*)out + (size_t)p*16 + c2) = pk;
          } else {
            const int cc = (co<192)? co : co-192;
            const int gg = cc/12, cll = cc - gg*12;
            u16* dst = out2 + ((co<192)? (size_t)0 : (size_t)ST*192)
                     + ((size_t)gg*ST + p)*12 + cll;
            uint2 pk;
            pk.x = f2bf(v.x)|(f2bf(v.y)<<16);
            pk.y = f2bf(v.z)|(f2bf(v.w)<<16);
            *(uint2*)dst = pk;
          }
          continue;
        }
        if (HASB){ const float4 bv=*(const float4*)(bias+co); v.x+=bv.x;v.y+=bv.y;v.z+=bv.z;v.w+=bv.w; }
        if (ACT==1){
          v.x=fmaxf(v.x,0.f); v.y=fmaxf(v.y,0.f); v.z=fmaxf(v.z,0.f); v.w=fmaxf(v.w,0.f);
        }
        if (HASR){ const float4 rv=*(const float4*)(res+(size_t)p*rstride+co); v.x+=rv.x;v.y+=rv.y;v.z+=rv.z;v.w+=rv.w; }
        if (OUTBF){
          uint2 pk;
          pk.x = f2bf(v.x)|(f2bf(v.y)<<16);
          pk.y = f2bf(v.z)|(f2bf(v.w)<<16);
          *(uint2*)((u16*)out + (size_t)p*ostride + co) = pk;
        } else {
          *(float4*)((float*)out + (size_t)p*ostride + co) = v;
        }
      }
    }
  }
}

template<int ACT, bool CONCAT, bool FINAL, bool HASB, bool HASR, bool OUTBF, bool SPLIT>
__global__ __launch_bounds__(256) void conv_mfma_k(
    const u16* __restrict__ in1, const float* __restrict__ in2f, int istride,
    const u16* __restrict__ wbf, const float* __restrict__ bias,
    const float* __restrict__ res, int rstride,
    void* __restrict__ out, int ostride, int Cin, int Cout,
    u16* __restrict__ out2)
{
  __shared__ __align__(16) unsigned char smem[39936];
  conv_body<ACT,CONCAT,FINAL,HASB,HASR,OUTBF,SPLIT>(smem, in1, in2f, istride, wbf, bias,
      res, rstride, out, ostride, Cin, Cout, out2, blockIdx.x, blockIdx.y);
}

// ---------------------------------------------------------------------------
// adaconv body: MFMA + fused dw1 (group-major inputs).
// LDS-pipe optimized: prv hoisted out of oo loop; WDW transposed [tap][12ch]
// so the dw epilogue reads one f32x4 per tap; setprio around MFMA.
// ---------------------------------------------------------------------------
__device__ __forceinline__ void adaconv_body(unsigned char* smem,
    const u16* __restrict__ x1g, const u16* __restrict__ x2g,
    const float* __restrict__ para, const u16* __restrict__ apre,
    const float* __restrict__ dww, u16* __restrict__ outb2,
    int b, int g, int reg)
{
  unsigned char* HB2 = smem;              // x2 halo 18x10 x 48B = 8640
  unsigned char* HB1 = smem + 8640;       // x1 halo 18x10 x 48B = 8640
  float* PS = (float*)(smem + 17280);     // [2 sub][64 px][20] f32 = 10240
  float* OS = (float*)(smem + 27520);     // [2 sub][64 px][12] f32 = 6144
  float* WDW = (float*)(smem + 33664);    // [9 taps][12 ch] f32 = 432

  const int tid=threadIdx.x, lane=tid&63, wv=tid>>6;
  const int lr=lane&15, g4=lane>>4;
  const int hi=(lane>>5)&1, lo16=(lane>>4)&1;
  const int rh=(reg/12)<<4, rw=(reg%12)<<3;

  bf16x8 af[3][5];
  {
    const u16* ag = apre + (size_t)g*30720;
    #pragma unroll
    for (int oo=0;oo<3;oo++){
      const int row=(wv*3+oo)*16+lr;
      #pragma unroll
      for (int ks=0;ks<5;ks++)
        af[oo][ks] = *(const bf16x8*)(ag + row*160 + ks*32 + g4*8);
    }
  }
  if (tid < 180){
    int hy = tid/10, hx = tid - hy*10;
    int gy = rh+hy-1, gx = rw+hx-1;
    uint2 a2={0,0},b2={0,0},c2={0,0}, a1={0,0},b1={0,0},c1={0,0};
    if ((unsigned)gy<IH && (unsigned)gx<IW){
      const size_t base = ((size_t)g*ST + (size_t)b*HW_ + gy*IW + gx)*12;
      const u16* s2 = x2g + base;
      a2=*(const uint2*)s2; b2=*(const uint2*)(s2+4); c2=*(const uint2*)(s2+8);
      const u16* s1 = x1g + base;
      a1=*(const uint2*)s1; b1=*(const uint2*)(s1+4); c1=*(const uint2*)(s1+8);
    }
    *(uint4*)(HB2 + tid*48)      = make_uint4(a2.x,a2.y,b2.x,b2.y);
    *(uint4*)(HB2 + tid*48 + 16) = make_uint4(c2.x,c2.y,0,0);
    *(uint4*)(HB1 + tid*48)      = make_uint4(a1.x,a1.y,b1.x,b1.y);
    *(uint4*)(HB1 + tid*48 + 16) = make_uint4(c1.x,c1.y,0,0);
  }
  if (tid < 108){
    const int ch = tid/9, tp = tid - ch*9;
    WDW[tp*12 + ch] = dww[g*108 + tid];     // transpose to [tap][ch]
  }
  #pragma unroll
  for (int it=0; it<2; ++it){
    int idx = tid + (it<<8);
    int sub = idx >> 8;
    int p = (idx>>2)&63, q = idx&3;
    int gy = rh + (sub<<3) + (p>>3), gx = rw + (p&7);
    float4 v = *(const float4*)(para + ((size_t)b*HW_+gy*IW+gx)*16 + q*4);
    *(float4*)&PS[sub*1280 + p*20 + q*4] = v;
  }
  __syncthreads();

  int tapoff[5];
  tapoff[0] = hi ? 48   : 0;
  tapoff[1] = hi ? 480  : 96;
  tapoff[2] = hi ? 576  : 528;
  tapoff[3] = hi ? 1008 : 960;
  tapoff[4] = 1056;

  #pragma unroll
  for (int sub=0; sub<2; ++sub){
    const int sy = sub<<3;
    const int base0 = ((sy + (lr>>3))*10 + (lr&7))*48 + lo16*16;

    f32x4 acc[3][4];
    #pragma unroll
    for (int oo=0;oo<3;oo++)
      #pragma unroll
      for (int n=0;n<4;n++) acc[oo][n]=(f32x4){0.f,0.f,0.f,0.f};

    __builtin_amdgcn_s_setprio(1);
    #pragma unroll
    for (int ks=0;ks<5;ks++){
      bf16x8 bfr[4];
      #pragma unroll
      for (int n=0;n<4;n++)
        bfr[n] = *(const bf16x8*)(HB2 + base0 + n*960 + tapoff[ks]);
      #pragma unroll
      for (int oo=0;oo<3;oo++)
        #pragma unroll
        for (int n=0;n<4;n++)
          acc[oo][n]=__builtin_amdgcn_mfma_f32_16x16x32_bf16(af[oo][ks], bfr[n], acc[oo][n],0,0,0);
    }
    __builtin_amdgcn_s_setprio(0);

    const float* ps = &PS[sub*1280];
    f32x4 prv[4];
    #pragma unroll
    for (int n=0;n<4;n++)
      prv[n] = *(const f32x4*)&ps[((n<<4)+lr)*20+(g4<<2)];
    #pragma unroll
    for (int oo=0;oo<3;oo++){
      const int o=wv*3+oo;
      #pragma unroll
      for (int n=0;n<4;n++){
        const int p=(n<<4)+lr;
        float s=acc[oo][n].x*prv[n].x+acc[oo][n].y*prv[n].y+acc[oo][n].z*prv[n].z+acc[oo][n].w*prv[n].w;
        s += __shfl_xor(s,16); s += __shfl_xor(s,32);
        if (g4==n) OS[((sub<<6)+p)*12+o] = gelu_f(s);
      }
    }
  }
  __syncthreads();
  {
    const size_t gb = (size_t)b*HW_;
    for (int idx=tid; idx<384; idx+=256){
      const int cq = idx % 3;
      const int rest = idx / 3;
      const int p = rest & 63, sub = rest >> 6;
      const int py = p>>3, px = p&7;
      const int Y = (sub<<3)+py, X = px;
      const unsigned char* hb1 = HB1 + (Y*10+X)*48 + cq*8;
      float v0=0.f,v1=0.f,v2=0.f,v3=0.f;
      #pragma unroll
      for (int i=0;i<3;i++){
        #pragma unroll
        for (int j=0;j<3;j++){
          const uint2 r = *(const uint2*)(hb1 + (i*10+j)*48);
          const int tp=i*3+j;
          const f32x4 wv4 = *(const f32x4*)&WDW[tp*12 + cq*4];
          v0 += bfl(r.x)*wv4.x;   v1 += bfh(r.x)*wv4.y;
          v2 += bfl(r.y)*wv4.z;   v3 += bfh(r.y)*wv4.w;
        }
      }
      const size_t gi = (gb + (rh+(sub<<3)+py)*IW + (rw+px))*192 + g*12 + cq*4;
      const float* os = &OS[((sub<<6)+p)*12 + cq*4];
      uint2 pk;
      pk.x = f2bf(os[0]*v0) | (f2bf(os[1]*v1)<<16);
      pk.y = f2bf(os[2]*v2) | (f2bf(os[3]*v3)<<16);
      *(uint2*)(outb2 + gi) = pk;
    }
  }
}

// ---------------------------------------------------------------------------
// allprep body (bid roles: [0,648) wcopy, [648,654) P1eff, [654,2574) ada)
// ---------------------------------------------------------------------------
__device__ __forceinline__ void allprep_body(
    const float* __restrict__ s0, const float* __restrict__ s1,
    const float* __restrict__ s2, const float* __restrict__ s3,
    const float* __restrict__ s4, const float* __restrict__ s5,
    const float* __restrict__ s6, const float* __restrict__ s7,
    const float* __restrict__ p1w, const float* __restrict__ aw,
    u16* __restrict__ wdst, u16* __restrict__ apre, int bid)
{
  const int tid = threadIdx.x;
  if (bid < 648){
    const int blks[8]={108,72,72,72,36,72,72,144};
    const int off[8] ={0,27648,46080,66048,84480,93696,112128,130560};
    const int sz[8]  ={27648,18432,18432,18432,9216,18432,18432,36864};
    int m=0, acc=0;
    #pragma unroll
    for (int k=0;k<8;k++){ if (bid >= acc + blks[k]){ acc += blks[k]; m=k+1; } }
    const float* s = (m==0)?s0:(m==1)?s1:(m==2)?s2:(m==3)?s3:(m==4)?s4:(m==5)?s5:(m==6)?s6:s7;
    int i = (bid-acc)*256 + tid;
    if (i < sz[m]) wdst[off[m]+i] = (u16)f2bf(s[i]);
  } else if (bid < 654){
    int i = (bid-648)*256 + tid;
    if (i < 1536){
      int o = i/96, ci = i - o*96;
      float s = 0.f;
      for (int k=0;k<192;k++) s += p1w[o*192+k]*s2[k*96+ci];
      wdst[64512+i] = (u16)f2bf(s);
    }
  } else {
    int E = (bid-654)*256 + tid;
    int g = E / 30720, e = E - g*30720;
    int row = e / 160, kp = e - row*160;
    int tap = kp >> 4, cl = kp & 15;
    int o = row >> 4, r = row & 15;
    float v = 0.f;
    if (tap < 9 && cl < 12)
      v = aw[(((size_t)(g*12+o)*108) + cl*9 + tap)*16 + r];
    apre[(size_t)g*30720 + e] = (u16)f2bf(v);
  }
}

// ---------------------------------------------------------------------------
// M0: allprep (2574) + ln12 (576)
// ---------------------------------------------------------------------------
__global__ __launch_bounds__(256) void prep_ln12_k(
    const float* s0, const float* s1, const float* s2, const float* s3,
    const float* s4, const float* s5, const float* s6, const float* s7,
    const float* p1w, const float* aw, u16* wdst, u16* apre,
    const float* x, const float* g1, const float* b1,
    const float* g2, const float* b2,
    u16* lnc, u16* ln1o, float* xc, float* xt)
{
  const int bid = blockIdx.x;
  if (bid < 2574)
    allprep_body(s0,s1,s2,s3,s4,s5,s6,s7,p1w,aw,wdst,apre,bid);
  else
    ln12_body(x,g1,b1,g2,b2,lnc,ln1o,xc,xt,bid-2574);
}

// ---------------------------------------------------------------------------
// M1: c12p GEMM (y<7) + qkv GEMM (y>=7)
// ---------------------------------------------------------------------------
__global__ __launch_bounds__(256) void gemm12_k(
    const u16* lnc, const u16* r6, const u16* wc12p, const float* p1b,
    const u16* wqkv, const float* qkvb, u16* pa1, u16* x1g, u16* qkv)
{
  __shared__ __align__(16) unsigned char smem[39936];
  if (blockIdx.y < 7)
    conv_body<0,false,false,false,false,true,true>(smem, lnc, nullptr, 96, wc12p, p1b,
        nullptr, 0, pa1, 16, 96, 400, x1g, blockIdx.x, blockIdx.y);
  else
    conv_body<0,false,false,true,false,true,false>(smem, r6, nullptr, 96, wqkv, qkvb,
        nullptr, 0, qkv, 288, 96, 288, nullptr, blockIdx.x, blockIdx.y-7);
}

// ---------------------------------------------------------------------------
// attn body: 1 wave per (window, head). bf16 in/out.
// ---------------------------------------------------------------------------
__device__ __forceinline__ void attn_body(const u16* __restrict__ qkv,
    const float* __restrict__ relpos, u16* __restrict__ outa, int bid)
{
  __shared__ float k_s[2048];
  __shared__ float v_s[2048];
  __shared__ float rel_s[225];
  const int win = bid % 144, head = (bid/144)%3, b = bid/432;
  const int wi = win/12, wj = win%12;
  const int lane = threadIdx.x;
  for (int i=lane;i<225;i+=64) rel_s[i] = relpos[i*3+head];
  const int pi = lane>>3, pj = lane&7;
  const int hr = wi*8+pi, wr = wj*8+pj;
  const int sh = (hr+4)%96, sw = (wr+4)%96;
  const size_t pix = (size_t)b*HW_ + sh*96 + sw;
  const u16* base = qkv + pix*288;
  const float SC = 0.17677669529663687f;
  float q[32];
  #pragma unroll
  for (int i=0;i<4;i++){
    const uint4 r = *(const uint4*)(base + head*32 + i*8);
    q[i*8+0]=bfl(r.x)*SC; q[i*8+1]=bfh(r.x)*SC;
    q[i*8+2]=bfl(r.y)*SC; q[i*8+3]=bfh(r.y)*SC;
    q[i*8+4]=bfl(r.z)*SC; q[i*8+5]=bfh(r.z)*SC;
    q[i*8+6]=bfl(r.w)*SC; q[i*8+7]=bfh(r.w)*SC;
  }
  #pragma unroll
  for (int i=0;i<4;i++){
    const uint4 rk = *(const uint4*)(base + 96 + head*32 + i*8);
    const uint4 rv = *(const uint4*)(base + 192 + head*32 + i*8);
    *(float4*)&k_s[(lane<<5)+i*8]   = make_float4(bfl(rk.x),bfh(rk.x),bfl(rk.y),bfh(rk.y));
    *(float4*)&k_s[(lane<<5)+i*8+4] = make_float4(bfl(rk.z),bfh(rk.z),bfl(rk.w),bfh(rk.w));
    *(float4*)&v_s[(lane<<5)+i*8]   = make_float4(bfl(rv.x),bfh(rv.x),bfl(rv.y),bfh(rv.y));
    *(float4*)&v_s[(lane<<5)+i*8+4] = make_float4(bfl(rv.z),bfh(rv.z),bfl(rv.w),bfh(rv.w));
  }
  __syncthreads();
  const bool mi = (wi==11), mj = (wj==11);
  float sc[64];
  #pragma unroll
  for (int qq=0; qq<64; qq++){
    const float4* kr4 = (const float4*)&k_s[qq<<5];
    float s = 0.f;
    #pragma unroll
    for (int i=0;i<8;i++){
      const float4 kv = kr4[i];
      s += q[4*i]*kv.x + q[4*i+1]*kv.y + q[4*i+2]*kv.z + q[4*i+3]*kv.w;
    }
    const int qi = qq>>3, qj = qq&7;
    s += rel_s[(pi-qi+7)*15 + (pj-qj+7)];
    const bool msk = (mi && ((pi<4)!=(qi<4))) || (mj && ((pj<4)!=(qj<4)));
    sc[qq] = msk ? -1e30f : s;
  }
  float m = sc[0];
  #pragma unroll
  for (int qq=1;qq<64;qq++) m = fmaxf(m, sc[qq]);
  float sum = 0.f;
  #pragma unroll
  for (int qq=0;qq<64;qq++){ float e = __expf(sc[qq]-m); sc[qq]=e; sum+=e; }
  const float inv = 1.f/sum;
  float acc[32];
  #pragma unroll
  for (int i=0;i<32;i++) acc[i]=0.f;
  #pragma unroll
  for (int qq=0;qq<64;qq++){
    const float a = sc[qq]*inv;
    const float4* vr4 = (const float4*)&v_s[qq<<5];
    #pragma unroll
    for (int i=0;i<8;i++){
      const float4 vv = vr4[i];
      acc[4*i]+=a*vv.x; acc[4*i+1]+=a*vv.y; acc[4*i+2]+=a*vv.z; acc[4*i+3]+=a*vv.w;
    }
  }
  u16* orow = outa + pix*96 + head*32;
  #pragma unroll
  for (int i=0;i<4;i++){
    uint4 pk;
    pk.x = f2bf(acc[i*8+0])|(f2bf(acc[i*8+1])<<16);
    pk.y = f2bf(acc[i*8+2])|(f2bf(acc[i*8+3])<<16);
    pk.z = f2bf(acc[i*8+4])|(f2bf(acc[i*8+5])<<16);
    pk.w = f2bf(acc[i*8+6])|(f2bf(acc[i*8+7])<<16);
    *(uint4*)(orow + i*8) = pk;
  }
}

// ---------------------------------------------------------------------------
// p2conv body (64-thread variant): full 3x3 conv 16->16, bf16 in / fp32 out.
// ---------------------------------------------------------------------------
__device__ __forceinline__ void p2conv_body(const u16* __restrict__ in,
    const float* __restrict__ w, const float* __restrict__ bias,
    float* __restrict__ out, int bid)
{
  __shared__ float ws[2304];
  int tid = threadIdx.x;
  for (int i=tid;i<2304;i+=64) ws[i]=w[i];
  __syncthreads();
  int gidx = bid*64 + tid;
  int p = gidx >> 2, qq = gidx & 3;
  int bb = p / HW_, hw = p - bb*HW_;
  int hy = hw / IW, wx = hw - hy*IW;
  const int cb = qq<<2;
  float a0=bias[cb], a1=bias[cb+1], a2=bias[cb+2], a3=bias[cb+3];
  #pragma unroll
  for (int i=0;i<3;i++){
    int y=hy+i-1; if ((unsigned)y>=IH) continue;
    #pragma unroll
    for (int j=0;j<3;j++){
      int x2=wx+j-1; if ((unsigned)x2>=IW) continue;
      int tap=i*3+j;
      const uint4 r = *(const uint4*)(in + ((size_t)bb*HW_ + y*IW + x2)*16);
      const uint4 r2 = *(const uint4*)(in + ((size_t)bb*HW_ + y*IW + x2)*16 + 8);
      float vv[16]={bfl(r.x),bfh(r.x),bfl(r.y),bfh(r.y),bfl(r.z),bfh(r.z),bfl(r.w),bfh(r.w),
                    bfl(r2.x),bfh(r2.x),bfl(r2.y),bfh(r2.y),bfl(r2.z),bfh(r2.z),bfl(r2.w),bfh(r2.w)};
      #pragma unroll
      for (int ci=0;ci<16;ci++){
        float v = vv[ci];
        a0 += ws[(cb+0)*144 + ci*9 + tap]*v;
        a1 += ws[(cb+1)*144 + ci*9 + tap]*v;
        a2 += ws[(cb+2)*144 + ci*9 + tap]*v;
        a3 += ws[(cb+3)*144 + ci*9 + tap]*v;
      }
    }
  }
  *(float4*)(out + (size_t)p*16 + cb) = make_float4(a0,a1,a2,a3);
}

// ---------------------------------------------------------------------------
// M1.5: attn (bid<864) + p2conv (1152 blocks of 64 threads)
// ---------------------------------------------------------------------------
__global__ __launch_bounds__(64) void attn_p2_k(
    const u16* __restrict__ qkv, const float* __restrict__ relpos,
    u16* __restrict__ outa,
    const u16* __restrict__ pa1, const float* __restrict__ p2w,
    const float* __restrict__ p2b, float* __restrict__ pa2)
{
  const int bid = blockIdx.x;
  if (bid < 864) attn_body(qkv, relpos, outa, bid);
  else           p2conv_body(pa1, p2w, p2b, pa2, bid-864);
}

// ---------------------------------------------------------------------------
// M2: adaconv (bid<2304, XCD-locality swizzled) + proj GEMM (288)
// ---------------------------------------------------------------------------
__global__ __launch_bounds__(256) void ada_proj_k(
    const u16* x1g, const u16* x2g, const float* para, const u16* apre,
    const float* dww, u16* outb2,
    const u16* r6, const u16* wproj, const float* projb, float* xt)
{
  __shared__ __align__(16) unsigned char smem[39936];
  const int bid = blockIdx.x;
  if (bid < 2304){
    const int xcd = bid & 7, j = bid >> 3;
    const int g = xcd + ((j & 1) << 3);
    const int t = j >> 1;                 // 0..143
    const int b = t / 72, reg = t - b*72;
    adaconv_body(smem, x1g, x2g, para, apre, dww, outb2, b, g, reg);
  } else {
    const int bx = bid - 2304;
    conv_body<0,false,false,true,true,false,false>(smem, r6, nullptr, 96, wproj, projb,
        xt, 96, xt, 96, 96, 96, nullptr, bx % 144, bx / 144);
  }
}

// ---------------------------------------------------------------------------
// M3: c3 GEMM (bid<288) + ln2 (4608)
// ---------------------------------------------------------------------------
__global__ __launch_bounds__(256) void c3_ln2_k(
    const u16* b2b, const u16* wc3, const float* xc, u16* r4,
    const float* xt, const float* g2, const float* bt2, u16* r6)
{
  __shared__ __align__(16) unsigned char smem[39936];
  const int bid = blockIdx.x;
  if (bid < 288)
    conv_body<0,false,false,false,true,true,false>(smem, b2b, nullptr, 192, wc3, nullptr,
        xc, 96, r4, 96, 192, 96, nullptr, bid % 144, bid / 144);
  else
    ln_body(xt, 96, g2, bt2, r6, bid-288);
}

// ---------------------------------------------------------------------------
// K4: depthwise 3x3, bf16 in/out, 4 ch/thread — FFN dw.
// ---------------------------------------------------------------------------
template<bool HASB, bool DOGELU>
__global__ __launch_bounds__(256) void dw3x3_k(const u16* __restrict__ in, int istride,
                                               const float* __restrict__ w,
                                               const float* __restrict__ bias,
                                               u16* __restrict__ out, int C){
  int t = blockIdx.x*256 + threadIdx.x;
  int cg = C >> 2;
  int p = t / cg;
  if (p >= ST) return;
  int c4 = (t - p*cg) << 2;
  int bb = p / HW_, hw = p - bb*HW_;
  int hy = hw / IW, wx = hw - hy*IW;
  float w0[9], w1[9], w2[9], w3[9];
  #pragma unroll
  for (int tp=0;tp<9;tp++){
    w0[tp]=w[(c4+0)*9+tp]; w1[tp]=w[(c4+1)*9+tp]; w2[tp]=w[(c4+2)*9+tp]; w3[tp]=w[(c4+3)*9+tp];
  }
  float ax=0.f, ay=0.f, az=0.f, aw=0.f;
  #pragma unroll
  for (int i=0;i<3;i++){
    int y = hy+i-1;
    if ((unsigned)y >= IH) continue;
    #pragma unroll
    for (int j=0;j<3;j++){
      int x2 = wx+j-1;
      if ((unsigned)x2 >= IW) continue;
      const uint2 r = *(const uint2*)(in + ((size_t)bb*HW_ + y*IW + x2)*istride + c4);
      int tp=i*3+j;
      ax += bfl(r.x)*w0[tp]; ay += bfh(r.x)*w1[tp];
      az += bfl(r.y)*w2[tp]; aw += bfh(r.y)*w3[tp];
    }
  }
  if (HASB){ ax+=bias[c4]; ay+=bias[c4+1]; az+=bias[c4+2]; aw+=bias[c4+3]; }
  if (DOGELU){ ax=gelu_f(ax); ay=gelu_f(ay); az=gelu_f(az); aw=gelu_f(aw); }
  uint2 pk;
  pk.x = f2bf(ax)|(f2bf(ay)<<16);
  pk.y = f2bf(az)|(f2bf(aw)<<16);
  *(uint2*)(out + (size_t)p*C + c4) = pk;
}

// ---------------------------------------------------------------------------
extern "C" void kernel_launch(void* const* d_in, const int* in_sizes, int n_in,
                              void* d_out, int out_size, void* d_ws, size_t ws_size,
                              hipStream_t stream)
{
  (void)in_sizes; (void)n_in; (void)out_size; (void)ws_size;
  const float* x        = (const float*)d_in[0];
  const float* cb_ln_g  = (const float*)d_in[1];
  const float* cb_ln_b  = (const float*)d_in[2];
  const float* cb_c1_pw = (const float*)d_in[3];
  const float* cb_c1_dw = (const float*)d_in[4];
  const float* cb_c2_pw = (const float*)d_in[5];
  const float* ada_w    = (const float*)d_in[6];
  const float* ada_p1_w = (const float*)d_in[7];
  const float* ada_p1_b = (const float*)d_in[8];
  const float* ada_p2_w = (const float*)d_in[9];
  const float* ada_p2_b = (const float*)d_in[10];
  const float* cb_c3_w  = (const float*)d_in[11];
  const float* ln1_g    = (const float*)d_in[12];
  const float* ln1_b    = (const float*)d_in[13];
  const float* qkv_w    = (const float*)d_in[14];
  const float* qkv_b    = (const float*)d_in[15];
  const float* rel_pos  = (const float*)d_in[16];
  const float* proj_w   = (const float*)d_in[17];
  const float* proj_b   = (const float*)d_in[18];
  const float* ln2_g    = (const float*)d_in[19];
  const float* ln2_b    = (const float*)d_in[20];
  const float* ffn_w1   = (const float*)d_in[21];
  const float* ffn_b1   = (const float*)d_in[22];
  const float* ffn_dw   = (const float*)d_in[23];
  const float* ffn_db   = (const float*)d_in[24];
  const float* ffn_w2   = (const float*)d_in[25];
  const float* ffn_b2   = (const float*)d_in[26];
  const float* out_w    = (const float*)d_in[27];
  const float* out_b    = (const float*)d_in[28];

  char* wsb = (char*)d_ws;
  // fp32 regions
  float* XC  = (float*)wsb;                                   // ST*96  raw conv residual
  float* U0f = (float*)(wsb + (size_t)ST*96*4);               // ST*288 f32 overlay region
  float* XT  = (float*)(wsb + (size_t)ST*384*4);              // ST*96  transformer residual
  float* PA2 = (float*)(wsb + (size_t)ST*480*4);              // ST*16
  // u16 regions
  u16* B2b  = (u16*)(wsb + (size_t)ST*496*4);                 // ST*192
  u16* LNCb = B2b  + (size_t)ST*192;                          // ST*96
  u16* R4b  = LNCb + (size_t)ST*96;                           // ST*96
  u16* R6b  = R4b  + (size_t)ST*96;                           // ST*96
  u16* PA1b = R6b  + (size_t)ST*96;                           // ST*16
  u16* Wbf  = PA1b + (size_t)ST*16;                           // 167424
  u16* Apre = Wbf + 167424;                                   // 491520
  u16* QKVb = Apre + 491520;                                  // ST*288 (dedicated)
  // overlays on U0f (capacity ST*576 u16):
  u16* X1G  = (u16*)U0f;                     // ST*192 u16, group-major c1
  u16* X2G  = X1G + (size_t)ST*192;          // ST*192 u16, group-major c2
  u16* FF1b = (u16*)U0f;                     // ST*192 u16 (after adaconv consumed X1G/X2G)
  u16* DWOb = (u16*)U0f + (size_t)ST*192;

  const u16* W_qkv  = Wbf + 0;
  const u16* W_c12p = Wbf + 27648;   // [400][96]: c1, c2, P1eff
  const u16* W_c3   = Wbf + 66048;
  const u16* W_proj = Wbf + 84480;
  const u16* W_ffn1 = Wbf + 93696;
  const u16* W_ffn2 = Wbf + 112128;
  const u16* W_fin  = Wbf + 130560;

  // M0: all weight preps + fused dual LN  (2574 + 576 blocks)
  prep_ln12_k<<<3150, 256, 0, stream>>>(qkv_w, cb_c1_pw, cb_c2_pw, cb_c3_w,
                                        proj_w, ffn_w1, ffn_w2, out_w,
                                        ada_p1_w, ada_w, Wbf, Apre,
                                        x, cb_ln_g, cb_ln_b, ln1_g, ln1_b,
                                        LNCb, R6b, XC, XT);

  // M1: c12p GEMM + qkv GEMM
  gemm12_k<<<dim3(144, 12), 256, 0, stream>>>(LNCb, R6b, W_c12p, ada_p1_b,
                                              W_qkv, qkv_b, PA1b, X1G, QKVb);

  // M1.5: attention + para conv (independent; both dep gemm12 only)
  attn_p2_k<<<2016, 64, 0, stream>>>(QKVb, rel_pos, R6b,
                                     PA1b, ada_p2_w, ada_p2_b, PA2);

  // M2: adaconv (+fused dw1, XCD-swizzled) + proj GEMM  (2304 + 288)
  ada_proj_k<<<2592, 256, 0, stream>>>(X1G, X2G, PA2, Apre, cb_c1_dw, B2b,
                                       R6b, W_proj, proj_b, XT);

  // M3: c3 GEMM + ln2  (288 + 4608)
  c3_ln2_k<<<4896, 256, 0, stream>>>(B2b, W_c3, XC, R4b, XT, ln2_g, ln2_b, R6b);

  // FFN chain
  conv_mfma_k<0,false,false,true,false,true,false><<<dim3(144, 3), 256, 0, stream>>>(R6b, nullptr, 96, W_ffn1, ffn_b1, nullptr, 0, FF1b, 192, 96, 192, nullptr);
  dw3x3_k<true,true><<<(ST*48)/256, 256, 0, stream>>>(FF1b, 192, ffn_dw, ffn_db, DWOb, 192);
  conv_mfma_k<0,false,false,true,true,false,false><<<dim3(144, 2), 256, 0, stream>>>(DWOb, nullptr, 192, W_ffn2, ffn_b2, XT, 96, XT, 96, 192, 96, nullptr);

  // final: out = x + conv1x1(concat(convout bf16, xt f32), out_w) + out_b
  conv_mfma_k<0,true,true,true,true,false,false><<<dim3(144, 3), 256, 0, stream>>>(R4b, XT, 96, W_fin, out_b, x, 0, (float*)d_out, 0, 192, 192, nullptr);
}

// Round 14
// 188.119 us; speedup vs baseline: 1.5267x; 1.0148x over previous
//
#include <hip/hip_runtime.h>
#include <math.h>

#define HW_ 9216
#define IH 96
#define IW 96
#define NB 2
#define ST (NB*HW_)   // 18432 pixels total

typedef __attribute__((ext_vector_type(8))) short bf16x8;
typedef __attribute__((ext_vector_type(4))) float f32x4;
typedef unsigned short u16;

__device__ __forceinline__ float gelu_f(float v){
  return 0.5f*v*(1.0f+erff(v*0.70710678118654752440f));
}
__device__ __forceinline__ unsigned f2bf(float f){
  unsigned u = __float_as_uint(f);
  return (u + 0x7FFF + ((u>>16)&1)) >> 16;
}
__device__ __forceinline__ float bfl(unsigned u){ return __uint_as_float(u<<16); }
__device__ __forceinline__ float bfh(unsigned u){ return __uint_as_float(u & 0xffff0000u); }

// ---------------------------------------------------------------------------
// ln12 body: fused dual LayerNorm from NCHW input (32 px per block-index).
// ---------------------------------------------------------------------------
__device__ __forceinline__ void ln12_body(const float* __restrict__ x,
    const float* __restrict__ g1, const float* __restrict__ b1,
    const float* __restrict__ g2, const float* __restrict__ b2,
    u16* __restrict__ lnc, u16* __restrict__ ln1o,
    float* __restrict__ xc, float* __restrict__ xt, int bidx)
{
  __shared__ float t[192][33];
  const int p0 = bidx<<5;
  const int bb = p0/HW_, hw0 = p0 - bb*HW_;
  const int tid = threadIdx.x;
  const int px = tid & 31, cr = tid >> 5;
  const float* xb = x + (size_t)bb*192*HW_ + hw0;
  #pragma unroll
  for (int k=0;k<24;k++){
    int c = cr + k*8;
    t[c][px] = xb[(size_t)c*HW_ + px];
  }
  __syncthreads();
  const int lane = tid&63, wv = tid>>6;
  #pragma unroll 1
  for (int i=0;i<8;i++){
    const int lp = wv*8+i;
    const size_t p = p0 + lp;
    float a0 = t[lane][lp];
    float a1 = (lane<32)? t[64+lane][lp] : 0.f;
    float c0 = t[96+lane][lp];
    float c1 = (lane<32)? t[160+lane][lp] : 0.f;
    float s1=a0+a1, s2=c0+c1;
    #pragma unroll
    for (int o=32;o;o>>=1){ s1+=__shfl_xor(s1,o); s2+=__shfl_xor(s2,o); }
    const float mu1=s1*(1.f/96.f), mu2=s2*(1.f/96.f);
    const float d0=a0-mu1, d1=a1-mu1, e0=c0-mu2, e1=c1-mu2;
    float q1=d0*d0+((lane<32)?d1*d1:0.f), q2=e0*e0+((lane<32)?e1*e1:0.f);
    #pragma unroll
    for (int o=32;o;o>>=1){ q1+=__shfl_xor(q1,o); q2+=__shfl_xor(q2,o); }
    const float r1=rsqrtf(q1*(1.f/96.f)+1e-5f), r2=rsqrtf(q2*(1.f/96.f)+1e-5f);
    lnc [p*96+lane] = (u16)f2bf(d0*r1*g1[lane]+b1[lane]);
    ln1o[p*96+lane] = (u16)f2bf(e0*r2*g2[lane]+b2[lane]);
    xc  [p*96+lane] = a0;
    xt  [p*96+lane] = c0;
    if (lane<32){
      lnc [p*96+64+lane] = (u16)f2bf(d1*r1*g1[64+lane]+b1[64+lane]);
      ln1o[p*96+64+lane] = (u16)f2bf(e1*r2*g2[64+lane]+b2[64+lane]);
      xc  [p*96+64+lane] = a1;
      xt  [p*96+64+lane] = c1;
    }
  }
}

// ---------------------------------------------------------------------------
// ln body: single LayerNorm (fp32 in, bf16 out), 4 px per block-index.
// ---------------------------------------------------------------------------
__device__ __forceinline__ void ln_body(const float* __restrict__ in, int istride,
    const float* __restrict__ gam, const float* __restrict__ bet,
    u16* __restrict__ out, int bidx)
{
  int lane = threadIdx.x & 63;
  int wv   = threadIdx.x >> 6;
  int p    = (bidx << 2) + wv;
  const float* row = in + (size_t)p*istride;
  float v0 = row[lane];
  float v1 = (lane < 32) ? row[64+lane] : 0.0f;
  float s = v0 + v1;
  #pragma unroll
  for (int o=32;o;o>>=1) s += __shfl_xor(s,o);
  float mu = s * (1.0f/96.0f);
  float d0 = v0 - mu;
  float d1 = v1 - mu;
  float qv = d0*d0 + ((lane<32)? d1*d1 : 0.0f);
  #pragma unroll
  for (int o=32;o;o>>=1) qv += __shfl_xor(qv,o);
  float rstd = rsqrtf(qv*(1.0f/96.0f) + 1e-5f);
  u16* orow = out + (size_t)p*96;
  orow[lane] = (u16)f2bf(d0*rstd*gam[lane] + bet[lane]);
  if (lane < 32) orow[64+lane] = (u16)f2bf(d1*rstd*gam[64+lane] + bet[64+lane]);
}

// ---------------------------------------------------------------------------
// conv body: bf16-MFMA conv1x1. 128 px x 64 couts per (bx,by).
// GMAJOR: in1 is 16 group-major slabs [(g*ST+p)*12] (used by c3).
// ---------------------------------------------------------------------------
template<int ACT, bool CONCAT, bool FINAL, bool HASB, bool HASR, bool OUTBF, bool SPLIT, bool GMAJOR>
__device__ __forceinline__ void conv_body(unsigned char* smem,
    const u16* __restrict__ in1, const float* __restrict__ in2f, int istride,
    const u16* __restrict__ wbf, const float* __restrict__ bias,
    const float* __restrict__ res, int rstride,
    void* __restrict__ out, int ostride, int Cin, int Cout,
    u16* __restrict__ out2, int bx, int by)
{
  unsigned char* actl = smem;          // [128][208B]
  unsigned char* wl   = smem + 26624;  // [64][208B]
  const int tid=threadIdx.x, lane=tid&63, wv=tid>>6;
  const int lr=lane&15, g4=lane>>4, wm=wv>>1, wn=wv&1;
  const int p0=bx<<7, co0=by<<6;

  f32x4 acc[2][4];
  #pragma unroll
  for (int m=0;m<2;m++)
    #pragma unroll
    for (int n=0;n<4;n++) acc[m][n]=(f32x4){0.f,0.f,0.f,0.f};

  for (int kc=0; kc<Cin; kc+=96){
    {
      const int row=tid>>1, half=tid&1;
      if (GMAJOR){
        const int g0 = (kc + half*48)/12;
        #pragma unroll
        for (int gg=0; gg<4; ++gg){
          const u16* gp = in1 + ((size_t)(g0+gg)*ST + p0+row)*12;
          uint2 w0=*(const uint2*)gp, w1=*(const uint2*)(gp+4), w2=*(const uint2*)(gp+8);
          unsigned char* dst = actl + row*208 + (half*48 + gg*12)*2;
          *(uint2*)dst = w0; *(uint2*)(dst+8) = w1; *(uint2*)(dst+16) = w2;
        }
      } else if (!CONCAT || kc==0){
        const u16* rp = in1 + (size_t)(p0+row)*istride + (CONCAT?0:kc) + half*48;
        #pragma unroll
        for (int s=0;s<6;s++)
          *(uint4*)(actl + row*208 + (half*6+s)*16) = *(const uint4*)(rp + s*8);
      } else {
        const float* rp = in2f + (size_t)(p0+row)*96 + half*48;
        #pragma unroll
        for (int s=0;s<6;s++){
          float4 a=*(const float4*)(rp+s*8), b=*(const float4*)(rp+s*8+4);
          uint4 pk;
          pk.x=f2bf(a.x)|(f2bf(a.y)<<16);
          pk.y=f2bf(a.z)|(f2bf(a.w)<<16);
          pk.z=f2bf(b.x)|(f2bf(b.y)<<16);
          pk.w=f2bf(b.z)|(f2bf(b.w)<<16);
          *(uint4*)(actl + row*208 + (half*6+s)*16) = pk;
        }
      }
    }
    {
      const int row=tid&63, grp=tid>>6;
      const int co=co0+row;
      const u16* wr = wbf + (size_t)co*Cin + kc;
      #pragma unroll
      for (int s=0;s<3;s++){
        int sl=grp*3+s;
        uint4 v={0,0,0,0};
        if (co<Cout) v=*(const uint4*)(wr + sl*8);
        *(uint4*)(wl + row*208 + sl*16)=v;
      }
    }
    __syncthreads();
    #pragma unroll
    for (int ks=0;ks<3;ks++){
      const int sl=ks*4+g4;
      bf16x8 afr[2], bfr[4];
      #pragma unroll
      for (int m=0;m<2;m++) afr[m]=*(const bf16x8*)(wl + ((wm*2+m)*16+lr)*208 + sl*16);
      #pragma unroll
      for (int n=0;n<4;n++) bfr[n]=*(const bf16x8*)(actl + (wn*64+n*16+lr)*208 + sl*16);
      #pragma unroll
      for (int m=0;m<2;m++)
        #pragma unroll
        for (int n=0;n<4;n++)
          acc[m][n]=__builtin_amdgcn_mfma_f32_16x16x32_bf16(afr[m], bfr[n], acc[m][n],0,0,0);
    }
    __syncthreads();
  }

  if (FINAL){
    float* outf = (float*)out;
    #pragma unroll
    for (int m=0;m<2;m++){
      const int cb=co0+(wm*2+m)*16+(g4<<2);
      float4 bv = make_float4(0.f,0.f,0.f,0.f);
      if (HASB) bv = *(const float4*)(bias+cb);
      #pragma unroll
      for (int n=0;n<4;n++){
        const int p=p0+wn*64+n*16+lr;
        const int bb=p/HW_, hw=p-bb*HW_;
        const float av[4]={acc[m][n].x,acc[m][n].y,acc[m][n].z,acc[m][n].w};
        const float bvv[4]={bv.x,bv.y,bv.z,bv.w};
        #pragma unroll
        for (int j=0;j<4;j++){
          size_t oi=((size_t)bb*192+cb+j)*HW_+hw;
          outf[oi]=av[j]+bvv[j]+res[oi];
        }
      }
    }
    return;
  }
  float* lt=(float*)smem;
  #pragma unroll
  for (int m=0;m<2;m++)
    #pragma unroll
    for (int n=0;n<4;n++){
      int px=wn*64+n*16+lr;
      int c=(wm*2+m)*16+(g4<<2);
      *(f32x4*)&lt[px*68+c]=acc[m][n];
    }
  __syncthreads();
  {
    const int pr=tid>>1, half=tid&1;
    const int p=p0+pr;
    #pragma unroll
    for (int s=0;s<8;s++){
      int cl=half*32+s*4;
      int co=co0+cl;
      if (co<Cout){
        float4 v=*(float4*)&lt[pr*68+cl];
        if (SPLIT){
          if (co>=384){
            const int c2 = co-384;
            const float4 bv=*(const float4*)(bias+c2);
            v.x=fmaxf(v.x+bv.x,0.f); v.y=fmaxf(v.y+bv.y,0.f);
            v.z=fmaxf(v.z+bv.z,0.f); v.w=fmaxf(v.w+bv.w,0.f);
            uint2 pk;
            pk.x = f2bf(v.x)|(f2bf(v.y)<<16);
            pk.y = f2bf(v.z)|(f2bf(v.w)<<16);
            *(uint2*)((u16*)out + (size_t)p*16 + c2) = pk;
          } else {
            const int cc = (co<192)? co : co-192;
            const int gg = cc/12, cll = cc - gg*12;
            u16* dst = out2 + ((co<192)? (size_t)0 : (size_t)ST*192)
                     + ((size_t)gg*ST + p)*12 + cll;
            uint2 pk;
            pk.x = f2bf(v.x)|(f2bf(v.y)<<16);
            pk.y = f2bf(v.z)|(f2bf(v.w)<<16);
            *(uint2*)dst = pk;
          }
          continue;
        }
        if (HASB){ const float4 bv=*(const float4*)(bias+co); v.x+=bv.x;v.y+=bv.y;v.z+=bv.z;v.w+=bv.w; }
        if (ACT==1){
          v.x=fmaxf(v.x,0.f); v.y=fmaxf(v.y,0.f); v.z=fmaxf(v.z,0.f); v.w=fmaxf(v.w,0.f);
        }
        if (HASR){ const float4 rv=*(const float4*)(res+(size_t)p*rstride+co); v.x+=rv.x;v.y+=rv.y;v.z+=rv.z;v.w+=rv.w; }
        if (OUTBF){
          uint2 pk;
          pk.x = f2bf(v.x)|(f2bf(v.y)<<16);
          pk.y = f2bf(v.z)|(f2bf(v.w)<<16);
          *(uint2*)((u16*)out + (size_t)p*ostride + co) = pk;
        } else {
          *(float4*)((float*)out + (size_t)p*ostride + co) = v;
        }
      }
    }
  }
}

template<int ACT, bool CONCAT, bool FINAL, bool HASB, bool HASR, bool OUTBF, bool SPLIT, bool GMAJOR>
__global__ __launch_bounds__(256) void conv_mfma_k(
    const u16* __restrict__ in1, const float* __restrict__ in2f, int istride,
    const u16* __restrict__ wbf, const float* __restrict__ bias,
    const float* __restrict__ res, int rstride,
    void* __restrict__ out, int ostride, int Cin, int Cout,
    u16* __restrict__ out2)
{
  __shared__ __align__(16) unsigned char smem[39936];
  conv_body<ACT,CONCAT,FINAL,HASB,HASR,OUTBF,SPLIT,GMAJOR>(smem, in1, in2f, istride, wbf, bias,
      res, rstride, out, ostride, Cin, Cout, out2, blockIdx.x, blockIdx.y);
}

// ---------------------------------------------------------------------------
// adaconv body: MFMA + fused dw1 (group-major inputs AND group-major output).
// ---------------------------------------------------------------------------
__device__ __forceinline__ void adaconv_body(unsigned char* smem,
    const u16* __restrict__ x1g, const u16* __restrict__ x2g,
    const float* __restrict__ para, const u16* __restrict__ apre,
    const float* __restrict__ dww, u16* __restrict__ outb2,
    int b, int g, int reg)
{
  unsigned char* HB2 = smem;              // x2 halo 18x10 x 48B = 8640
  unsigned char* HB1 = smem + 8640;       // x1 halo 18x10 x 48B = 8640
  float* PS = (float*)(smem + 17280);     // [2 sub][64 px][20] f32 = 10240
  float* OS = (float*)(smem + 27520);     // [2 sub][64 px][12] f32 = 6144
  float* WDW = (float*)(smem + 33664);    // [9 taps][12 ch] f32 = 432

  const int tid=threadIdx.x, lane=tid&63, wv=tid>>6;
  const int lr=lane&15, g4=lane>>4;
  const int hi=(lane>>5)&1, lo16=(lane>>4)&1;
  const int rh=(reg/12)<<4, rw=(reg%12)<<3;

  bf16x8 af[3][5];
  {
    const u16* ag = apre + (size_t)g*30720;
    #pragma unroll
    for (int oo=0;oo<3;oo++){
      const int row=(wv*3+oo)*16+lr;
      #pragma unroll
      for (int ks=0;ks<5;ks++)
        af[oo][ks] = *(const bf16x8*)(ag + row*160 + ks*32 + g4*8);
    }
  }
  if (tid < 180){
    int hy = tid/10, hx = tid - hy*10;
    int gy = rh+hy-1, gx = rw+hx-1;
    uint2 a2={0,0},b2={0,0},c2={0,0}, a1={0,0},b1={0,0},c1={0,0};
    if ((unsigned)gy<IH && (unsigned)gx<IW){
      const size_t base = ((size_t)g*ST + (size_t)b*HW_ + gy*IW + gx)*12;
      const u16* s2 = x2g + base;
      a2=*(const uint2*)s2; b2=*(const uint2*)(s2+4); c2=*(const uint2*)(s2+8);
      const u16* s1 = x1g + base;
      a1=*(const uint2*)s1; b1=*(const uint2*)(s1+4); c1=*(const uint2*)(s1+8);
    }
    *(uint4*)(HB2 + tid*48)      = make_uint4(a2.x,a2.y,b2.x,b2.y);
    *(uint4*)(HB2 + tid*48 + 16) = make_uint4(c2.x,c2.y,0,0);
    *(uint4*)(HB1 + tid*48)      = make_uint4(a1.x,a1.y,b1.x,b1.y);
    *(uint4*)(HB1 + tid*48 + 16) = make_uint4(c1.x,c1.y,0,0);
  }
  if (tid < 108){
    const int ch = tid/9, tp = tid - ch*9;
    WDW[tp*12 + ch] = dww[g*108 + tid];     // transpose to [tap][ch]
  }
  #pragma unroll
  for (int it=0; it<2; ++it){
    int idx = tid + (it<<8);
    int sub = idx >> 8;
    int p = (idx>>2)&63, q = idx&3;
    int gy = rh + (sub<<3) + (p>>3), gx = rw + (p&7);
    float4 v = *(const float4*)(para + ((size_t)b*HW_+gy*IW+gx)*16 + q*4);
    *(float4*)&PS[sub*1280 + p*20 + q*4] = v;
  }
  __syncthreads();

  int tapoff[5];
  tapoff[0] = hi ? 48   : 0;
  tapoff[1] = hi ? 480  : 96;
  tapoff[2] = hi ? 576  : 528;
  tapoff[3] = hi ? 1008 : 960;
  tapoff[4] = 1056;

  #pragma unroll
  for (int sub=0; sub<2; ++sub){
    const int sy = sub<<3;
    const int base0 = ((sy + (lr>>3))*10 + (lr&7))*48 + lo16*16;

    f32x4 acc[3][4];
    #pragma unroll
    for (int oo=0;oo<3;oo++)
      #pragma unroll
      for (int n=0;n<4;n++) acc[oo][n]=(f32x4){0.f,0.f,0.f,0.f};

    __builtin_amdgcn_s_setprio(1);
    #pragma unroll
    for (int ks=0;ks<5;ks++){
      bf16x8 bfr[4];
      #pragma unroll
      for (int n=0;n<4;n++)
        bfr[n] = *(const bf16x8*)(HB2 + base0 + n*960 + tapoff[ks]);
      #pragma unroll
      for (int oo=0;oo<3;oo++)
        #pragma unroll
        for (int n=0;n<4;n++)
          acc[oo][n]=__builtin_amdgcn_mfma_f32_16x16x32_bf16(af[oo][ks], bfr[n], acc[oo][n],0,0,0);
    }
    __builtin_amdgcn_s_setprio(0);

    const float* ps = &PS[sub*1280];
    f32x4 prv[4];
    #pragma unroll
    for (int n=0;n<4;n++)
      prv[n] = *(const f32x4*)&ps[((n<<4)+lr)*20+(g4<<2)];
    #pragma unroll
    for (int oo=0;oo<3;oo++){
      const int o=wv*3+oo;
      #pragma unroll
      for (int n=0;n<4;n++){
        const int p=(n<<4)+lr;
        float s=acc[oo][n].x*prv[n].x+acc[oo][n].y*prv[n].y+acc[oo][n].z*prv[n].z+acc[oo][n].w*prv[n].w;
        s += __shfl_xor(s,16); s += __shfl_xor(s,32);
        if (g4==n) OS[((sub<<6)+p)*12+o] = gelu_f(s);
      }
    }
  }
  __syncthreads();
  {
    const size_t gb = (size_t)b*HW_;
    for (int idx=tid; idx<384; idx+=256){
      const int cq = idx % 3;
      const int rest = idx / 3;
      const int p = rest & 63, sub = rest >> 6;
      const int py = p>>3, px = p&7;
      const int Y = (sub<<3)+py, X = px;
      const unsigned char* hb1 = HB1 + (Y*10+X)*48 + cq*8;
      float v0=0.f,v1=0.f,v2=0.f,v3=0.f;
      #pragma unroll
      for (int i=0;i<3;i++){
        #pragma unroll
        for (int j=0;j<3;j++){
          const uint2 r = *(const uint2*)(hb1 + (i*10+j)*48);
          const int tp=i*3+j;
          const f32x4 wv4 = *(const f32x4*)&WDW[tp*12 + cq*4];
          v0 += bfl(r.x)*wv4.x;   v1 += bfh(r.x)*wv4.y;
          v2 += bfl(r.y)*wv4.z;   v3 += bfh(r.y)*wv4.w;
        }
      }
      // group-major coalesced write
      const size_t gi = ((size_t)g*ST + gb + (rh+(sub<<3)+py)*IW + (rw+px))*12 + cq*4;
      const float* os = &OS[((sub<<6)+p)*12 + cq*4];
      uint2 pk;
      pk.x = f2bf(os[0]*v0) | (f2bf(os[1]*v1)<<16);
      pk.y = f2bf(os[2]*v2) | (f2bf(os[3]*v3)<<16);
      *(uint2*)(outb2 + gi) = pk;
    }
  }
}

// ---------------------------------------------------------------------------
// allprep body (bid roles: [0,648) wcopy, [648,654) P1eff, [654,2574) ada)
// ---------------------------------------------------------------------------
__device__ __forceinline__ void allprep_body(
    const float* __restrict__ s0, const float* __restrict__ s1,
    const float* __restrict__ s2, const float* __restrict__ s3,
    const float* __restrict__ s4, const float* __restrict__ s5,
    const float* __restrict__ s6, const float* __restrict__ s7,
    const float* __restrict__ p1w, const float* __restrict__ aw,
    u16* __restrict__ wdst, u16* __restrict__ apre, int bid)
{
  const int tid = threadIdx.x;
  if (bid < 648){
    const int blks[8]={108,72,72,72,36,72,72,144};
    const int off[8] ={0,27648,46080,66048,84480,93696,112128,130560};
    const int sz[8]  ={27648,18432,18432,18432,9216,18432,18432,36864};
    int m=0, acc=0;
    #pragma unroll
    for (int k=0;k<8;k++){ if (bid >= acc + blks[k]){ acc += blks[k]; m=k+1; } }
    const float* s = (m==0)?s0:(m==1)?s1:(m==2)?s2:(m==3)?s3:(m==4)?s4:(m==5)?s5:(m==6)?s6:s7;
    int i = (bid-acc)*256 + tid;
    if (i < sz[m]) wdst[off[m]+i] = (u16)f2bf(s[i]);
  } else if (bid < 654){
    int i = (bid-648)*256 + tid;
    if (i < 1536){
      int o = i/96, ci = i - o*96;
      float s = 0.f;
      for (int k=0;k<192;k++) s += p1w[o*192+k]*s2[k*96+ci];
      wdst[64512+i] = (u16)f2bf(s);
    }
  } else {
    int E = (bid-654)*256 + tid;
    int g = E / 30720, e = E - g*30720;
    int row = e / 160, kp = e - row*160;
    int tap = kp >> 4, cl = kp & 15;
    int o = row >> 4, r = row & 15;
    float v = 0.f;
    if (tap < 9 && cl < 12)
      v = aw[(((size_t)(g*12+o)*108) + cl*9 + tap)*16 + r];
    apre[(size_t)g*30720 + e] = (u16)f2bf(v);
  }
}

// ---------------------------------------------------------------------------
// M0: allprep (2574) + ln12 (576)
// ---------------------------------------------------------------------------
__global__ __launch_bounds__(256) void prep_ln12_k(
    const float* s0, const float* s1, const float* s2, const float* s3,
    const float* s4, const float* s5, const float* s6, const float* s7,
    const float* p1w, const float* aw, u16* wdst, u16* apre,
    const float* x, const float* g1, const float* b1,
    const float* g2, const float* b2,
    u16* lnc, u16* ln1o, float* xc, float* xt)
{
  const int bid = blockIdx.x;
  if (bid < 2574)
    allprep_body(s0,s1,s2,s3,s4,s5,s6,s7,p1w,aw,wdst,apre,bid);
  else
    ln12_body(x,g1,b1,g2,b2,lnc,ln1o,xc,xt,bid-2574);
}

// ---------------------------------------------------------------------------
// M1: c12p GEMM (y<7) + qkv GEMM (y>=7)
// ---------------------------------------------------------------------------
__global__ __launch_bounds__(256) void gemm12_k(
    const u16* lnc, const u16* r6, const u16* wc12p, const float* p1b,
    const u16* wqkv, const float* qkvb, u16* pa1, u16* x1g, u16* qkv)
{
  __shared__ __align__(16) unsigned char smem[39936];
  if (blockIdx.y < 7)
    conv_body<0,false,false,false,false,true,true,false>(smem, lnc, nullptr, 96, wc12p, p1b,
        nullptr, 0, pa1, 16, 96, 400, x1g, blockIdx.x, blockIdx.y);
  else
    conv_body<0,false,false,true,false,true,false,false>(smem, r6, nullptr, 96, wqkv, qkvb,
        nullptr, 0, qkv, 288, 96, 288, nullptr, blockIdx.x, blockIdx.y-7);
}

// ---------------------------------------------------------------------------
// attn body: 1 wave per (window, head). bf16 in/out.
// ---------------------------------------------------------------------------
__device__ __forceinline__ void attn_body(const u16* __restrict__ qkv,
    const float* __restrict__ relpos, u16* __restrict__ outa, int bid)
{
  __shared__ float k_s[2048];
  __shared__ float v_s[2048];
  __shared__ float rel_s[225];
  const int win = bid % 144, head = (bid/144)%3, b = bid/432;
  const int wi = win/12, wj = win%12;
  const int lane = threadIdx.x;
  for (int i=lane;i<225;i+=64) rel_s[i] = relpos[i*3+head];
  const int pi = lane>>3, pj = lane&7;
  const int hr = wi*8+pi, wr = wj*8+pj;
  const int sh = (hr+4)%96, sw = (wr+4)%96;
  const size_t pix = (size_t)b*HW_ + sh*96 + sw;
  const u16* base = qkv + pix*288;
  const float SC = 0.17677669529663687f;
  float q[32];
  #pragma unroll
  for (int i=0;i<4;i++){
    const uint4 r = *(const uint4*)(base + head*32 + i*8);
    q[i*8+0]=bfl(r.x)*SC; q[i*8+1]=bfh(r.x)*SC;
    q[i*8+2]=bfl(r.y)*SC; q[i*8+3]=bfh(r.y)*SC;
    q[i*8+4]=bfl(r.z)*SC; q[i*8+5]=bfh(r.z)*SC;
    q[i*8+6]=bfl(r.w)*SC; q[i*8+7]=bfh(r.w)*SC;
  }
  #pragma unroll
  for (int i=0;i<4;i++){
    const uint4 rk = *(const uint4*)(base + 96 + head*32 + i*8);
    const uint4 rv = *(const uint4*)(base + 192 + head*32 + i*8);
    *(float4*)&k_s[(lane<<5)+i*8]   = make_float4(bfl(rk.x),bfh(rk.x),bfl(rk.y),bfh(rk.y));
    *(float4*)&k_s[(lane<<5)+i*8+4] = make_float4(bfl(rk.z),bfh(rk.z),bfl(rk.w),bfh(rk.w));
    *(float4*)&v_s[(lane<<5)+i*8]   = make_float4(bfl(rv.x),bfh(rv.x),bfl(rv.y),bfh(rv.y));
    *(float4*)&v_s[(lane<<5)+i*8+4] = make_float4(bfl(rv.z),bfh(rv.z),bfl(rv.w),bfh(rv.w));
  }
  __syncthreads();
  const bool mi = (wi==11), mj = (wj==11);
  float sc[64];
  #pragma unroll
  for (int qq=0; qq<64; qq++){
    const float4* kr4 = (const float4*)&k_s[qq<<5];
    float s = 0.f;
    #pragma unroll
    for (int i=0;i<8;i++){
      const float4 kv = kr4[i];
      s += q[4*i]*kv.x + q[4*i+1]*kv.y + q[4*i+2]*kv.z + q[4*i+3]*kv.w;
    }
    const int qi = qq>>3, qj = qq&7;
    s += rel_s[(pi-qi+7)*15 + (pj-qj+7)];
    const bool msk = (mi && ((pi<4)!=(qi<4))) || (mj && ((pj<4)!=(qj<4)));
    sc[qq] = msk ? -1e30f : s;
  }
  float m = sc[0];
  #pragma unroll
  for (int qq=1;qq<64;qq++) m = fmaxf(m, sc[qq]);
  float sum = 0.f;
  #pragma unroll
  for (int qq=0;qq<64;qq++){ float e = __expf(sc[qq]-m); sc[qq]=e; sum+=e; }
  const float inv = 1.f/sum;
  float acc[32];
  #pragma unroll
  for (int i=0;i<32;i++) acc[i]=0.f;
  #pragma unroll
  for (int qq=0;qq<64;qq++){
    const float a = sc[qq]*inv;
    const float4* vr4 = (const float4*)&v_s[qq<<5];
    #pragma unroll
    for (int i=0;i<8;i++){
      const float4 vv = vr4[i];
      acc[4*i]+=a*vv.x; acc[4*i+1]+=a*vv.y; acc[4*i+2]+=a*vv.z; acc[4*i+3]+=a*vv.w;
    }
  }
  u16* orow = outa + pix*96 + head*32;
  #pragma unroll
  for (int i=0;i<4;i++){
    uint4 pk;
    pk.x = f2bf(acc[i*8+0])|(f2bf(acc[i*8+1])<<16);
    pk.y = f2bf(acc[i*8+2])|(f2bf(acc[i*8+3])<<16);
    pk.z = f2bf(acc[i*8+4])|(f2bf(acc[i*8+5])<<16);
    pk.w = f2bf(acc[i*8+6])|(f2bf(acc[i*8+7])<<16);
    *(uint4*)(orow + i*8) = pk;
  }
}

// ---------------------------------------------------------------------------
// p2conv body (64-thread, 4 task-chunks per block to amortize W staging).
// ---------------------------------------------------------------------------
__device__ __forceinline__ void p2conv_body(const u16* __restrict__ in,
    const float* __restrict__ w, const float* __restrict__ bias,
    float* __restrict__ out, int bid)
{
  __shared__ float ws[2304];
  int tid = threadIdx.x;
  for (int i=tid;i<2304;i+=64) ws[i]=w[i];
  __syncthreads();
  #pragma unroll 1
  for (int it=0; it<4; ++it){
    int gidx = bid*256 + it*64 + tid;
    int p = gidx >> 2, qq = gidx & 3;
    int bb = p / HW_, hw = p - bb*HW_;
    int hy = hw / IW, wx = hw - hy*IW;
    const int cb = qq<<2;
    float a0=bias[cb], a1=bias[cb+1], a2=bias[cb+2], a3=bias[cb+3];
    #pragma unroll
    for (int i=0;i<3;i++){
      int y=hy+i-1; if ((unsigned)y>=IH) continue;
      #pragma unroll
      for (int j=0;j<3;j++){
        int x2=wx+j-1; if ((unsigned)x2>=IW) continue;
        int tap=i*3+j;
        const uint4 r = *(const uint4*)(in + ((size_t)bb*HW_ + y*IW + x2)*16);
        const uint4 r2 = *(const uint4*)(in + ((size_t)bb*HW_ + y*IW + x2)*16 + 8);
        float vv[16]={bfl(r.x),bfh(r.x),bfl(r.y),bfh(r.y),bfl(r.z),bfh(r.z),bfl(r.w),bfh(r.w),
                      bfl(r2.x),bfh(r2.x),bfl(r2.y),bfh(r2.y),bfl(r2.z),bfh(r2.z),bfl(r2.w),bfh(r2.w)};
        #pragma unroll
        for (int ci=0;ci<16;ci++){
          float v = vv[ci];
          a0 += ws[(cb+0)*144 + ci*9 + tap]*v;
          a1 += ws[(cb+1)*144 + ci*9 + tap]*v;
          a2 += ws[(cb+2)*144 + ci*9 + tap]*v;
          a3 += ws[(cb+3)*144 + ci*9 + tap]*v;
        }
      }
    }
    *(float4*)(out + (size_t)p*16 + cb) = make_float4(a0,a1,a2,a3);
  }
}

// ---------------------------------------------------------------------------
// M1.5: attn (bid<864) + p2conv (288 blocks x 4 chunks)
// ---------------------------------------------------------------------------
__global__ __launch_bounds__(64) void attn_p2_k(
    const u16* __restrict__ qkv, const float* __restrict__ relpos,
    u16* __restrict__ outa,
    const u16* __restrict__ pa1, const float* __restrict__ p2w,
    const float* __restrict__ p2b, float* __restrict__ pa2)
{
  const int bid = blockIdx.x;
  if (bid < 864) attn_body(qkv, relpos, outa, bid);
  else           p2conv_body(pa1, p2w, p2b, pa2, bid-864);
}

// ---------------------------------------------------------------------------
// M2: adaconv (bid<2304, XCD-locality swizzled) + proj GEMM (288)
// ---------------------------------------------------------------------------
__global__ __launch_bounds__(256) void ada_proj_k(
    const u16* x1g, const u16* x2g, const float* para, const u16* apre,
    const float* dww, u16* outb2,
    const u16* r6, const u16* wproj, const float* projb, float* xt)
{
  __shared__ __align__(16) unsigned char smem[39936];
  const int bid = blockIdx.x;
  if (bid < 2304){
    const int xcd = bid & 7, j = bid >> 3;
    const int g = xcd + ((j & 1) << 3);
    const int t = j >> 1;                 // 0..143
    const int b = t / 72, reg = t - b*72;
    adaconv_body(smem, x1g, x2g, para, apre, dww, outb2, b, g, reg);
  } else {
    const int bx = bid - 2304;
    conv_body<0,false,false,true,true,false,false,false>(smem, r6, nullptr, 96, wproj, projb,
        xt, 96, xt, 96, 96, 96, nullptr, bx % 144, bx / 144);
  }
}

// ---------------------------------------------------------------------------
// M3: c3 GEMM (bid<288, group-major gather) + ln2 (4608)
// ---------------------------------------------------------------------------
__global__ __launch_bounds__(256) void c3_ln2_k(
    const u16* b2g, const u16* wc3, const float* xc, u16* r4,
    const float* xt, const float* g2, const float* bt2, u16* r6)
{
  __shared__ __align__(16) unsigned char smem[39936];
  const int bid = blockIdx.x;
  if (bid < 288)
    conv_body<0,false,false,false,true,true,false,true>(smem, b2g, nullptr, 12, wc3, nullptr,
        xc, 96, r4, 96, 192, 96, nullptr, bid % 144, bid / 144);
  else
    ln_body(xt, 96, g2, bt2, r6, bid-288);
}

// ---------------------------------------------------------------------------
// K4: depthwise 3x3, bf16 in/out, 4 ch/thread — FFN dw (XCD-chunked swizzle).
// ---------------------------------------------------------------------------
template<bool HASB, bool DOGELU>
__global__ __launch_bounds__(256) void dw3x3_k(const u16* __restrict__ in, int istride,
                                               const float* __restrict__ w,
                                               const float* __restrict__ bias,
                                               u16* __restrict__ out, int C){
  // XCD-chunked bijective swizzle (gridDim.x % 8 == 0): contiguous image
  // slabs per XCD -> halo-row reuse stays in one L2.
  const int q8 = gridDim.x >> 3;
  const int bid = (blockIdx.x & 7)*q8 + (blockIdx.x >> 3);
  int t = bid*256 + threadIdx.x;
  int cg = C >> 2;
  int p = t / cg;
  if (p >= ST) return;
  int c4 = (t - p*cg) << 2;
  int bb = p / HW_, hw = p - bb*HW_;
  int hy = hw / IW, wx = hw - hy*IW;
  float w0[9], w1[9], w2[9], w3[9];
  #pragma unroll
  for (int tp=0;tp<9;tp++){
    w0[tp]=w[(c4+0)*9+tp]; w1[tp]=w[(c4+1)*9+tp]; w2[tp]=w[(c4+2)*9+tp]; w3[tp]=w[(c4+3)*9+tp];
  }
  float ax=0.f, ay=0.f, az=0.f, aw=0.f;
  #pragma unroll
  for (int i=0;i<3;i++){
    int y = hy+i-1;
    if ((unsigned)y >= IH) continue;
    #pragma unroll
    for (int j=0;j<3;j++){
      int x2 = wx+j-1;
      if ((unsigned)x2 >= IW) continue;
      const uint2 r = *(const uint2*)(in + ((size_t)bb*HW_ + y*IW + x2)*istride + c4);
      int tp=i*3+j;
      ax += bfl(r.x)*w0[tp]; ay += bfh(r.x)*w1[tp];
      az += bfl(r.y)*w2[tp]; aw += bfh(r.y)*w3[tp];
    }
  }
  if (HASB){ ax+=bias[c4]; ay+=bias[c4+1]; az+=bias[c4+2]; aw+=bias[c4+3]; }
  if (DOGELU){ ax=gelu_f(ax); ay=gelu_f(ay); az=gelu_f(az); aw=gelu_f(aw); }
  uint2 pk;
  pk.x = f2bf(ax)|(f2bf(ay)<<16);
  pk.y = f2bf(az)|(f2bf(aw)<<16);
  *(uint2*)(out + (size_t)p*C + c4) = pk;
}

// ---------------------------------------------------------------------------
extern "C" void kernel_launch(void* const* d_in, const int* in_sizes, int n_in,
                              void* d_out, int out_size, void* d_ws, size_t ws_size,
                              hipStream_t stream)
{
  (void)in_sizes; (void)n_in; (void)out_size; (void)ws_size;
  const float* x        = (const float*)d_in[0];
  const float* cb_ln_g  = (const float*)d_in[1];
  const float* cb_ln_b  = (const float*)d_in[2];
  const float* cb_c1_pw = (const float*)d_in[3];
  const float* cb_c1_dw = (const float*)d_in[4];
  const float* cb_c2_pw = (const float*)d_in[5];
  const float* ada_w    = (const float*)d_in[6];
  const float* ada_p1_w = (const float*)d_in[7];
  const float* ada_p1_b = (const float*)d_in[8];
  const float* ada_p2_w = (const float*)d_in[9];
  const float* ada_p2_b = (const float*)d_in[10];
  const float* cb_c3_w  = (const float*)d_in[11];
  const float* ln1_g    = (const float*)d_in[12];
  const float* ln1_b    = (const float*)d_in[13];
  const float* qkv_w    = (const float*)d_in[14];
  const float* qkv_b    = (const float*)d_in[15];
  const float* rel_pos  = (const float*)d_in[16];
  const float* proj_w   = (const float*)d_in[17];
  const float* proj_b   = (const float*)d_in[18];
  const float* ln2_g    = (const float*)d_in[19];
  const float* ln2_b    = (const float*)d_in[20];
  const float* ffn_w1   = (const float*)d_in[21];
  const float* ffn_b1   = (const float*)d_in[22];
  const float* ffn_dw   = (const float*)d_in[23];
  const float* ffn_db   = (const float*)d_in[24];
  const float* ffn_w2   = (const float*)d_in[25];
  const float* ffn_b2   = (const float*)d_in[26];
  const float* out_w    = (const float*)d_in[27];
  const float* out_b    = (const float*)d_in[28];

  char* wsb = (char*)d_ws;
  // fp32 regions
  float* XC  = (float*)wsb;                                   // ST*96  raw conv residual
  float* U0f = (float*)(wsb + (size_t)ST*96*4);               // ST*288 f32 overlay region
  float* XT  = (float*)(wsb + (size_t)ST*384*4);              // ST*96  transformer residual
  float* PA2 = (float*)(wsb + (size_t)ST*480*4);              // ST*16
  // u16 regions
  u16* B2G  = (u16*)(wsb + (size_t)ST*496*4);                 // ST*192 (group-major slabs)
  u16* LNCb = B2G  + (size_t)ST*192;                          // ST*96
  u16* R4b  = LNCb + (size_t)ST*96;                           // ST*96
  u16* R6b  = R4b  + (size_t)ST*96;                           // ST*96
  u16* PA1b = R6b  + (size_t)ST*96;                           // ST*16
  u16* Wbf  = PA1b + (size_t)ST*16;                           // 167424
  u16* Apre = Wbf + 167424;                                   // 491520
  u16* QKVb = Apre + 491520;                                  // ST*288 (dedicated)
  // overlays on U0f (capacity ST*576 u16):
  u16* X1G  = (u16*)U0f;                     // ST*192 u16, group-major c1
  u16* X2G  = X1G + (size_t)ST*192;          // ST*192 u16, group-major c2
  u16* FF1b = (u16*)U0f;                     // ST*192 u16 (after adaconv consumed X1G/X2G)
  u16* DWOb = (u16*)U0f + (size_t)ST*192;

  const u16* W_qkv  = Wbf + 0;
  const u16* W_c12p = Wbf + 27648;   // [400][96]: c1, c2, P1eff
  const u16* W_c3   = Wbf + 66048;
  const u16* W_proj = Wbf + 84480;
  const u16* W_ffn1 = Wbf + 93696;
  const u16* W_ffn2 = Wbf + 112128;
  const u16* W_fin  = Wbf + 130560;

  // M0: all weight preps + fused dual LN  (2574 + 576 blocks)
  prep_ln12_k<<<3150, 256, 0, stream>>>(qkv_w, cb_c1_pw, cb_c2_pw, cb_c3_w,
                                        proj_w, ffn_w1, ffn_w2, out_w,
                                        ada_p1_w, ada_w, Wbf, Apre,
                                        x, cb_ln_g, cb_ln_b, ln1_g, ln1_b,
                                        LNCb, R6b, XC, XT);

  // M1: c12p GEMM + qkv GEMM
  gemm12_k<<<dim3(144, 12), 256, 0, stream>>>(LNCb, R6b, W_c12p, ada_p1_b,
                                              W_qkv, qkv_b, PA1b, X1G, QKVb);

  // M1.5: attention + para conv (864 + 288 blocks)
  attn_p2_k<<<1152, 64, 0, stream>>>(QKVb, rel_pos, R6b,
                                     PA1b, ada_p2_w, ada_p2_b, PA2);

  // M2: adaconv (+fused dw1, XCD-swizzled, group-major out) + proj GEMM
  ada_proj_k<<<2592, 256, 0, stream>>>(X1G, X2G, PA2, Apre, cb_c1_dw, B2G,
                                       R6b, W_proj, proj_b, XT);

  // M3: c3 GEMM (group-major gather) + ln2  (288 + 4608)
  c3_ln2_k<<<4896, 256, 0, stream>>>(B2G, W_c3, XC, R4b, XT, ln2_g, ln2_b, R6b);

  // FFN chain
  conv_mfma_k<0,false,false,true,false,true,false,false><<<dim3(144, 3), 256, 0, stream>>>(R6b, nullptr, 96, W_ffn1, ffn_b1, nullptr, 0, FF1b, 192, 96, 192, nullptr);
  dw3x3_k<true,true><<<(ST*48)/256, 256, 0, stream>>>(FF1b, 192, ffn_dw, ffn_db, DWOb, 192);
  conv_mfma_k<0,false,false,true,true,false,false,false><<<dim3(144, 2), 256, 0, stream>>>(DWOb, nullptr, 192, W_ffn2, ffn_b2, XT, 96, XT, 96, 192, 96, nullptr);

  // final: out = x + conv1x1(concat(convout bf16, xt f32), out_w) + out_b
  conv_mfma_k<0,true,true,true,true,false,false,false><<<dim3(144, 3), 256, 0, stream>>>(R4b, XT, 96, W_fin, out_b, x, 0, (float*)d_out, 0, 192, 192, nullptr);
}